// Round 14
// baseline (569.583 us; speedup 1.0000x reference)
//
#include <hip/hip_runtime.h>
#include <hip/hip_bf16.h>
#include <math.h>

#define EPSV 1e-5f

typedef float vf2 __attribute__((ext_vector_type(2)));
typedef float vf4 __attribute__((ext_vector_type(4)));

// ---------------- sizes ----------------
// B=32 Bc=16 L=2048 TOKEN=40 STRIDE=4 D=81 H=9 dk=9 S=512 FF=256 FC1=512 FC2=256 Y=4

// ---------------- minmax: two-stage ----------------
__global__ void minmax_part(const float* __restrict__ x, float* __restrict__ part) {
    __shared__ float smin[256], smax[256];
    int tid = threadIdx.x;
    float mn = 1e30f, mx = -1e30f;
    for (int i = blockIdx.x * 256 + tid; i < 32 * 2008; i += 64 * 256) {
        int b = i / 2008, c = i % 2008 + 20;
        float v = x[b * 2048 + c];
        mn = fminf(mn, v); mx = fmaxf(mx, v);
    }
    smin[tid] = mn; smax[tid] = mx; __syncthreads();
    for (int off = 128; off > 0; off >>= 1) {
        if (tid < off) { smin[tid] = fminf(smin[tid], smin[tid + off]); smax[tid] = fmaxf(smax[tid], smax[tid + off]); }
        __syncthreads();
    }
    if (tid == 0) { part[blockIdx.x] = smin[0]; part[64 + blockIdx.x] = smax[0]; }
}

__global__ void minmax_fin(const float* __restrict__ part, float* __restrict__ scal) {
    __shared__ float smn[64], smx[64];
    int tid = threadIdx.x;
    smn[tid] = part[tid]; smx[tid] = part[64 + tid]; __syncthreads();
    for (int off = 32; off > 0; off >>= 1) {
        if (tid < off) { smn[tid] = fminf(smn[tid], smn[tid + off]); smx[tid] = fmaxf(smx[tid], smx[tid + off]); }
        __syncthreads();
    }
    if (tid == 0) { scal[0] = smn[0]; scal[1] = smx[0] - smn[0]; }
}

// ---------------- PE table (512 x 81) ----------------
__global__ void pe_kernel(float* __restrict__ pe) {
    int idx = blockIdx.x * blockDim.x + threadIdx.x;
    if (idx >= 512 * 81) return;
    int d = idx % 81, s = idx / 81;
    int j = d >> 1;
    float dv = __expf(-9.210340371976184f * (2.0f * (float)j) / 81.0f);
    float ang = (float)s * dv;
    pe[idx] = (d & 1) ? cosf(ang) : sinf(ang);
}

// ---------------- tokenize + add PE ----------------
__global__ void tokenize_kernel(const float* __restrict__ x, const float* __restrict__ cali,
                                const float* __restrict__ scal, const float* __restrict__ pe,
                                float* __restrict__ txall) {
    int idx = blockIdx.x * blockDim.x + threadIdx.x;
    if (idx >= 48 * 512 * 81) return;
    int d = idx % 81;
    int s = (idx / 81) % 512;
    int r = idx / (81 * 512);
    float xm = scal[0], inv_xs = 1.0f / scal[1];
    int oc = s * 4 + d - 40;
    float val = 0.0f;
    if (oc >= 0 && oc < 2048) {
        float sv = (r < 32) ? x[r * 2048 + oc] : cali[(r - 32) * 2048 + oc];
        val = (sv - xm) * inv_xs;
    }
    txall[idx] = val + pe[s * 81 + d];
}

// ======== 4x4-tile 81->81 GEMM pieces (rows stride 84, W [e][col] stride 84) ========

// ---------------- qkv2: 64 rows/block, W-pass split (1024 blocks), 4x4 tile ----------------
__global__ __launch_bounds__(256) void qkv2_kernel(const float* __restrict__ txall,
                            const float* __restrict__ Wq2, const float* __restrict__ Wk2,
                            const float* __restrict__ Wv2,
                            float* __restrict__ Q2, float* __restrict__ Kc, float* __restrict__ Vc) {
    __shared__ float rows_[64 * 84];
    __shared__ float Wl[84 * 84];
    int blk = blockIdx.x;            // 0..1023
    int t, rb;
    if (blk < 256)      { t = 0; rb = blk; }
    else if (blk < 640) { t = 1; rb = blk - 256; }
    else                { t = 2; rb = blk - 640; }
    int row0 = rb * 64;
    int k = row0 >> 9;
    int s0 = row0 & 511;
    const float* W = (t == 0) ? Wq2 : (t == 1) ? Wk2 : Wv2;
    int tid = threadIdx.x;
    for (int i = tid; i < 64 * 84; i += 256) {
        int c = i % 84;
        rows_[i] = (c < 81) ? txall[(row0 + i / 84) * 81 + c] : 0.0f;
    }
    for (int i = tid; i < 84 * 84; i += 256) {
        int e = i / 84, hd = i % 84;
        Wl[i] = (e < 81 && hd < 81) ? W[(hd / 9) * 729 + e * 9 + (hd % 9)] : 0.0f;
    }
    __syncthreads();
    for (int o = tid; o < 336; o += 256) {
        int r4 = o / 21, cg = o % 21;
        int c0 = cg * 4;
        const float* rp = rows_ + r4 * 4 * 84;
        vf4 acc0 = 0.0f, acc1 = 0.0f, acc2 = 0.0f, acc3 = 0.0f;
        #pragma unroll 7
        for (int e = 0; e < 84; e += 4) {
            vf4 w0 = *(const vf4*)(Wl + (e + 0) * 84 + c0);
            vf4 w1 = *(const vf4*)(Wl + (e + 1) * 84 + c0);
            vf4 w2 = *(const vf4*)(Wl + (e + 2) * 84 + c0);
            vf4 w3 = *(const vf4*)(Wl + (e + 3) * 84 + c0);
            vf4 r0 = *(const vf4*)(rp + e);
            vf4 r1 = *(const vf4*)(rp + 84 + e);
            vf4 r2 = *(const vf4*)(rp + 168 + e);
            vf4 r3 = *(const vf4*)(rp + 252 + e);
            acc0 += r0[0] * w0 + r0[1] * w1 + r0[2] * w2 + r0[3] * w3;
            acc1 += r1[0] * w0 + r1[1] * w1 + r1[2] * w2 + r1[3] * w3;
            acc2 += r2[0] * w0 + r2[1] * w1 + r2[2] * w2 + r2[3] * w3;
            acc3 += r3[0] * w0 + r3[1] * w1 + r3[2] * w2 + r3[3] * w3;
        }
        vf4 av[4] = {acc0, acc1, acc2, acc3};
        #pragma unroll
        for (int cc = 0; cc < 4; cc++) {
            int col = c0 + cc;
            if (col < 81) {
                int h = col / 9, d = col % 9;
                #pragma unroll
                for (int rr = 0; rr < 4; rr++) {
                    int s = s0 + r4 * 4 + rr;
                    if (t == 0)      Q2[((s * 9 + h) * 32 + k) * 9 + d] = av[rr][cc];
                    else if (t == 1) Kc[((s * 9 + h) * 48 + k) * 9 + d] = av[rr][cc];
                    else             Vc[((s * 9 + h) * 48 + k) * 9 + d] = av[rr][cc];
                }
            }
        }
    }
}

// ---------------- attention-2 (masked: key==b or key>=32), no-max softmax (exp2) ----------------
__global__ void attn2_kernel(const float* __restrict__ Q2, const float* __restrict__ Kc,
                             const float* __restrict__ Vc, float* __restrict__ tmp2) {
    int tid = blockIdx.x * blockDim.x + threadIdx.x;
    if (tid >= 512 * 9 * 32) return;
    int b = tid & 31;
    int h = (tid >> 5) % 9;
    int s = tid / 288;
    const float* q = Q2 + ((s * 9 + h) * 32 + b) * 9;
    float qr[9];
    const float c2 = 1.4426950408889634f / 3.0f;   // log2e / 3
    #pragma unroll
    for (int d = 0; d < 9; d++) qr[d] = q[d] * c2;
    const float* Kb = Kc + (s * 9 + h) * 48 * 9;
    const float* Vb = Vc + (s * 9 + h) * 48 * 9;
    float l = 0.0f, outv[9];
    #pragma unroll
    for (int d = 0; d < 9; d++) outv[d] = 0.0f;
    #pragma unroll
    for (int j = 0; j < 17; j++) {
        int k = (j == 0) ? b : 31 + j;
        const float* kp = Kb + k * 9;
        float acc = 0.0f;
        #pragma unroll
        for (int d = 0; d < 9; d++) acc += qr[d] * kp[d];
        float p = exp2f(acc);
        l += p;
        const float* vp = Vb + k * 9;
        #pragma unroll
        for (int d = 0; d < 9; d++) outv[d] += p * vp[d];
    }
    float invl = 1.0f / l;
    float* op = tmp2 + (b * 512 + s) * 81 + h * 9;
    #pragma unroll
    for (int d = 0; d < 9; d++) op[d] = outv[d] * invl;
}

// ---------------- h2 = tmp2 @ Wo2 ; xh = tx + h2  (64 rows/block, 4x4 tile) ----------------
__global__ __launch_bounds__(256) void h2xh_kernel(const float* __restrict__ tmp2,
                            const float* __restrict__ Wo2, const float* __restrict__ txall,
                            float* __restrict__ h2, float* __restrict__ xh) {
    __shared__ float rows_[64 * 84];
    __shared__ float Wl[84 * 84];
    int row0 = blockIdx.x * 64;
    int tid = threadIdx.x;
    for (int i = tid; i < 64 * 84; i += 256) {
        int c = i % 84;
        rows_[i] = (c < 81) ? tmp2[(row0 + i / 84) * 81 + c] : 0.0f;
    }
    for (int i = tid; i < 84 * 84; i += 256) {
        int e = i / 84, c = i % 84;
        Wl[i] = (e < 81 && c < 81) ? Wo2[e * 81 + c] : 0.0f;
    }
    __syncthreads();
    for (int o = tid; o < 336; o += 256) {
        int r4 = o / 21, cg = o % 21;
        int c0 = cg * 4;
        const float* rp = rows_ + r4 * 4 * 84;
        vf4 acc0 = 0.0f, acc1 = 0.0f, acc2 = 0.0f, acc3 = 0.0f;
        #pragma unroll 7
        for (int e = 0; e < 84; e += 4) {
            vf4 w0 = *(const vf4*)(Wl + (e + 0) * 84 + c0);
            vf4 w1 = *(const vf4*)(Wl + (e + 1) * 84 + c0);
            vf4 w2 = *(const vf4*)(Wl + (e + 2) * 84 + c0);
            vf4 w3 = *(const vf4*)(Wl + (e + 3) * 84 + c0);
            vf4 r0 = *(const vf4*)(rp + e);
            vf4 r1 = *(const vf4*)(rp + 84 + e);
            vf4 r2 = *(const vf4*)(rp + 168 + e);
            vf4 r3 = *(const vf4*)(rp + 252 + e);
            acc0 += r0[0] * w0 + r0[1] * w1 + r0[2] * w2 + r0[3] * w3;
            acc1 += r1[0] * w0 + r1[1] * w1 + r1[2] * w2 + r1[3] * w3;
            acc2 += r2[0] * w0 + r2[1] * w1 + r2[2] * w2 + r2[3] * w3;
            acc3 += r3[0] * w0 + r3[1] * w1 + r3[2] * w2 + r3[3] * w3;
        }
        vf4 av[4] = {acc0, acc1, acc2, acc3};
        #pragma unroll
        for (int cc = 0; cc < 4; cc++) {
            int col = c0 + cc;
            if (col < 81) {
                #pragma unroll
                for (int rr = 0; rr < 4; rr++) {
                    int idx = (row0 + r4 * 4 + rr) * 81 + col;
                    float v = av[rr][cc];
                    h2[idx] = v;
                    xh[idx] = txall[idx] + v;
                }
            }
        }
    }
}

// ---------------- Qs/Ks (Vs == Qs): 64 rows/block, W-pass split (512 blocks), 4x4 ----------------
__global__ __launch_bounds__(256) void qks_kernel(const float* __restrict__ xh,
                           const float* __restrict__ Wq, const float* __restrict__ Wk,
                           float* __restrict__ Qs, float* __restrict__ Ks) {
    __shared__ float rows_[64 * 84];
    __shared__ float Wl[84 * 84];
    int blk = blockIdx.x;            // 0..511
    int t = blk >> 8;                // 0: Q, 1: K
    int rb = blk & 255;
    int row0 = rb * 64;
    int b = row0 >> 9;
    int s0 = row0 & 511;
    const float* W = (t == 0) ? Wq : Wk;
    int tid = threadIdx.x;
    for (int i = tid; i < 64 * 84; i += 256) {
        int c = i % 84;
        rows_[i] = (c < 81) ? xh[(row0 + i / 84) * 81 + c] : 0.0f;
    }
    for (int i = tid; i < 84 * 84; i += 256) {
        int e = i / 84, hd = i % 84;
        Wl[i] = (e < 81 && hd < 81) ? W[(hd / 9) * 729 + e * 9 + (hd % 9)] : 0.0f;
    }
    __syncthreads();
    float* dst = (t == 0) ? Qs : Ks;
    for (int o = tid; o < 336; o += 256) {
        int r4 = o / 21, cg = o % 21;
        int c0 = cg * 4;
        const float* rp = rows_ + r4 * 4 * 84;
        vf4 acc0 = 0.0f, acc1 = 0.0f, acc2 = 0.0f, acc3 = 0.0f;
        #pragma unroll 7
        for (int e = 0; e < 84; e += 4) {
            vf4 w0 = *(const vf4*)(Wl + (e + 0) * 84 + c0);
            vf4 w1 = *(const vf4*)(Wl + (e + 1) * 84 + c0);
            vf4 w2 = *(const vf4*)(Wl + (e + 2) * 84 + c0);
            vf4 w3 = *(const vf4*)(Wl + (e + 3) * 84 + c0);
            vf4 r0 = *(const vf4*)(rp + e);
            vf4 r1 = *(const vf4*)(rp + 84 + e);
            vf4 r2 = *(const vf4*)(rp + 168 + e);
            vf4 r3 = *(const vf4*)(rp + 252 + e);
            acc0 += r0[0] * w0 + r0[1] * w1 + r0[2] * w2 + r0[3] * w3;
            acc1 += r1[0] * w0 + r1[1] * w1 + r1[2] * w2 + r1[3] * w3;
            acc2 += r2[0] * w0 + r2[1] * w1 + r2[2] * w2 + r2[3] * w3;
            acc3 += r3[0] * w0 + r3[1] * w1 + r3[2] * w2 + r3[3] * w3;
        }
        vf4 av[4] = {acc0, acc1, acc2, acc3};
        #pragma unroll
        for (int cc = 0; cc < 4; cc++) {
            int col = c0 + cc;
            if (col < 81) {
                int h = col / 9, d = col % 9;
                #pragma unroll
                for (int rr = 0; rr < 4; rr++)
                    dst[((b * 9 + h) * 512 + (s0 + r4 * 4 + rr)) * 9 + d] = av[rr][cc];
            }
        }
    }
}

// ---------------- EBT[t*512+s] = exp(cw * (corr @ Cv)^T[t][s] / sqrt(S)) ----------------
__global__ __launch_bounds__(256) void biasmm_kernel(const float* __restrict__ corr,
                              const float* __restrict__ Cv, const float* __restrict__ cwp,
                              float* __restrict__ ebT) {
    __shared__ float As[32][33];
    __shared__ float Bs[32][33];
    int tx = threadIdx.x, ty = threadIdx.y;   // 16 x 16
    int tid = ty * 16 + tx;
    int t0 = blockIdx.y * 32, s0 = blockIdx.x * 32;
    float a00 = 0, a01 = 0, a10 = 0, a11 = 0;
    for (int k0 = 0; k0 < 512; k0 += 32) {
        for (int ii = tid; ii < 1024; ii += 256) {
            int r = ii >> 5, c = ii & 31;
            As[r][c] = Cv[(k0 + r) * 512 + t0 + c];
            Bs[r][c] = corr[(s0 + r) * 512 + k0 + c];
        }
        __syncthreads();
        #pragma unroll
        for (int kk = 0; kk < 32; kk++) {
            float b0 = Bs[tx][kk], b1 = Bs[tx + 16][kk];
            float c0 = As[kk][ty], c1 = As[kk][ty + 16];
            a00 += c0 * b0; a01 += c0 * b1; a10 += c1 * b0; a11 += c1 * b1;
        }
        __syncthreads();
    }
    float cws = cwp[0] * 0.04419417382415922f;   // cw / sqrt(512)
    ebT[(t0 + ty) * 512 + s0 + tx]            = __expf(a00 * cws);
    ebT[(t0 + ty) * 512 + s0 + tx + 16]       = __expf(a01 * cws);
    ebT[(t0 + ty + 16) * 512 + s0 + tx]       = __expf(a10 * cws);
    ebT[(t0 + ty + 16) * 512 + s0 + tx + 16]  = __expf(a11 * cws);
}

// ---------------- attention-1: no-max softmax (exp2), max-occupancy split ----------------
// grid 2304: bh = blk>>3, qq = (blk>>1)&3 (128-query quarter), kq = blk&1 (256-key plane)
// block: 256 threads = 128 queries x 2 key-subhalves (ks); 128 keys/thread
// batch-8 EB prefetch; in-block ks-merge via LDS; 2 global planes (h1o unchanged)
__global__ __launch_bounds__(256) void attn1_kernel(const float* __restrict__ Qs,
                                                    const float* __restrict__ Ks,
                                                    const float* __restrict__ ebT,
                                                    const float* __restrict__ cwp,
                                                    float* __restrict__ part) {
    int blk = blockIdx.x;          // 0..2303
    int bh = blk >> 3;             // b*9+h
    int qq = (blk >> 1) & 3;
    int kq = blk & 1;
    __shared__ float sh[2560];     // [ks][10 elems][128 q]
    int tid = threadIdx.x;
    int qt = tid & 127, ks = tid >> 7;
    const float* Kb = Ks + bh * 4608;
    const float* Qb = Qs + bh * 4608;
    int q = qq * 128 + qt;
    float c1 = (1.0f - cwp[0]) * (1.4426950408889634f / 3.0f);   // fold log2e
    vf2 qv[4];
    float q8;
    {
        const float* qp = Qb + q * 9;
        #pragma unroll
        for (int d = 0; d < 4; d++) {
            vf2 t; t.x = c1 * qp[2 * d]; t.y = c1 * qp[2 * d + 1];
            qv[d] = t;
        }
        q8 = c1 * qp[8];
    }
    float l = 0.0f, a8 = 0.0f;
    vf2 acc[4];
    #pragma unroll
    for (int d = 0; d < 4; d++) acc[d] = (vf2)0.0f;
    int k0 = kq * 256 + ks * 128;
    const float* ebp = ebT + q;
    for (int t0 = k0; t0 < k0 + 128; t0 += 8) {
        float eb[8];
        #pragma unroll
        for (int j = 0; j < 8; j++) eb[j] = ebp[(t0 + j) << 9];   // 8 loads in flight
        #pragma unroll
        for (int j = 0; j < 8; j++) {
            const float* kr = Kb + (t0 + j) * 9;   // wave-uniform -> scalar loads
            const float* vr = Qb + (t0 + j) * 9;   // Vs == Qs
            vf2 k0v; k0v.x = kr[0]; k0v.y = kr[1];
            vf2 k1v; k1v.x = kr[2]; k1v.y = kr[3];
            vf2 k2v; k2v.x = kr[4]; k2v.y = kr[5];
            vf2 k3v; k3v.x = kr[6]; k3v.y = kr[7];
            vf2 u2 = qv[0] * k0v + qv[1] * k1v + qv[2] * k2v + qv[3] * k3v;
            float u = u2.x + u2.y + q8 * kr[8];
            float p = exp2f(u) * eb[j];
            l += p;
            vf2 p2; p2.x = p; p2.y = p;
            vf2 v0; v0.x = vr[0]; v0.y = vr[1];
            vf2 v1; v1.x = vr[2]; v1.y = vr[3];
            vf2 v2; v2.x = vr[4]; v2.y = vr[5];
            vf2 v3; v3.x = vr[6]; v3.y = vr[7];
            acc[0] += p2 * v0; acc[1] += p2 * v1;
            acc[2] += p2 * v2; acc[3] += p2 * v3;
            a8 += p * vr[8];
        }
    }
    // in-block merge of the 2 key-subhalves; [ks][elem][128] -> conflict-free
    int base = ks * 1280;
    sh[base + qt] = l;
    #pragma unroll
    for (int d = 0; d < 4; d++) {
        sh[base + (1 + 2 * d) * 128 + qt] = acc[d].x;
        sh[base + (2 + 2 * d) * 128 + qt] = acc[d].y;
    }
    sh[base + 9 * 128 + qt] = a8;
    __syncthreads();
    if (tid < 128) {
        float* pp = part + (size_t)kq * 1474560;
        int gidx = bh * 512 + qq * 128 + tid;
        pp[gidx] = sh[tid] + sh[1280 + tid];
        #pragma unroll
        for (int e = 1; e <= 9; e++)
            pp[e * 147456 + gidx] = sh[e * 128 + tid] + sh[1280 + e * 128 + tid];
    }
}

// ---------------- matin = (1-hw)*(h1@Wo1) + hw*h2 + tx ; merge fused, st1 fused ----------------
__global__ __launch_bounds__(256) void h1o_kernel(const float* __restrict__ apart,
                           const float* __restrict__ Wo1, const float* __restrict__ h2,
                           const float* __restrict__ txall, const float* __restrict__ hwp,
                           float* __restrict__ matin, float* __restrict__ st1) {
    __shared__ float rows_[64 * 84];
    __shared__ float Wl[84 * 84];
    __shared__ float ssum[81], ssq[81];
    int row0 = blockIdx.x * 64;
    int tid = threadIdx.x;
    if (tid < 81) { ssum[tid] = 0.0f; ssq[tid] = 0.0f; }
    // stage h1 rows: merge the 2 key-half partials inline
    for (int i = tid; i < 64 * 84; i += 256) {
        int r = i / 84, c = i % 84;
        float v = 0.0f;
        if (c < 81) {
            int row = row0 + r;             // b*512+s
            int b = row >> 9, s = row & 511;
            int h = c / 9, d = c % 9;
            int gidx = (b * 9 + h) * 512 + s;
            float L = apart[gidx] + apart[1474560 + gidx];
            float A = apart[(1 + d) * 147456 + gidx]
                    + apart[1474560 + (1 + d) * 147456 + gidx];
            v = A / L;
        }
        rows_[i] = v;
    }
    for (int i = tid; i < 84 * 84; i += 256) {
        int e = i / 84, c = i % 84;
        Wl[i] = (e < 81 && c < 81) ? Wo1[e * 81 + c] : 0.0f;
    }
    __syncthreads();
    float hw = hwp[0];
    float onemhw = 1.0f - hw;
    for (int o = tid; o < 336; o += 256) {
        int r4 = o / 21, cg = o % 21;
        int c0 = cg * 4;
        const float* rp = rows_ + r4 * 4 * 84;
        vf4 acc0 = 0.0f, acc1 = 0.0f, acc2 = 0.0f, acc3 = 0.0f;
        #pragma unroll 7
        for (int e = 0; e < 84; e += 4) {
            vf4 w0 = *(const vf4*)(Wl + (e + 0) * 84 + c0);
            vf4 w1 = *(const vf4*)(Wl + (e + 1) * 84 + c0);
            vf4 w2 = *(const vf4*)(Wl + (e + 2) * 84 + c0);
            vf4 w3 = *(const vf4*)(Wl + (e + 3) * 84 + c0);
            vf4 r0 = *(const vf4*)(rp + e);
            vf4 r1 = *(const vf4*)(rp + 84 + e);
            vf4 r2 = *(const vf4*)(rp + 168 + e);
            vf4 r3 = *(const vf4*)(rp + 252 + e);
            acc0 += r0[0] * w0 + r0[1] * w1 + r0[2] * w2 + r0[3] * w3;
            acc1 += r1[0] * w0 + r1[1] * w1 + r1[2] * w2 + r1[3] * w3;
            acc2 += r2[0] * w0 + r2[1] * w1 + r2[2] * w2 + r2[3] * w3;
            acc3 += r3[0] * w0 + r3[1] * w1 + r3[2] * w2 + r3[3] * w3;
        }
        vf4 av[4] = {acc0, acc1, acc2, acc3};
        #pragma unroll
        for (int cc = 0; cc < 4; cc++) {
            int col = c0 + cc;
            if (col < 81) {
                float ls = 0.0f, lq = 0.0f;
                #pragma unroll
                for (int rr = 0; rr < 4; rr++) {
                    int idx = (row0 + r4 * 4 + rr) * 81 + col;
                    float v = onemhw * av[rr][cc] + hw * h2[idx] + txall[idx];
                    matin[idx] = v;
                    ls += v; lq += v * v;
                }
                atomicAdd(&ssum[col], ls);
                atomicAdd(&ssq[col], lq);
            }
        }
    }
    __syncthreads();
    if (tid < 81) {
        atomicAdd(&st1[tid], ssum[tid]);
        atomicAdd(&st1[81 + tid], ssq[tid]);
    }
}

// ---------------- ff1: 64 rows x 64 cols/block, 4x4 tile ; fused st2 ----------------
__global__ __launch_bounds__(256) void ff1_kernel(const float* __restrict__ matin,
                           const float* __restrict__ st1, const float* __restrict__ g1,
                           const float* __restrict__ b1, const float* __restrict__ W,
                           const float* __restrict__ bias, float* __restrict__ f1,
                           float* __restrict__ st2) {
    __shared__ float rows_[64 * 84];
    __shared__ float Wl[84 * 64];       // rows 81..83 zero
    __shared__ float s2s[64], s2q[64];
    int row0 = blockIdx.x * 64;
    int cb = blockIdx.y * 64;
    int tid = threadIdx.x;
    const float invN = 1.0f / 16384.0f;
    if (tid < 64) { s2s[tid] = 0.0f; s2q[tid] = 0.0f; }
    for (int i = tid; i < 64 * 84; i += 256) {
        int c = i % 84;
        float v = 0.0f;
        if (c < 81) {
            float mean = st1[c] * invN;
            float var = st1[81 + c] * invN - mean * mean;
            v = (matin[(row0 + i / 84) * 81 + c] - mean) * rsqrtf(var + EPSV) * g1[c] + b1[c];
        }
        rows_[i] = v;
    }
    for (int i = tid; i < 84 * 64; i += 256) {
        int e = i >> 6, cc = i & 63;
        Wl[i] = (e < 81) ? W[e * 256 + cb + cc] : 0.0f;
    }
    __syncthreads();
    {
        int o = tid;                 // 256 tasks: 16 r-groups x 16 c-groups
        int r4 = o >> 4, cg = o & 15;
        int c0 = cg * 4;
        const float* rp = rows_ + r4 * 4 * 84;
        vf4 acc0 = 0.0f, acc1 = 0.0f, acc2 = 0.0f, acc3 = 0.0f;
        #pragma unroll 7
        for (int e = 0; e < 84; e += 4) {
            vf4 w0 = *(const vf4*)(Wl + ((e + 0) << 6) + c0);
            vf4 w1 = *(const vf4*)(Wl + ((e + 1) << 6) + c0);
            vf4 w2 = *(const vf4*)(Wl + ((e + 2) << 6) + c0);
            vf4 w3 = *(const vf4*)(Wl + ((e + 3) << 6) + c0);
            vf4 r0 = *(const vf4*)(rp + e);
            vf4 r1 = *(const vf4*)(rp + 84 + e);
            vf4 r2 = *(const vf4*)(rp + 168 + e);
            vf4 r3 = *(const vf4*)(rp + 252 + e);
            acc0 += r0[0] * w0 + r0[1] * w1 + r0[2] * w2 + r0[3] * w3;
            acc1 += r1[0] * w0 + r1[1] * w1 + r1[2] * w2 + r1[3] * w3;
            acc2 += r2[0] * w0 + r2[1] * w1 + r2[2] * w2 + r2[3] * w3;
            acc3 += r3[0] * w0 + r3[1] * w1 + r3[2] * w2 + r3[3] * w3;
        }
        vf4 bv = *(const vf4*)(bias + cb + c0);
        acc0 = __builtin_elementwise_max(acc0 + bv, (vf4)0.0f);
        acc1 = __builtin_elementwise_max(acc1 + bv, (vf4)0.0f);
        acc2 = __builtin_elementwise_max(acc2 + bv, (vf4)0.0f);
        acc3 = __builtin_elementwise_max(acc3 + bv, (vf4)0.0f);
        int base = (row0 + r4 * 4) * 256 + cb + c0;
        *(vf4*)(f1 + base)       = acc0;
        *(vf4*)(f1 + base + 256) = acc1;
        *(vf4*)(f1 + base + 512) = acc2;
        *(vf4*)(f1 + base + 768) = acc3;
        vf4 cs = acc0 + acc1 + acc2 + acc3;
        vf4 cq = acc0 * acc0 + acc1 * acc1 + acc2 * acc2 + acc3 * acc3;
        #pragma unroll
        for (int cc = 0; cc < 4; cc++) {
            atomicAdd(&s2s[c0 + cc], cs[cc]);
            atomicAdd(&s2q[c0 + cc], cq[cc]);
        }
    }
    __syncthreads();
    if (tid < 64) {
        atomicAdd(&st2[cb + tid], s2s[tid]);
        atomicAdd(&st2[256 + cb + tid], s2q[tid]);
    }
}

// ---------------- ff2: 32 rows/block, 4 K-quarter passes, 4x4 tile ; fused st3 ----------------
__global__ __launch_bounds__(256) void ff2_kernel(const float* __restrict__ f1,
                           const float* __restrict__ st2, const float* __restrict__ g2,
                           const float* __restrict__ b2, const float* __restrict__ W,
                           const float* __restrict__ bias, const float* __restrict__ matin,
                           const float* __restrict__ st1, const float* __restrict__ g1,
                           const float* __restrict__ b1, float* __restrict__ t3,
                           float* __restrict__ st3) {
    __shared__ float rows_[32 * 64];
    __shared__ float Wl[64 * 84];
    __shared__ float s3s[81], s3q[81];
    int row0 = blockIdx.x * 32;
    int tid = threadIdx.x;
    const float invN = 1.0f / 16384.0f;
    if (tid < 81) { s3s[tid] = 0.0f; s3q[tid] = 0.0f; }
    int o = tid;
    int r4 = o / 21, cg = o % 21;
    int c0 = cg * 4;
    bool active = (o < 168);
    vf4 acc0 = 0.0f, acc1 = 0.0f, acc2 = 0.0f, acc3 = 0.0f;
    for (int kq = 0; kq < 4; kq++) {
        __syncthreads();
        for (int i = tid; i < 32 * 64; i += 256) {
            int r = i >> 6, e = i & 63;
            int c = kq * 64 + e;
            float mean = st2[c] * invN;
            float var = st2[256 + c] * invN - mean * mean;
            rows_[i] = (f1[(row0 + r) * 256 + c] - mean) * rsqrtf(var + EPSV) * g2[c] + b2[c];
        }
        for (int i = tid; i < 64 * 84; i += 256) {
            int e = i / 84, c = i % 84;
            Wl[i] = (c < 81) ? W[(kq * 64 + e) * 81 + c] : 0.0f;
        }
        __syncthreads();
        if (active) {
            const float* rp = rows_ + r4 * 4 * 64;
            #pragma unroll 8
            for (int e = 0; e < 64; e += 4) {
                vf4 w0 = *(const vf4*)(Wl + (e + 0) * 84 + c0);
                vf4 w1 = *(const vf4*)(Wl + (e + 1) * 84 + c0);
                vf4 w2 = *(const vf4*)(Wl + (e + 2) * 84 + c0);
                vf4 w3 = *(const vf4*)(Wl + (e + 3) * 84 + c0);
                vf4 r0 = *(const vf4*)(rp + e);
                vf4 r1 = *(const vf4*)(rp + 64 + e);
                vf4 r2 = *(const vf4*)(rp + 128 + e);
                vf4 r3 = *(const vf4*)(rp + 192 + e);
                acc0 += r0[0] * w0 + r0[1] * w1 + r0[2] * w2 + r0[3] * w3;
                acc1 += r1[0] * w0 + r1[1] * w1 + r1[2] * w2 + r1[3] * w3;
                acc2 += r2[0] * w0 + r2[1] * w1 + r2[2] * w2 + r2[3] * w3;
                acc3 += r3[0] * w0 + r3[1] * w1 + r3[2] * w2 + r3[3] * w3;
            }
        }
    }
    if (active) {
        vf4 av[4] = {acc0, acc1, acc2, acc3};
        #pragma unroll
        for (int cc = 0; cc < 4; cc++) {
            int col = c0 + cc;
            if (col < 81) {
                float mean = st1[col] * invN;
                float var = st1[81 + col] * invN - mean * mean;
                float rstd = rsqrtf(var + EPSV);
                float bval = bias[col];
                float ls = 0.0f, lq = 0.0f;
                #pragma unroll
                for (int rr = 0; rr < 4; rr++) {
                    int idx = (row0 + r4 * 4 + rr) * 81 + col;
                    float ma = (matin[idx] - mean) * rstd * g1[col] + b1[col];
                    float v = ma + fmaxf(av[rr][cc] + bval, 0.0f);
                    t3[idx] = v;
                    ls += v; lq += v * v;
                }
                atomicAdd(&s3s[col], ls);
                atomicAdd(&s3q[col], lq);
            }
        }
    }
    __syncthreads();
    if (tid < 81) {
        atomicAdd(&st3[tid], s3s[tid]);
        atomicAdd(&st3[81 + tid], s3q[tid]);
    }
}

// ---------------- token_mm: u/v dual GEMM (64 rows/block, W-pass split, 4x4 tile) ----------------
__global__ __launch_bounds__(256) void token_mm(const float* __restrict__ t3,
                            const float* __restrict__ st3, const float* __restrict__ g3,
                            const float* __restrict__ b3, const float* __restrict__ tvw,
                            const float* __restrict__ beta1,
                            float* __restrict__ uv0, float* __restrict__ uv1) {
    __shared__ float rows_[64 * 84];
    __shared__ float Wl[84 * 84];
    int blk = blockIdx.x;            // 0..511
    int t = blk >> 8;
    int row0 = (blk & 255) * 64;
    const float* W = (t == 0) ? tvw : beta1;
    float* dst = (t == 0) ? uv0 : uv1;
    int tid = threadIdx.x;
    const float invN = 1.0f / 16384.0f;
    for (int i = tid; i < 64 * 84; i += 256) {
        int c = i % 84;
        float v = 0.0f;
        if (c < 81) {
            float mean = st3[c] * invN;
            float var = st3[81 + c] * invN - mean * mean;
            v = (t3[(row0 + i / 84) * 81 + c] - mean) * rsqrtf(var + EPSV) * g3[c] + b3[c];
        }
        rows_[i] = v;
    }
    for (int i = tid; i < 84 * 84; i += 256) {
        int e = i / 84, c = i % 84;
        Wl[i] = (e < 81 && c < 81) ? W[e * 81 + c] : 0.0f;
    }
    __syncthreads();
    for (int o = tid; o < 336; o += 256) {
        int r4 = o / 21, cg = o % 21;
        int c0 = cg * 4;
        const float* rp = rows_ + r4 * 4 * 84;
        vf4 acc0 = 0.0f, acc1 = 0.0f, acc2 = 0.0f, acc3 = 0.0f;
        #pragma unroll 7
        for (int e = 0; e < 84; e += 4) {
            vf4 w0 = *(const vf4*)(Wl + (e + 0) * 84 + c0);
            vf4 w1 = *(const vf4*)(Wl + (e + 1) * 84 + c0);
            vf4 w2 = *(const vf4*)(Wl + (e + 2) * 84 + c0);
            vf4 w3 = *(const vf4*)(Wl + (e + 3) * 84 + c0);
            vf4 r0 = *(const vf4*)(rp + e);
            vf4 r1 = *(const vf4*)(rp + 84 + e);
            vf4 r2 = *(const vf4*)(rp + 168 + e);
            vf4 r3 = *(const vf4*)(rp + 252 + e);
            acc0 += r0[0] * w0 + r0[1] * w1 + r0[2] * w2 + r0[3] * w3;
            acc1 += r1[0] * w0 + r1[1] * w1 + r1[2] * w2 + r1[3] * w3;
            acc2 += r2[0] * w0 + r2[1] * w1 + r2[2] * w2 + r2[3] * w3;
            acc3 += r3[0] * w0 + r3[1] * w1 + r3[2] * w2 + r3[3] * w3;
        }
        vf4 av[4] = {acc0, acc1, acc2, acc3};
        #pragma unroll
        for (int cc = 0; cc < 4; cc++) {
            int col = c0 + cc;
            if (col < 81) {
                #pragma unroll
                for (int rr = 0; rr < 4; rr++)
                    dst[(row0 + r4 * 4 + rr) * 81 + col] = av[rr][cc];
            }
        }
    }
}

// ---------------- token_pool: softmax-pool over 81, 32 rows/block, 8 lanes/row ----------------
__global__ __launch_bounds__(256) void token_pool(const float* __restrict__ uv0,
                             const float* __restrict__ uv1, const float* __restrict__ tvb,
                             const float* __restrict__ basel, const float* __restrict__ a1p,
                             const float* __restrict__ a2p, float* __restrict__ fea) {
    int tid = threadIdx.x;
    int r = tid >> 3, j = tid & 7;
    int row = blockIdx.x * 32 + r;
    int base = row * 81;
    float u[11], v[11];
    #pragma unroll
    for (int dd = 0; dd < 11; dd++) {
        int d = j + dd * 8;
        if (d < 81) {
            u[dd] = uv0[base + d] + tvb[d];
            v[dd] = uv1[base + d];
        } else {
            u[dd] = 0.0f; v[dd] = -1e30f;
        }
    }
    float mx = -1e30f;
    #pragma unroll
    for (int dd = 0; dd < 11; dd++) mx = fmaxf(mx, v[dd]);
    #pragma unroll
    for (int msk = 1; msk < 8; msk <<= 1) mx = fmaxf(mx, __shfl_xor(mx, msk, 8));
    float sp = 0.0f, sup = 0.0f;
    #pragma unroll
    for (int dd = 0; dd < 11; dd++) {
        float p = __expf(v[dd] - mx);
        sp += p; sup += u[dd] * p;
    }
    #pragma unroll
    for (int msk = 1; msk < 8; msk <<= 1) {
        sp  += __shfl_xor(sp, msk, 8);
        sup += __shfl_xor(sup, msk, 8);
    }
    if (j == 0) {
        int b = row >> 9, s = row & 511;
        fea[row] = a1p[0] * (sup / sp) + a2p[0] * basel[b * 2048 + s * 4];
    }
}

// ---------------- fc1: relu(fea @ W + b), fused st4 ----------------
__global__ void fc1_kernel(const float* __restrict__ in, const float* __restrict__ W,
                           const float* __restrict__ bias, float* __restrict__ out,
                           float* __restrict__ st) {
    int idx = blockIdx.x * blockDim.x + threadIdx.x;
    if (idx >= 32 * 512) return;
    int b = idx >> 9, j = idx & 511;
    float acc = bias[j];
    const float* ip = in + (b << 9);
    #pragma unroll 8
    for (int k = 0; k < 512; k++) acc += ip[k] * W[k * 512 + j];
    acc = fmaxf(acc, 0.0f);
    out[idx] = acc;
    atomicAdd(&st[j], acc);
    atomicAdd(&st[512 + j], acc * acc);
}

// ---------------- fc2: relu(bn(fch1) @ W + b), fused st5 ----------------
__global__ __launch_bounds__(256) void fc2_kernel(const float* __restrict__ in,
                           const float* __restrict__ st4, const float* __restrict__ g,
                           const float* __restrict__ bb, const float* __restrict__ W,
                           const float* __restrict__ bias, float* __restrict__ out,
                           float* __restrict__ st5) {
    __shared__ float scale[512], shift[512];
    int tid = threadIdx.x;
    for (int k = tid; k < 512; k += 256) {
        float mean = st4[k] * (1.0f / 32.0f);
        float var = st4[512 + k] * (1.0f / 32.0f) - mean * mean;
        float sc_ = rsqrtf(var + EPSV) * g[k];
        scale[k] = sc_;
        shift[k] = bb[k] - mean * sc_;
    }
    __syncthreads();
    int idx = blockIdx.x * 256 + tid;
    if (idx >= 32 * 256) return;
    int b = idx >> 8, j = idx & 255;
    float acc = bias[j];
    const float* ip = in + (b << 9);
    #pragma unroll 8
    for (int k = 0; k < 512; k++) acc += (ip[k] * scale[k] + shift[k]) * W[k * 256 + j];
    acc = fmaxf(acc, 0.0f);
    out[idx] = acc;
    atomicAdd(&st5[j], acc);
    atomicAdd(&st5[256 + j], acc * acc);
}

// ---------------- fc3: tanh(bn(fch2) @ W + b) ----------------
__global__ void fc3_kernel(const float* __restrict__ in, const float* __restrict__ st5,
                           const float* __restrict__ g, const float* __restrict__ bb,
                           const float* __restrict__ W, const float* __restrict__ bias,
                           float* __restrict__ out) {
    __shared__ float scale[256], shift[256];
    int tid = threadIdx.x;   // 128
    for (int k = tid; k < 256; k += 128) {
        float mean = st5[k] * (1.0f / 32.0f);
        float var = st5[256 + k] * (1.0f / 32.0f) - mean * mean;
        float sc_ = rsqrtf(var + EPSV) * g[k];
        scale[k] = sc_;
        shift[k] = bb[k] - mean * sc_;
    }
    __syncthreads();
    int b = tid >> 2, j = tid & 3;
    float acc = bias[j];
    const float* ip = in + (b << 8);
    #pragma unroll 8
    for (int k = 0; k < 256; k++) acc += (ip[k] * scale[k] + shift[k]) * W[k * 4 + j];
    out[tid] = tanhf(acc);
}

// =======================================================================
extern "C" void kernel_launch(void* const* d_in, const int* in_sizes, int n_in,
                              void* d_out, int out_size, void* d_ws, size_t ws_size,
                              hipStream_t stream) {
    const float* x       = (const float*)d_in[0];
    const float* basel   = (const float*)d_in[1];
    const float* cali    = (const float*)d_in[2];
    const float* Wq      = (const float*)d_in[3];
    const float* Wk      = (const float*)d_in[4];
    const float* Wq2     = (const float*)d_in[5];
    const float* Wk2     = (const float*)d_in[6];
    const float* Wv2     = (const float*)d_in[7];
    const float* Cv      = (const float*)d_in[8];
    const float* Wo1     = (const float*)d_in[9];
    const float* Wo2     = (const float*)d_in[10];
    const float* corr_w  = (const float*)d_in[11];
    const float* h_w     = (const float*)d_in[12];
    const float* corr    = (const float*)d_in[13];
    const float* g1      = (const float*)d_in[14];
    const float* b1      = (const float*)d_in[15];
    const float* ff1_w   = (const float*)d_in[16];
    const float* ff1_b   = (const float*)d_in[17];
    const float* g2      = (const float*)d_in[18];
    const float* b2      = (const float*)d_in[19];
    const float* ff2_w   = (const float*)d_in[20];
    const float* ff2_b   = (const float*)d_in[21];
    const float* g3      = (const float*)d_in[22];
    const float* b3      = (const float*)d_in[23];
    const float* tvw     = (const float*)d_in[24];
    const float* tvb     = (const float*)d_in[25];
    const float* beta1   = (const float*)d_in[26];
    const float* a1      = (const float*)d_in[27];
    const float* a2      = (const float*)d_in[28];
    const float* fc1_w   = (const float*)d_in[29];
    const float* fc1_b   = (const float*)d_in[30];
    const float* bnf1_g  = (const float*)d_in[31];
    const float* bnf1_b  = (const float*)d_in[32];
    const float* fc2_w   = (const float*)d_in[33];
    const float* fc2_b   = (const float*)d_in[34];
    const float* bnf2_g  = (const float*)d_in[35];
    const float* bnf2_b  = (const float*)d_in[36];
    const float* fc3_w   = (const float*)d_in[37];
    const float* fc3_b   = (const float*)d_in[38];
    float* out = (float*)d_out;
    float* ws = (float*)d_ws;

    // ---- workspace layout (float offsets) ----
    const size_t SCAL  = 0;         // 2
    const size_t PART  = 16;        // 128
    const size_t ST1   = 512;       // 162
    const size_t ST2   = 768;       // 512
    const size_t ST3   = 1536;      // 162
    const size_t ST4   = 1792;      // 1024
    const size_t ST5   = 2880;      // 512
    const size_t FEA   = 4096;      // 16384
    const size_t FCH1  = 20480;     // 16384
    const size_t FCH2  = 36864;     // 8192
    const size_t PEO   = 45056;     // 41472
    const size_t TX    = 90112;     // 1990656
    const size_t Q2O   = 2080768;   // 1327104
    const size_t KCO   = 3407872;   // 1990656   (reused: Qs)
    const size_t VCO   = 5398528;   // 1990656   (reused: Ks)
    const size_t TMP2  = 7389184;   // 1327104   (reused: matin, then uv0)
    const size_t H2O   = 8716288;   // 1327104   (reused: t3)
    const size_t XHO   = 10043392;  // 1327104   (xh, dead after qks -> uv1)
    const size_t BIASO = 11370496;  // 262144    (EBT)
    const size_t F1O   = 11632640;  // 4194304   (f1; also attn1 partials 2949120)

    float* scal  = ws + SCAL;
    float* part  = ws + PART;
    float* st1   = ws + ST1;
    float* st2   = ws + ST2;
    float* st3   = ws + ST3;
    float* st4   = ws + ST4;
    float* st5   = ws + ST5;
    float* fea   = ws + FEA;
    float* fch1  = ws + FCH1;
    float* fch2  = ws + FCH2;
    float* pe    = ws + PEO;
    float* txall = ws + TX;
    float* Q2    = ws + Q2O;
    float* Kc    = ws + KCO;
    float* Vc    = ws + VCO;
    float* tmp2  = ws + TMP2;
    float* h2    = ws + H2O;
    float* xh    = ws + XHO;
    float* ebT   = ws + BIASO;
    float* f1    = ws + F1O;
    float* Qs    = Kc;     // reuse
    float* Ks    = Vc;     // reuse
    float* matin = tmp2;   // reuse (dead after ff2 -> uv0)
    float* t3    = h2;     // reuse
    float* apart = f1;     // attn1 partials live in the (not-yet-used) f1 region
    float* uv0   = tmp2;   // token u plane (matin dead after ff2)
    float* uv1   = xh;     // token v plane (xh dead after qks)

    // zero scal/part/stats region — capture-safe
    hipMemsetAsync(ws, 0, 4096 * sizeof(float), stream);

    minmax_part<<<64, 256, 0, stream>>>(x, part);
    minmax_fin<<<1, 64, 0, stream>>>(part, scal);

    pe_kernel<<<(512 * 81 + 255) / 256, 256, 0, stream>>>(pe);

    tokenize_kernel<<<(48 * 512 * 81 + 255) / 256, 256, 0, stream>>>(x, cali, scal, pe, txall);

    qkv2_kernel<<<1024, 256, 0, stream>>>(txall, Wq2, Wk2, Wv2, Q2, Kc, Vc);

    attn2_kernel<<<(512 * 9 * 32) / 256, 256, 0, stream>>>(Q2, Kc, Vc, tmp2);

    h2xh_kernel<<<256, 256, 0, stream>>>(tmp2, Wo2, txall, h2, xh);

    qks_kernel<<<512, 256, 0, stream>>>(xh, Wq, Wk, Qs, Ks);

    biasmm_kernel<<<dim3(16, 16), dim3(16, 16), 0, stream>>>(corr, Cv, corr_w, ebT);

    attn1_kernel<<<2304, 256, 0, stream>>>(Qs, Ks, ebT, corr_w, apart);

    h1o_kernel<<<256, 256, 0, stream>>>(apart, Wo1, h2, txall, h_w, matin, st1);

    ff1_kernel<<<dim3(256, 4), 256, 0, stream>>>(matin, st1, g1, b1, ff1_w, ff1_b, f1, st2);

    ff2_kernel<<<512, 256, 0, stream>>>(f1, st2, g2, b2, ff2_w, ff2_b,
                                        matin, st1, g1, b1, t3, st3);

    token_mm<<<512, 256, 0, stream>>>(t3, st3, g3, b3, tvw, beta1, uv0, uv1);
    token_pool<<<512, 256, 0, stream>>>(uv0, uv1, tvb, basel, a1, a2, fea);

    fc1_kernel<<<64, 256, 0, stream>>>(fea, fc1_w, fc1_b, fch1, st4);

    fc2_kernel<<<32, 256, 0, stream>>>(fch1, st4, bnf1_g, bnf1_b, fc2_w, fc2_b, fch2, st5);

    fc3_kernel<<<1, 128, 0, stream>>>(fch2, st5, bnf2_g, bnf2_b, fc3_w, fc3_b, out);
}

// Round 15
// 481.223 us; speedup vs baseline: 1.1836x; 1.1836x over previous
//
#include <hip/hip_runtime.h>
#include <hip/hip_bf16.h>
#include <math.h>

#define EPSV 1e-5f

typedef float vf2 __attribute__((ext_vector_type(2)));
typedef float vf4 __attribute__((ext_vector_type(4)));

// ---------------- sizes ----------------
// B=32 Bc=16 L=2048 TOKEN=40 STRIDE=4 D=81 H=9 dk=9 S=512 FF=256 FC1=512 FC2=256 Y=4

// ---------------- minmax: two-stage ----------------
__global__ void minmax_part(const float* __restrict__ x, float* __restrict__ part) {
    __shared__ float smin[256], smax[256];
    int tid = threadIdx.x;
    float mn = 1e30f, mx = -1e30f;
    for (int i = blockIdx.x * 256 + tid; i < 32 * 2008; i += 64 * 256) {
        int b = i / 2008, c = i % 2008 + 20;
        float v = x[b * 2048 + c];
        mn = fminf(mn, v); mx = fmaxf(mx, v);
    }
    smin[tid] = mn; smax[tid] = mx; __syncthreads();
    for (int off = 128; off > 0; off >>= 1) {
        if (tid < off) { smin[tid] = fminf(smin[tid], smin[tid + off]); smax[tid] = fmaxf(smax[tid], smax[tid + off]); }
        __syncthreads();
    }
    if (tid == 0) { part[blockIdx.x] = smin[0]; part[64 + blockIdx.x] = smax[0]; }
}

__global__ void minmax_fin(const float* __restrict__ part, float* __restrict__ scal) {
    __shared__ float smn[64], smx[64];
    int tid = threadIdx.x;
    smn[tid] = part[tid]; smx[tid] = part[64 + tid]; __syncthreads();
    for (int off = 32; off > 0; off >>= 1) {
        if (tid < off) { smn[tid] = fminf(smn[tid], smn[tid + off]); smx[tid] = fmaxf(smx[tid], smx[tid + off]); }
        __syncthreads();
    }
    if (tid == 0) { scal[0] = smn[0]; scal[1] = smx[0] - smn[0]; }
}

// ---------------- PE table (512 x 81) ----------------
__global__ void pe_kernel(float* __restrict__ pe) {
    int idx = blockIdx.x * blockDim.x + threadIdx.x;
    if (idx >= 512 * 81) return;
    int d = idx % 81, s = idx / 81;
    int j = d >> 1;
    float dv = __expf(-9.210340371976184f * (2.0f * (float)j) / 81.0f);
    float ang = (float)s * dv;
    pe[idx] = (d & 1) ? cosf(ang) : sinf(ang);
}

// ---------------- tokenize + add PE ----------------
__global__ void tokenize_kernel(const float* __restrict__ x, const float* __restrict__ cali,
                                const float* __restrict__ scal, const float* __restrict__ pe,
                                float* __restrict__ txall) {
    int idx = blockIdx.x * blockDim.x + threadIdx.x;
    if (idx >= 48 * 512 * 81) return;
    int d = idx % 81;
    int s = (idx / 81) % 512;
    int r = idx / (81 * 512);
    float xm = scal[0], inv_xs = 1.0f / scal[1];
    int oc = s * 4 + d - 40;
    float val = 0.0f;
    if (oc >= 0 && oc < 2048) {
        float sv = (r < 32) ? x[r * 2048 + oc] : cali[(r - 32) * 2048 + oc];
        val = (sv - xm) * inv_xs;
    }
    txall[idx] = val + pe[s * 81 + d];
}

// ======== 4x4-tile 81->81 GEMM pieces (rows stride 84, W [e][col] stride 84) ========

// ---------------- qkv2: 64 rows/block, W-pass split (1024 blocks), 4x4 tile ----------------
__global__ __launch_bounds__(256) void qkv2_kernel(const float* __restrict__ txall,
                            const float* __restrict__ Wq2, const float* __restrict__ Wk2,
                            const float* __restrict__ Wv2,
                            float* __restrict__ Q2, float* __restrict__ Kc, float* __restrict__ Vc) {
    __shared__ float rows_[64 * 84];
    __shared__ float Wl[84 * 84];
    int blk = blockIdx.x;            // 0..1023
    int t, rb;
    if (blk < 256)      { t = 0; rb = blk; }
    else if (blk < 640) { t = 1; rb = blk - 256; }
    else                { t = 2; rb = blk - 640; }
    int row0 = rb * 64;
    int k = row0 >> 9;
    int s0 = row0 & 511;
    const float* W = (t == 0) ? Wq2 : (t == 1) ? Wk2 : Wv2;
    int tid = threadIdx.x;
    for (int i = tid; i < 64 * 84; i += 256) {
        int c = i % 84;
        rows_[i] = (c < 81) ? txall[(row0 + i / 84) * 81 + c] : 0.0f;
    }
    for (int i = tid; i < 84 * 84; i += 256) {
        int e = i / 84, hd = i % 84;
        Wl[i] = (e < 81 && hd < 81) ? W[(hd / 9) * 729 + e * 9 + (hd % 9)] : 0.0f;
    }
    __syncthreads();
    for (int o = tid; o < 336; o += 256) {
        int r4 = o / 21, cg = o % 21;
        int c0 = cg * 4;
        const float* rp = rows_ + r4 * 4 * 84;
        vf4 acc0 = 0.0f, acc1 = 0.0f, acc2 = 0.0f, acc3 = 0.0f;
        #pragma unroll 7
        for (int e = 0; e < 84; e += 4) {
            vf4 w0 = *(const vf4*)(Wl + (e + 0) * 84 + c0);
            vf4 w1 = *(const vf4*)(Wl + (e + 1) * 84 + c0);
            vf4 w2 = *(const vf4*)(Wl + (e + 2) * 84 + c0);
            vf4 w3 = *(const vf4*)(Wl + (e + 3) * 84 + c0);
            vf4 r0 = *(const vf4*)(rp + e);
            vf4 r1 = *(const vf4*)(rp + 84 + e);
            vf4 r2 = *(const vf4*)(rp + 168 + e);
            vf4 r3 = *(const vf4*)(rp + 252 + e);
            acc0 += r0[0] * w0 + r0[1] * w1 + r0[2] * w2 + r0[3] * w3;
            acc1 += r1[0] * w0 + r1[1] * w1 + r1[2] * w2 + r1[3] * w3;
            acc2 += r2[0] * w0 + r2[1] * w1 + r2[2] * w2 + r2[3] * w3;
            acc3 += r3[0] * w0 + r3[1] * w1 + r3[2] * w2 + r3[3] * w3;
        }
        vf4 av[4] = {acc0, acc1, acc2, acc3};
        #pragma unroll
        for (int cc = 0; cc < 4; cc++) {
            int col = c0 + cc;
            if (col < 81) {
                int h = col / 9, d = col % 9;
                #pragma unroll
                for (int rr = 0; rr < 4; rr++) {
                    int s = s0 + r4 * 4 + rr;
                    if (t == 0)      Q2[((s * 9 + h) * 32 + k) * 9 + d] = av[rr][cc];
                    else if (t == 1) Kc[((s * 9 + h) * 48 + k) * 9 + d] = av[rr][cc];
                    else             Vc[((s * 9 + h) * 48 + k) * 9 + d] = av[rr][cc];
                }
            }
        }
    }
}

// ---------------- attention-2 (masked: key==b or key>=32), no-max softmax (exp2) ----------------
__global__ void attn2_kernel(const float* __restrict__ Q2, const float* __restrict__ Kc,
                             const float* __restrict__ Vc, float* __restrict__ tmp2) {
    int tid = blockIdx.x * blockDim.x + threadIdx.x;
    if (tid >= 512 * 9 * 32) return;
    int b = tid & 31;
    int h = (tid >> 5) % 9;
    int s = tid / 288;
    const float* q = Q2 + ((s * 9 + h) * 32 + b) * 9;
    float qr[9];
    const float c2 = 1.4426950408889634f / 3.0f;   // log2e / 3
    #pragma unroll
    for (int d = 0; d < 9; d++) qr[d] = q[d] * c2;
    const float* Kb = Kc + (s * 9 + h) * 48 * 9;
    const float* Vb = Vc + (s * 9 + h) * 48 * 9;
    float l = 0.0f, outv[9];
    #pragma unroll
    for (int d = 0; d < 9; d++) outv[d] = 0.0f;
    #pragma unroll
    for (int j = 0; j < 17; j++) {
        int k = (j == 0) ? b : 31 + j;
        const float* kp = Kb + k * 9;
        float acc = 0.0f;
        #pragma unroll
        for (int d = 0; d < 9; d++) acc += qr[d] * kp[d];
        float p = exp2f(acc);
        l += p;
        const float* vp = Vb + k * 9;
        #pragma unroll
        for (int d = 0; d < 9; d++) outv[d] += p * vp[d];
    }
    float invl = 1.0f / l;
    float* op = tmp2 + (b * 512 + s) * 81 + h * 9;
    #pragma unroll
    for (int d = 0; d < 9; d++) op[d] = outv[d] * invl;
}

// ---------------- h2 = tmp2 @ Wo2 ; xh = tx + h2  (64 rows/block, 4x4 tile) ----------------
__global__ __launch_bounds__(256) void h2xh_kernel(const float* __restrict__ tmp2,
                            const float* __restrict__ Wo2, const float* __restrict__ txall,
                            float* __restrict__ h2, float* __restrict__ xh) {
    __shared__ float rows_[64 * 84];
    __shared__ float Wl[84 * 84];
    int row0 = blockIdx.x * 64;
    int tid = threadIdx.x;
    for (int i = tid; i < 64 * 84; i += 256) {
        int c = i % 84;
        rows_[i] = (c < 81) ? tmp2[(row0 + i / 84) * 81 + c] : 0.0f;
    }
    for (int i = tid; i < 84 * 84; i += 256) {
        int e = i / 84, c = i % 84;
        Wl[i] = (e < 81 && c < 81) ? Wo2[e * 81 + c] : 0.0f;
    }
    __syncthreads();
    for (int o = tid; o < 336; o += 256) {
        int r4 = o / 21, cg = o % 21;
        int c0 = cg * 4;
        const float* rp = rows_ + r4 * 4 * 84;
        vf4 acc0 = 0.0f, acc1 = 0.0f, acc2 = 0.0f, acc3 = 0.0f;
        #pragma unroll 7
        for (int e = 0; e < 84; e += 4) {
            vf4 w0 = *(const vf4*)(Wl + (e + 0) * 84 + c0);
            vf4 w1 = *(const vf4*)(Wl + (e + 1) * 84 + c0);
            vf4 w2 = *(const vf4*)(Wl + (e + 2) * 84 + c0);
            vf4 w3 = *(const vf4*)(Wl + (e + 3) * 84 + c0);
            vf4 r0 = *(const vf4*)(rp + e);
            vf4 r1 = *(const vf4*)(rp + 84 + e);
            vf4 r2 = *(const vf4*)(rp + 168 + e);
            vf4 r3 = *(const vf4*)(rp + 252 + e);
            acc0 += r0[0] * w0 + r0[1] * w1 + r0[2] * w2 + r0[3] * w3;
            acc1 += r1[0] * w0 + r1[1] * w1 + r1[2] * w2 + r1[3] * w3;
            acc2 += r2[0] * w0 + r2[1] * w1 + r2[2] * w2 + r2[3] * w3;
            acc3 += r3[0] * w0 + r3[1] * w1 + r3[2] * w2 + r3[3] * w3;
        }
        vf4 av[4] = {acc0, acc1, acc2, acc3};
        #pragma unroll
        for (int cc = 0; cc < 4; cc++) {
            int col = c0 + cc;
            if (col < 81) {
                #pragma unroll
                for (int rr = 0; rr < 4; rr++) {
                    int idx = (row0 + r4 * 4 + rr) * 81 + col;
                    float v = av[rr][cc];
                    h2[idx] = v;
                    xh[idx] = txall[idx] + v;
                }
            }
        }
    }
}

// ---------------- Qs/Ks (Vs == Qs): 64 rows/block, W-pass split (512 blocks), 4x4 ----------------
__global__ __launch_bounds__(256) void qks_kernel(const float* __restrict__ xh,
                           const float* __restrict__ Wq, const float* __restrict__ Wk,
                           float* __restrict__ Qs, float* __restrict__ Ks) {
    __shared__ float rows_[64 * 84];
    __shared__ float Wl[84 * 84];
    int blk = blockIdx.x;            // 0..511
    int t = blk >> 8;                // 0: Q, 1: K
    int rb = blk & 255;
    int row0 = rb * 64;
    int b = row0 >> 9;
    int s0 = row0 & 511;
    const float* W = (t == 0) ? Wq : Wk;
    int tid = threadIdx.x;
    for (int i = tid; i < 64 * 84; i += 256) {
        int c = i % 84;
        rows_[i] = (c < 81) ? xh[(row0 + i / 84) * 81 + c] : 0.0f;
    }
    for (int i = tid; i < 84 * 84; i += 256) {
        int e = i / 84, hd = i % 84;
        Wl[i] = (e < 81 && hd < 81) ? W[(hd / 9) * 729 + e * 9 + (hd % 9)] : 0.0f;
    }
    __syncthreads();
    float* dst = (t == 0) ? Qs : Ks;
    for (int o = tid; o < 336; o += 256) {
        int r4 = o / 21, cg = o % 21;
        int c0 = cg * 4;
        const float* rp = rows_ + r4 * 4 * 84;
        vf4 acc0 = 0.0f, acc1 = 0.0f, acc2 = 0.0f, acc3 = 0.0f;
        #pragma unroll 7
        for (int e = 0; e < 84; e += 4) {
            vf4 w0 = *(const vf4*)(Wl + (e + 0) * 84 + c0);
            vf4 w1 = *(const vf4*)(Wl + (e + 1) * 84 + c0);
            vf4 w2 = *(const vf4*)(Wl + (e + 2) * 84 + c0);
            vf4 w3 = *(const vf4*)(Wl + (e + 3) * 84 + c0);
            vf4 r0 = *(const vf4*)(rp + e);
            vf4 r1 = *(const vf4*)(rp + 84 + e);
            vf4 r2 = *(const vf4*)(rp + 168 + e);
            vf4 r3 = *(const vf4*)(rp + 252 + e);
            acc0 += r0[0] * w0 + r0[1] * w1 + r0[2] * w2 + r0[3] * w3;
            acc1 += r1[0] * w0 + r1[1] * w1 + r1[2] * w2 + r1[3] * w3;
            acc2 += r2[0] * w0 + r2[1] * w1 + r2[2] * w2 + r2[3] * w3;
            acc3 += r3[0] * w0 + r3[1] * w1 + r3[2] * w2 + r3[3] * w3;
        }
        vf4 av[4] = {acc0, acc1, acc2, acc3};
        #pragma unroll
        for (int cc = 0; cc < 4; cc++) {
            int col = c0 + cc;
            if (col < 81) {
                int h = col / 9, d = col % 9;
                #pragma unroll
                for (int rr = 0; rr < 4; rr++)
                    dst[((b * 9 + h) * 512 + (s0 + r4 * 4 + rr)) * 9 + d] = av[rr][cc];
            }
        }
    }
}

// ---------------- EBT[t*512+s] = exp(cw * (corr @ Cv)^T[t][s] / sqrt(S)) ----------------
__global__ __launch_bounds__(256) void biasmm_kernel(const float* __restrict__ corr,
                              const float* __restrict__ Cv, const float* __restrict__ cwp,
                              float* __restrict__ ebT) {
    __shared__ float As[32][33];
    __shared__ float Bs[32][33];
    int tx = threadIdx.x, ty = threadIdx.y;   // 16 x 16
    int tid = ty * 16 + tx;
    int t0 = blockIdx.y * 32, s0 = blockIdx.x * 32;
    float a00 = 0, a01 = 0, a10 = 0, a11 = 0;
    for (int k0 = 0; k0 < 512; k0 += 32) {
        for (int ii = tid; ii < 1024; ii += 256) {
            int r = ii >> 5, c = ii & 31;
            As[r][c] = Cv[(k0 + r) * 512 + t0 + c];
            Bs[r][c] = corr[(s0 + r) * 512 + k0 + c];
        }
        __syncthreads();
        #pragma unroll
        for (int kk = 0; kk < 32; kk++) {
            float b0 = Bs[tx][kk], b1 = Bs[tx + 16][kk];
            float c0 = As[kk][ty], c1 = As[kk][ty + 16];
            a00 += c0 * b0; a01 += c0 * b1; a10 += c1 * b0; a11 += c1 * b1;
        }
        __syncthreads();
    }
    float cws = cwp[0] * 0.04419417382415922f;   // cw / sqrt(512)
    ebT[(t0 + ty) * 512 + s0 + tx]            = __expf(a00 * cws);
    ebT[(t0 + ty) * 512 + s0 + tx + 16]       = __expf(a01 * cws);
    ebT[(t0 + ty + 16) * 512 + s0 + tx]       = __expf(a10 * cws);
    ebT[(t0 + ty + 16) * 512 + s0 + tx + 16]  = __expf(a11 * cws);
}

// ---------------- attention-1: no-max softmax (exp2), packed fp32, no LDS ----------------
// p = exp2(c1*log2e * q.k) * EB[key][q]
// grid 1152: bh = blk>>2, qhalf = (blk>>1)&1, kq = blk&1 (256-key half) -- ALL block-uniform
// K/V rows wave-uniform -> scalar loads; eb[8] batch prefetch for 8-deep VMEM MLP
// partials (l, acc[9]) in planes: part[kq*1474560 + e*147456 + (bh*512+q)]
__global__ __launch_bounds__(256) void attn1_kernel(const float* __restrict__ Qs,
                                                    const float* __restrict__ Ks,
                                                    const float* __restrict__ ebT,
                                                    const float* __restrict__ cwp,
                                                    float* __restrict__ part) {
    int blk = blockIdx.x;          // 0..1151
    int bh = blk >> 2;             // b*9+h
    int qhalf = (blk >> 1) & 1;
    int kq = blk & 1;
    int tid = threadIdx.x;
    const float* Kb = Ks + bh * 4608;
    const float* Qb = Qs + bh * 4608;
    int q = qhalf * 256 + tid;
    float c1 = (1.0f - cwp[0]) * (1.4426950408889634f / 3.0f);   // fold log2e
    vf2 qv[4];
    float q8;
    {
        const float* qp = Qb + q * 9;
        #pragma unroll
        for (int d = 0; d < 4; d++) {
            vf2 t; t.x = c1 * qp[2 * d]; t.y = c1 * qp[2 * d + 1];
            qv[d] = t;
        }
        q8 = c1 * qp[8];
    }
    float l = 0.0f, a8 = 0.0f;
    vf2 acc[4];
    #pragma unroll
    for (int d = 0; d < 4; d++) acc[d] = (vf2)0.0f;
    int k0 = kq * 256;             // block-uniform -> K/V scalar loads preserved
    const float* ebp = ebT + q;
    for (int t0 = k0; t0 < k0 + 256; t0 += 8) {
        float eb[8];
        #pragma unroll
        for (int j = 0; j < 8; j++) eb[j] = ebp[(t0 + j) << 9];   // 8 loads in flight
        #pragma unroll
        for (int j = 0; j < 8; j++) {
            const float* kr = Kb + (t0 + j) * 9;   // wave-uniform -> scalar loads
            const float* vr = Qb + (t0 + j) * 9;   // Vs == Qs
            vf2 k0v; k0v.x = kr[0]; k0v.y = kr[1];
            vf2 k1v; k1v.x = kr[2]; k1v.y = kr[3];
            vf2 k2v; k2v.x = kr[4]; k2v.y = kr[5];
            vf2 k3v; k3v.x = kr[6]; k3v.y = kr[7];
            vf2 u2 = qv[0] * k0v + qv[1] * k1v + qv[2] * k2v + qv[3] * k3v;
            float u = u2.x + u2.y + q8 * kr[8];
            float p = exp2f(u) * eb[j];
            l += p;
            vf2 p2; p2.x = p; p2.y = p;
            vf2 v0; v0.x = vr[0]; v0.y = vr[1];
            vf2 v1; v1.x = vr[2]; v1.y = vr[3];
            vf2 v2; v2.x = vr[4]; v2.y = vr[5];
            vf2 v3; v3.x = vr[6]; v3.y = vr[7];
            acc[0] += p2 * v0; acc[1] += p2 * v1;
            acc[2] += p2 * v2; acc[3] += p2 * v3;
            a8 += p * vr[8];
        }
    }
    float* pp = part + (size_t)kq * 1474560;
    int gidx = bh * 512 + q;
    pp[gidx] = l;
    #pragma unroll
    for (int d = 0; d < 4; d++) {
        pp[(1 + 2 * d) * 147456 + gidx] = acc[d].x;
        pp[(2 + 2 * d) * 147456 + gidx] = acc[d].y;
    }
    pp[9 * 147456 + gidx] = a8;
}

// ---------------- matin = (1-hw)*(h1@Wo1) + hw*h2 + tx ; merge fused, st1 fused ----------------
__global__ __launch_bounds__(256) void h1o_kernel(const float* __restrict__ apart,
                           const float* __restrict__ Wo1, const float* __restrict__ h2,
                           const float* __restrict__ txall, const float* __restrict__ hwp,
                           float* __restrict__ matin, float* __restrict__ st1) {
    __shared__ float rows_[64 * 84];
    __shared__ float Wl[84 * 84];
    __shared__ float ssum[81], ssq[81];
    int row0 = blockIdx.x * 64;
    int tid = threadIdx.x;
    if (tid < 81) { ssum[tid] = 0.0f; ssq[tid] = 0.0f; }
    // stage h1 rows: merge the 2 key-half partials inline
    for (int i = tid; i < 64 * 84; i += 256) {
        int r = i / 84, c = i % 84;
        float v = 0.0f;
        if (c < 81) {
            int row = row0 + r;             // b*512+s
            int b = row >> 9, s = row & 511;
            int h = c / 9, d = c % 9;
            int gidx = (b * 9 + h) * 512 + s;
            float L = apart[gidx] + apart[1474560 + gidx];
            float A = apart[(1 + d) * 147456 + gidx]
                    + apart[1474560 + (1 + d) * 147456 + gidx];
            v = A / L;
        }
        rows_[i] = v;
    }
    for (int i = tid; i < 84 * 84; i += 256) {
        int e = i / 84, c = i % 84;
        Wl[i] = (e < 81 && c < 81) ? Wo1[e * 81 + c] : 0.0f;
    }
    __syncthreads();
    float hw = hwp[0];
    float onemhw = 1.0f - hw;
    for (int o = tid; o < 336; o += 256) {
        int r4 = o / 21, cg = o % 21;
        int c0 = cg * 4;
        const float* rp = rows_ + r4 * 4 * 84;
        vf4 acc0 = 0.0f, acc1 = 0.0f, acc2 = 0.0f, acc3 = 0.0f;
        #pragma unroll 7
        for (int e = 0; e < 84; e += 4) {
            vf4 w0 = *(const vf4*)(Wl + (e + 0) * 84 + c0);
            vf4 w1 = *(const vf4*)(Wl + (e + 1) * 84 + c0);
            vf4 w2 = *(const vf4*)(Wl + (e + 2) * 84 + c0);
            vf4 w3 = *(const vf4*)(Wl + (e + 3) * 84 + c0);
            vf4 r0 = *(const vf4*)(rp + e);
            vf4 r1 = *(const vf4*)(rp + 84 + e);
            vf4 r2 = *(const vf4*)(rp + 168 + e);
            vf4 r3 = *(const vf4*)(rp + 252 + e);
            acc0 += r0[0] * w0 + r0[1] * w1 + r0[2] * w2 + r0[3] * w3;
            acc1 += r1[0] * w0 + r1[1] * w1 + r1[2] * w2 + r1[3] * w3;
            acc2 += r2[0] * w0 + r2[1] * w1 + r2[2] * w2 + r2[3] * w3;
            acc3 += r3[0] * w0 + r3[1] * w1 + r3[2] * w2 + r3[3] * w3;
        }
        vf4 av[4] = {acc0, acc1, acc2, acc3};
        #pragma unroll
        for (int cc = 0; cc < 4; cc++) {
            int col = c0 + cc;
            if (col < 81) {
                float ls = 0.0f, lq = 0.0f;
                #pragma unroll
                for (int rr = 0; rr < 4; rr++) {
                    int idx = (row0 + r4 * 4 + rr) * 81 + col;
                    float v = onemhw * av[rr][cc] + hw * h2[idx] + txall[idx];
                    matin[idx] = v;
                    ls += v; lq += v * v;
                }
                atomicAdd(&ssum[col], ls);
                atomicAdd(&ssq[col], lq);
            }
        }
    }
    __syncthreads();
    if (tid < 81) {
        atomicAdd(&st1[tid], ssum[tid]);
        atomicAdd(&st1[81 + tid], ssq[tid]);
    }
}

// ---------------- ff1: 64 rows x 64 cols/block, 4x4 tile ; fused st2 ----------------
__global__ __launch_bounds__(256) void ff1_kernel(const float* __restrict__ matin,
                           const float* __restrict__ st1, const float* __restrict__ g1,
                           const float* __restrict__ b1, const float* __restrict__ W,
                           const float* __restrict__ bias, float* __restrict__ f1,
                           float* __restrict__ st2) {
    __shared__ float rows_[64 * 84];
    __shared__ float Wl[84 * 64];       // rows 81..83 zero
    __shared__ float s2s[64], s2q[64];
    int row0 = blockIdx.x * 64;
    int cb = blockIdx.y * 64;
    int tid = threadIdx.x;
    const float invN = 1.0f / 16384.0f;
    if (tid < 64) { s2s[tid] = 0.0f; s2q[tid] = 0.0f; }
    for (int i = tid; i < 64 * 84; i += 256) {
        int c = i % 84;
        float v = 0.0f;
        if (c < 81) {
            float mean = st1[c] * invN;
            float var = st1[81 + c] * invN - mean * mean;
            v = (matin[(row0 + i / 84) * 81 + c] - mean) * rsqrtf(var + EPSV) * g1[c] + b1[c];
        }
        rows_[i] = v;
    }
    for (int i = tid; i < 84 * 64; i += 256) {
        int e = i >> 6, cc = i & 63;
        Wl[i] = (e < 81) ? W[e * 256 + cb + cc] : 0.0f;
    }
    __syncthreads();
    {
        int o = tid;                 // 256 tasks: 16 r-groups x 16 c-groups
        int r4 = o >> 4, cg = o & 15;
        int c0 = cg * 4;
        const float* rp = rows_ + r4 * 4 * 84;
        vf4 acc0 = 0.0f, acc1 = 0.0f, acc2 = 0.0f, acc3 = 0.0f;
        #pragma unroll 7
        for (int e = 0; e < 84; e += 4) {
            vf4 w0 = *(const vf4*)(Wl + ((e + 0) << 6) + c0);
            vf4 w1 = *(const vf4*)(Wl + ((e + 1) << 6) + c0);
            vf4 w2 = *(const vf4*)(Wl + ((e + 2) << 6) + c0);
            vf4 w3 = *(const vf4*)(Wl + ((e + 3) << 6) + c0);
            vf4 r0 = *(const vf4*)(rp + e);
            vf4 r1 = *(const vf4*)(rp + 84 + e);
            vf4 r2 = *(const vf4*)(rp + 168 + e);
            vf4 r3 = *(const vf4*)(rp + 252 + e);
            acc0 += r0[0] * w0 + r0[1] * w1 + r0[2] * w2 + r0[3] * w3;
            acc1 += r1[0] * w0 + r1[1] * w1 + r1[2] * w2 + r1[3] * w3;
            acc2 += r2[0] * w0 + r2[1] * w1 + r2[2] * w2 + r2[3] * w3;
            acc3 += r3[0] * w0 + r3[1] * w1 + r3[2] * w2 + r3[3] * w3;
        }
        vf4 bv = *(const vf4*)(bias + cb + c0);
        acc0 = __builtin_elementwise_max(acc0 + bv, (vf4)0.0f);
        acc1 = __builtin_elementwise_max(acc1 + bv, (vf4)0.0f);
        acc2 = __builtin_elementwise_max(acc2 + bv, (vf4)0.0f);
        acc3 = __builtin_elementwise_max(acc3 + bv, (vf4)0.0f);
        int base = (row0 + r4 * 4) * 256 + cb + c0;
        *(vf4*)(f1 + base)       = acc0;
        *(vf4*)(f1 + base + 256) = acc1;
        *(vf4*)(f1 + base + 512) = acc2;
        *(vf4*)(f1 + base + 768) = acc3;
        vf4 cs = acc0 + acc1 + acc2 + acc3;
        vf4 cq = acc0 * acc0 + acc1 * acc1 + acc2 * acc2 + acc3 * acc3;
        #pragma unroll
        for (int cc = 0; cc < 4; cc++) {
            atomicAdd(&s2s[c0 + cc], cs[cc]);
            atomicAdd(&s2q[c0 + cc], cq[cc]);
        }
    }
    __syncthreads();
    if (tid < 64) {
        atomicAdd(&st2[cb + tid], s2s[tid]);
        atomicAdd(&st2[256 + cb + tid], s2q[tid]);
    }
}

// ---------------- ff2: 32 rows/block, 4 K-quarter passes, 4x4 tile ; fused st3 ----------------
__global__ __launch_bounds__(256) void ff2_kernel(const float* __restrict__ f1,
                           const float* __restrict__ st2, const float* __restrict__ g2,
                           const float* __restrict__ b2, const float* __restrict__ W,
                           const float* __restrict__ bias, const float* __restrict__ matin,
                           const float* __restrict__ st1, const float* __restrict__ g1,
                           const float* __restrict__ b1, float* __restrict__ t3,
                           float* __restrict__ st3) {
    __shared__ float rows_[32 * 64];
    __shared__ float Wl[64 * 84];
    __shared__ float s3s[81], s3q[81];
    int row0 = blockIdx.x * 32;
    int tid = threadIdx.x;
    const float invN = 1.0f / 16384.0f;
    if (tid < 81) { s3s[tid] = 0.0f; s3q[tid] = 0.0f; }
    int o = tid;
    int r4 = o / 21, cg = o % 21;
    int c0 = cg * 4;
    bool active = (o < 168);
    vf4 acc0 = 0.0f, acc1 = 0.0f, acc2 = 0.0f, acc3 = 0.0f;
    for (int kq = 0; kq < 4; kq++) {
        __syncthreads();
        for (int i = tid; i < 32 * 64; i += 256) {
            int r = i >> 6, e = i & 63;
            int c = kq * 64 + e;
            float mean = st2[c] * invN;
            float var = st2[256 + c] * invN - mean * mean;
            rows_[i] = (f1[(row0 + r) * 256 + c] - mean) * rsqrtf(var + EPSV) * g2[c] + b2[c];
        }
        for (int i = tid; i < 64 * 84; i += 256) {
            int e = i / 84, c = i % 84;
            Wl[i] = (c < 81) ? W[(kq * 64 + e) * 81 + c] : 0.0f;
        }
        __syncthreads();
        if (active) {
            const float* rp = rows_ + r4 * 4 * 64;
            #pragma unroll 8
            for (int e = 0; e < 64; e += 4) {
                vf4 w0 = *(const vf4*)(Wl + (e + 0) * 84 + c0);
                vf4 w1 = *(const vf4*)(Wl + (e + 1) * 84 + c0);
                vf4 w2 = *(const vf4*)(Wl + (e + 2) * 84 + c0);
                vf4 w3 = *(const vf4*)(Wl + (e + 3) * 84 + c0);
                vf4 r0 = *(const vf4*)(rp + e);
                vf4 r1 = *(const vf4*)(rp + 64 + e);
                vf4 r2 = *(const vf4*)(rp + 128 + e);
                vf4 r3 = *(const vf4*)(rp + 192 + e);
                acc0 += r0[0] * w0 + r0[1] * w1 + r0[2] * w2 + r0[3] * w3;
                acc1 += r1[0] * w0 + r1[1] * w1 + r1[2] * w2 + r1[3] * w3;
                acc2 += r2[0] * w0 + r2[1] * w1 + r2[2] * w2 + r2[3] * w3;
                acc3 += r3[0] * w0 + r3[1] * w1 + r3[2] * w2 + r3[3] * w3;
            }
        }
    }
    if (active) {
        vf4 av[4] = {acc0, acc1, acc2, acc3};
        #pragma unroll
        for (int cc = 0; cc < 4; cc++) {
            int col = c0 + cc;
            if (col < 81) {
                float mean = st1[col] * invN;
                float var = st1[81 + col] * invN - mean * mean;
                float rstd = rsqrtf(var + EPSV);
                float bval = bias[col];
                float ls = 0.0f, lq = 0.0f;
                #pragma unroll
                for (int rr = 0; rr < 4; rr++) {
                    int idx = (row0 + r4 * 4 + rr) * 81 + col;
                    float ma = (matin[idx] - mean) * rstd * g1[col] + b1[col];
                    float v = ma + fmaxf(av[rr][cc] + bval, 0.0f);
                    t3[idx] = v;
                    ls += v; lq += v * v;
                }
                atomicAdd(&s3s[col], ls);
                atomicAdd(&s3q[col], lq);
            }
        }
    }
    __syncthreads();
    if (tid < 81) {
        atomicAdd(&st3[tid], s3s[tid]);
        atomicAdd(&st3[81 + tid], s3q[tid]);
    }
}

// ---------------- token_mm: u/v dual GEMM (64 rows/block, W-pass split, 4x4 tile) ----------------
__global__ __launch_bounds__(256) void token_mm(const float* __restrict__ t3,
                            const float* __restrict__ st3, const float* __restrict__ g3,
                            const float* __restrict__ b3, const float* __restrict__ tvw,
                            const float* __restrict__ beta1,
                            float* __restrict__ uv0, float* __restrict__ uv1) {
    __shared__ float rows_[64 * 84];
    __shared__ float Wl[84 * 84];
    int blk = blockIdx.x;            // 0..511
    int t = blk >> 8;
    int row0 = (blk & 255) * 64;
    const float* W = (t == 0) ? tvw : beta1;
    float* dst = (t == 0) ? uv0 : uv1;
    int tid = threadIdx.x;
    const float invN = 1.0f / 16384.0f;
    for (int i = tid; i < 64 * 84; i += 256) {
        int c = i % 84;
        float v = 0.0f;
        if (c < 81) {
            float mean = st3[c] * invN;
            float var = st3[81 + c] * invN - mean * mean;
            v = (t3[(row0 + i / 84) * 81 + c] - mean) * rsqrtf(var + EPSV) * g3[c] + b3[c];
        }
        rows_[i] = v;
    }
    for (int i = tid; i < 84 * 84; i += 256) {
        int e = i / 84, c = i % 84;
        Wl[i] = (e < 81 && c < 81) ? W[e * 81 + c] : 0.0f;
    }
    __syncthreads();
    for (int o = tid; o < 336; o += 256) {
        int r4 = o / 21, cg = o % 21;
        int c0 = cg * 4;
        const float* rp = rows_ + r4 * 4 * 84;
        vf4 acc0 = 0.0f, acc1 = 0.0f, acc2 = 0.0f, acc3 = 0.0f;
        #pragma unroll 7
        for (int e = 0; e < 84; e += 4) {
            vf4 w0 = *(const vf4*)(Wl + (e + 0) * 84 + c0);
            vf4 w1 = *(const vf4*)(Wl + (e + 1) * 84 + c0);
            vf4 w2 = *(const vf4*)(Wl + (e + 2) * 84 + c0);
            vf4 w3 = *(const vf4*)(Wl + (e + 3) * 84 + c0);
            vf4 r0 = *(const vf4*)(rp + e);
            vf4 r1 = *(const vf4*)(rp + 84 + e);
            vf4 r2 = *(const vf4*)(rp + 168 + e);
            vf4 r3 = *(const vf4*)(rp + 252 + e);
            acc0 += r0[0] * w0 + r0[1] * w1 + r0[2] * w2 + r0[3] * w3;
            acc1 += r1[0] * w0 + r1[1] * w1 + r1[2] * w2 + r1[3] * w3;
            acc2 += r2[0] * w0 + r2[1] * w1 + r2[2] * w2 + r2[3] * w3;
            acc3 += r3[0] * w0 + r3[1] * w1 + r3[2] * w2 + r3[3] * w3;
        }
        vf4 av[4] = {acc0, acc1, acc2, acc3};
        #pragma unroll
        for (int cc = 0; cc < 4; cc++) {
            int col = c0 + cc;
            if (col < 81) {
                #pragma unroll
                for (int rr = 0; rr < 4; rr++)
                    dst[(row0 + r4 * 4 + rr) * 81 + col] = av[rr][cc];
            }
        }
    }
}

// ---------------- token_pool: softmax-pool over 81, 32 rows/block, 8 lanes/row ----------------
__global__ __launch_bounds__(256) void token_pool(const float* __restrict__ uv0,
                             const float* __restrict__ uv1, const float* __restrict__ tvb,
                             const float* __restrict__ basel, const float* __restrict__ a1p,
                             const float* __restrict__ a2p, float* __restrict__ fea) {
    int tid = threadIdx.x;
    int r = tid >> 3, j = tid & 7;
    int row = blockIdx.x * 32 + r;
    int base = row * 81;
    float u[11], v[11];
    #pragma unroll
    for (int dd = 0; dd < 11; dd++) {
        int d = j + dd * 8;
        if (d < 81) {
            u[dd] = uv0[base + d] + tvb[d];
            v[dd] = uv1[base + d];
        } else {
            u[dd] = 0.0f; v[dd] = -1e30f;
        }
    }
    float mx = -1e30f;
    #pragma unroll
    for (int dd = 0; dd < 11; dd++) mx = fmaxf(mx, v[dd]);
    #pragma unroll
    for (int msk = 1; msk < 8; msk <<= 1) mx = fmaxf(mx, __shfl_xor(mx, msk, 8));
    float sp = 0.0f, sup = 0.0f;
    #pragma unroll
    for (int dd = 0; dd < 11; dd++) {
        float p = __expf(v[dd] - mx);
        sp += p; sup += u[dd] * p;
    }
    #pragma unroll
    for (int msk = 1; msk < 8; msk <<= 1) {
        sp  += __shfl_xor(sp, msk, 8);
        sup += __shfl_xor(sup, msk, 8);
    }
    if (j == 0) {
        int b = row >> 9, s = row & 511;
        fea[row] = a1p[0] * (sup / sp) + a2p[0] * basel[b * 2048 + s * 4];
    }
}

// ---------------- fc1: relu(fea @ W + b), fused st4 ----------------
__global__ void fc1_kernel(const float* __restrict__ in, const float* __restrict__ W,
                           const float* __restrict__ bias, float* __restrict__ out,
                           float* __restrict__ st) {
    int idx = blockIdx.x * blockDim.x + threadIdx.x;
    if (idx >= 32 * 512) return;
    int b = idx >> 9, j = idx & 511;
    float acc = bias[j];
    const float* ip = in + (b << 9);
    #pragma unroll 8
    for (int k = 0; k < 512; k++) acc += ip[k] * W[k * 512 + j];
    acc = fmaxf(acc, 0.0f);
    out[idx] = acc;
    atomicAdd(&st[j], acc);
    atomicAdd(&st[512 + j], acc * acc);
}

// ---------------- fc2: relu(bn(fch1) @ W + b), fused st5 ----------------
__global__ __launch_bounds__(256) void fc2_kernel(const float* __restrict__ in,
                           const float* __restrict__ st4, const float* __restrict__ g,
                           const float* __restrict__ bb, const float* __restrict__ W,
                           const float* __restrict__ bias, float* __restrict__ out,
                           float* __restrict__ st5) {
    __shared__ float scale[512], shift[512];
    int tid = threadIdx.x;
    for (int k = tid; k < 512; k += 256) {
        float mean = st4[k] * (1.0f / 32.0f);
        float var = st4[512 + k] * (1.0f / 32.0f) - mean * mean;
        float sc_ = rsqrtf(var + EPSV) * g[k];
        scale[k] = sc_;
        shift[k] = bb[k] - mean * sc_;
    }
    __syncthreads();
    int idx = blockIdx.x * 256 + tid;
    if (idx >= 32 * 256) return;
    int b = idx >> 8, j = idx & 255;
    float acc = bias[j];
    const float* ip = in + (b << 9);
    #pragma unroll 8
    for (int k = 0; k < 512; k++) acc += (ip[k] * scale[k] + shift[k]) * W[k * 256 + j];
    acc = fmaxf(acc, 0.0f);
    out[idx] = acc;
    atomicAdd(&st5[j], acc);
    atomicAdd(&st5[256 + j], acc * acc);
}

// ---------------- fc3: tanh(bn(fch2) @ W + b) ----------------
__global__ void fc3_kernel(const float* __restrict__ in, const float* __restrict__ st5,
                           const float* __restrict__ g, const float* __restrict__ bb,
                           const float* __restrict__ W, const float* __restrict__ bias,
                           float* __restrict__ out) {
    __shared__ float scale[256], shift[256];
    int tid = threadIdx.x;   // 128
    for (int k = tid; k < 256; k += 128) {
        float mean = st5[k] * (1.0f / 32.0f);
        float var = st5[256 + k] * (1.0f / 32.0f) - mean * mean;
        float sc_ = rsqrtf(var + EPSV) * g[k];
        scale[k] = sc_;
        shift[k] = bb[k] - mean * sc_;
    }
    __syncthreads();
    int b = tid >> 2, j = tid & 3;
    float acc = bias[j];
    const float* ip = in + (b << 8);
    #pragma unroll 8
    for (int k = 0; k < 256; k++) acc += (ip[k] * scale[k] + shift[k]) * W[k * 4 + j];
    out[tid] = tanhf(acc);
}

// =======================================================================
extern "C" void kernel_launch(void* const* d_in, const int* in_sizes, int n_in,
                              void* d_out, int out_size, void* d_ws, size_t ws_size,
                              hipStream_t stream) {
    const float* x       = (const float*)d_in[0];
    const float* basel   = (const float*)d_in[1];
    const float* cali    = (const float*)d_in[2];
    const float* Wq      = (const float*)d_in[3];
    const float* Wk      = (const float*)d_in[4];
    const float* Wq2     = (const float*)d_in[5];
    const float* Wk2     = (const float*)d_in[6];
    const float* Wv2     = (const float*)d_in[7];
    const float* Cv      = (const float*)d_in[8];
    const float* Wo1     = (const float*)d_in[9];
    const float* Wo2     = (const float*)d_in[10];
    const float* corr_w  = (const float*)d_in[11];
    const float* h_w     = (const float*)d_in[12];
    const float* corr    = (const float*)d_in[13];
    const float* g1      = (const float*)d_in[14];
    const float* b1      = (const float*)d_in[15];
    const float* ff1_w   = (const float*)d_in[16];
    const float* ff1_b   = (const float*)d_in[17];
    const float* g2      = (const float*)d_in[18];
    const float* b2      = (const float*)d_in[19];
    const float* ff2_w   = (const float*)d_in[20];
    const float* ff2_b   = (const float*)d_in[21];
    const float* g3      = (const float*)d_in[22];
    const float* b3      = (const float*)d_in[23];
    const float* tvw     = (const float*)d_in[24];
    const float* tvb     = (const float*)d_in[25];
    const float* beta1   = (const float*)d_in[26];
    const float* a1      = (const float*)d_in[27];
    const float* a2      = (const float*)d_in[28];
    const float* fc1_w   = (const float*)d_in[29];
    const float* fc1_b   = (const float*)d_in[30];
    const float* bnf1_g  = (const float*)d_in[31];
    const float* bnf1_b  = (const float*)d_in[32];
    const float* fc2_w   = (const float*)d_in[33];
    const float* fc2_b   = (const float*)d_in[34];
    const float* bnf2_g  = (const float*)d_in[35];
    const float* bnf2_b  = (const float*)d_in[36];
    const float* fc3_w   = (const float*)d_in[37];
    const float* fc3_b   = (const float*)d_in[38];
    float* out = (float*)d_out;
    float* ws = (float*)d_ws;

    // ---- workspace layout (float offsets) ----
    const size_t SCAL  = 0;         // 2
    const size_t PART  = 16;        // 128
    const size_t ST1   = 512;       // 162
    const size_t ST2   = 768;       // 512
    const size_t ST3   = 1536;      // 162
    const size_t ST4   = 1792;      // 1024
    const size_t ST5   = 2880;      // 512
    const size_t FEA   = 4096;      // 16384
    const size_t FCH1  = 20480;     // 16384
    const size_t FCH2  = 36864;     // 8192
    const size_t PEO   = 45056;     // 41472
    const size_t TX    = 90112;     // 1990656
    const size_t Q2O   = 2080768;   // 1327104
    const size_t KCO   = 3407872;   // 1990656   (reused: Qs)
    const size_t VCO   = 5398528;   // 1990656   (reused: Ks)
    const size_t TMP2  = 7389184;   // 1327104   (reused: matin, then uv0)
    const size_t H2O   = 8716288;   // 1327104   (reused: t3)
    const size_t XHO   = 10043392;  // 1327104   (xh, dead after qks -> uv1)
    const size_t BIASO = 11370496;  // 262144    (EBT)
    const size_t F1O   = 11632640;  // 4194304   (f1; also attn1 partials 2949120)

    float* scal  = ws + SCAL;
    float* part  = ws + PART;
    float* st1   = ws + ST1;
    float* st2   = ws + ST2;
    float* st3   = ws + ST3;
    float* st4   = ws + ST4;
    float* st5   = ws + ST5;
    float* fea   = ws + FEA;
    float* fch1  = ws + FCH1;
    float* fch2  = ws + FCH2;
    float* pe    = ws + PEO;
    float* txall = ws + TX;
    float* Q2    = ws + Q2O;
    float* Kc    = ws + KCO;
    float* Vc    = ws + VCO;
    float* tmp2  = ws + TMP2;
    float* h2    = ws + H2O;
    float* xh    = ws + XHO;
    float* ebT   = ws + BIASO;
    float* f1    = ws + F1O;
    float* Qs    = Kc;     // reuse
    float* Ks    = Vc;     // reuse
    float* matin = tmp2;   // reuse (dead after ff2 -> uv0)
    float* t3    = h2;     // reuse
    float* apart = f1;     // attn1 partials live in the (not-yet-used) f1 region
    float* uv0   = tmp2;   // token u plane (matin dead after ff2)
    float* uv1   = xh;     // token v plane (xh dead after qks)

    // zero scal/part/stats region — capture-safe
    hipMemsetAsync(ws, 0, 4096 * sizeof(float), stream);

    minmax_part<<<64, 256, 0, stream>>>(x, part);
    minmax_fin<<<1, 64, 0, stream>>>(part, scal);

    pe_kernel<<<(512 * 81 + 255) / 256, 256, 0, stream>>>(pe);

    tokenize_kernel<<<(48 * 512 * 81 + 255) / 256, 256, 0, stream>>>(x, cali, scal, pe, txall);

    qkv2_kernel<<<1024, 256, 0, stream>>>(txall, Wq2, Wk2, Wv2, Q2, Kc, Vc);

    attn2_kernel<<<(512 * 9 * 32) / 256, 256, 0, stream>>>(Q2, Kc, Vc, tmp2);

    h2xh_kernel<<<256, 256, 0, stream>>>(tmp2, Wo2, txall, h2, xh);

    qks_kernel<<<512, 256, 0, stream>>>(xh, Wq, Wk, Qs, Ks);

    biasmm_kernel<<<dim3(16, 16), dim3(16, 16), 0, stream>>>(corr, Cv, corr_w, ebT);

    attn1_kernel<<<1152, 256, 0, stream>>>(Qs, Ks, ebT, corr_w, apart);

    h1o_kernel<<<256, 256, 0, stream>>>(apart, Wo1, h2, txall, h_w, matin, st1);

    ff1_kernel<<<dim3(256, 4), 256, 0, stream>>>(matin, st1, g1, b1, ff1_w, ff1_b, f1, st2);

    ff2_kernel<<<512, 256, 0, stream>>>(f1, st2, g2, b2, ff2_w, ff2_b,
                                        matin, st1, g1, b1, t3, st3);

    token_mm<<<512, 256, 0, stream>>>(t3, st3, g3, b3, tvw, beta1, uv0, uv1);
    token_pool<<<512, 256, 0, stream>>>(uv0, uv1, tvb, basel, a1, a2, fea);

    fc1_kernel<<<64, 256, 0, stream>>>(fea, fc1_w, fc1_b, fch1, st4);

    fc2_kernel<<<32, 256, 0, stream>>>(fch1, st4, bnf1_g, bnf1_b, fc2_w, fc2_b, fch2, st5);

    fc3_kernel<<<1, 128, 0, stream>>>(fch2, st5, bnf2_g, bnf2_b, fc3_w, fc3_b, out);
}

// Round 16
// 475.777 us; speedup vs baseline: 1.1972x; 1.0114x over previous
//
#include <hip/hip_runtime.h>
#include <hip/hip_bf16.h>
#include <math.h>

#define EPSV 1e-5f

typedef float vf2 __attribute__((ext_vector_type(2)));
typedef float vf4 __attribute__((ext_vector_type(4)));

// ---------------- sizes ----------------
// B=32 Bc=16 L=2048 TOKEN=40 STRIDE=4 D=81 H=9 dk=9 S=512 FF=256 FC1=512 FC2=256 Y=4

// ---------------- minmax: two-stage ----------------
__global__ void minmax_part(const float* __restrict__ x, float* __restrict__ part) {
    __shared__ float smin[256], smax[256];
    int tid = threadIdx.x;
    float mn = 1e30f, mx = -1e30f;
    for (int i = blockIdx.x * 256 + tid; i < 32 * 2008; i += 64 * 256) {
        int b = i / 2008, c = i % 2008 + 20;
        float v = x[b * 2048 + c];
        mn = fminf(mn, v); mx = fmaxf(mx, v);
    }
    smin[tid] = mn; smax[tid] = mx; __syncthreads();
    for (int off = 128; off > 0; off >>= 1) {
        if (tid < off) { smin[tid] = fminf(smin[tid], smin[tid + off]); smax[tid] = fmaxf(smax[tid], smax[tid + off]); }
        __syncthreads();
    }
    if (tid == 0) { part[blockIdx.x] = smin[0]; part[64 + blockIdx.x] = smax[0]; }
}

__global__ void minmax_fin(const float* __restrict__ part, float* __restrict__ scal) {
    __shared__ float smn[64], smx[64];
    int tid = threadIdx.x;
    smn[tid] = part[tid]; smx[tid] = part[64 + tid]; __syncthreads();
    for (int off = 32; off > 0; off >>= 1) {
        if (tid < off) { smn[tid] = fminf(smn[tid], smn[tid + off]); smx[tid] = fmaxf(smx[tid], smx[tid + off]); }
        __syncthreads();
    }
    if (tid == 0) { scal[0] = smn[0]; scal[1] = smx[0] - smn[0]; }
}

// ---------------- PE table (512 x 81) ----------------
__global__ void pe_kernel(float* __restrict__ pe) {
    int idx = blockIdx.x * blockDim.x + threadIdx.x;
    if (idx >= 512 * 81) return;
    int d = idx % 81, s = idx / 81;
    int j = d >> 1;
    float dv = __expf(-9.210340371976184f * (2.0f * (float)j) / 81.0f);
    float ang = (float)s * dv;
    pe[idx] = (d & 1) ? cosf(ang) : sinf(ang);
}

// ---------------- tokenize + add PE ----------------
__global__ void tokenize_kernel(const float* __restrict__ x, const float* __restrict__ cali,
                                const float* __restrict__ scal, const float* __restrict__ pe,
                                float* __restrict__ txall) {
    int idx = blockIdx.x * blockDim.x + threadIdx.x;
    if (idx >= 48 * 512 * 81) return;
    int d = idx % 81;
    int s = (idx / 81) % 512;
    int r = idx / (81 * 512);
    float xm = scal[0], inv_xs = 1.0f / scal[1];
    int oc = s * 4 + d - 40;
    float val = 0.0f;
    if (oc >= 0 && oc < 2048) {
        float sv = (r < 32) ? x[r * 2048 + oc] : cali[(r - 32) * 2048 + oc];
        val = (sv - xm) * inv_xs;
    }
    txall[idx] = val + pe[s * 81 + d];
}

// ======== 4x4-tile 81->81 GEMM pieces (rows stride 84, W [e][col] stride 84) ========

// ---------------- qkv2: 64 rows/block, W-pass split (1024 blocks), 4x4 tile ----------------
__global__ __launch_bounds__(256) void qkv2_kernel(const float* __restrict__ txall,
                            const float* __restrict__ Wq2, const float* __restrict__ Wk2,
                            const float* __restrict__ Wv2,
                            float* __restrict__ Q2, float* __restrict__ Kc, float* __restrict__ Vc) {
    __shared__ float rows_[64 * 84];
    __shared__ float Wl[84 * 84];
    int blk = blockIdx.x;            // 0..1023
    int t, rb;
    if (blk < 256)      { t = 0; rb = blk; }
    else if (blk < 640) { t = 1; rb = blk - 256; }
    else                { t = 2; rb = blk - 640; }
    int row0 = rb * 64;
    int k = row0 >> 9;
    int s0 = row0 & 511;
    const float* W = (t == 0) ? Wq2 : (t == 1) ? Wk2 : Wv2;
    int tid = threadIdx.x;
    for (int i = tid; i < 64 * 84; i += 256) {
        int c = i % 84;
        rows_[i] = (c < 81) ? txall[(row0 + i / 84) * 81 + c] : 0.0f;
    }
    for (int i = tid; i < 84 * 84; i += 256) {
        int e = i / 84, hd = i % 84;
        Wl[i] = (e < 81 && hd < 81) ? W[(hd / 9) * 729 + e * 9 + (hd % 9)] : 0.0f;
    }
    __syncthreads();
    for (int o = tid; o < 336; o += 256) {
        int r4 = o / 21, cg = o % 21;
        int c0 = cg * 4;
        const float* rp = rows_ + r4 * 4 * 84;
        vf4 acc0 = 0.0f, acc1 = 0.0f, acc2 = 0.0f, acc3 = 0.0f;
        #pragma unroll 7
        for (int e = 0; e < 84; e += 4) {
            vf4 w0 = *(const vf4*)(Wl + (e + 0) * 84 + c0);
            vf4 w1 = *(const vf4*)(Wl + (e + 1) * 84 + c0);
            vf4 w2 = *(const vf4*)(Wl + (e + 2) * 84 + c0);
            vf4 w3 = *(const vf4*)(Wl + (e + 3) * 84 + c0);
            vf4 r0 = *(const vf4*)(rp + e);
            vf4 r1 = *(const vf4*)(rp + 84 + e);
            vf4 r2 = *(const vf4*)(rp + 168 + e);
            vf4 r3 = *(const vf4*)(rp + 252 + e);
            acc0 += r0[0] * w0 + r0[1] * w1 + r0[2] * w2 + r0[3] * w3;
            acc1 += r1[0] * w0 + r1[1] * w1 + r1[2] * w2 + r1[3] * w3;
            acc2 += r2[0] * w0 + r2[1] * w1 + r2[2] * w2 + r2[3] * w3;
            acc3 += r3[0] * w0 + r3[1] * w1 + r3[2] * w2 + r3[3] * w3;
        }
        vf4 av[4] = {acc0, acc1, acc2, acc3};
        #pragma unroll
        for (int cc = 0; cc < 4; cc++) {
            int col = c0 + cc;
            if (col < 81) {
                int h = col / 9, d = col % 9;
                #pragma unroll
                for (int rr = 0; rr < 4; rr++) {
                    int s = s0 + r4 * 4 + rr;
                    if (t == 0)      Q2[((s * 9 + h) * 32 + k) * 9 + d] = av[rr][cc];
                    else if (t == 1) Kc[((s * 9 + h) * 48 + k) * 9 + d] = av[rr][cc];
                    else             Vc[((s * 9 + h) * 48 + k) * 9 + d] = av[rr][cc];
                }
            }
        }
    }
}

// ---------------- attention-2 (masked: key==b or key>=32), no-max softmax (exp2) ----------------
__global__ void attn2_kernel(const float* __restrict__ Q2, const float* __restrict__ Kc,
                             const float* __restrict__ Vc, float* __restrict__ tmp2) {
    int tid = blockIdx.x * blockDim.x + threadIdx.x;
    if (tid >= 512 * 9 * 32) return;
    int b = tid & 31;
    int h = (tid >> 5) % 9;
    int s = tid / 288;
    const float* q = Q2 + ((s * 9 + h) * 32 + b) * 9;
    float qr[9];
    const float c2 = 1.4426950408889634f / 3.0f;   // log2e / 3
    #pragma unroll
    for (int d = 0; d < 9; d++) qr[d] = q[d] * c2;
    const float* Kb = Kc + (s * 9 + h) * 48 * 9;
    const float* Vb = Vc + (s * 9 + h) * 48 * 9;
    float l = 0.0f, outv[9];
    #pragma unroll
    for (int d = 0; d < 9; d++) outv[d] = 0.0f;
    #pragma unroll
    for (int j = 0; j < 17; j++) {
        int k = (j == 0) ? b : 31 + j;
        const float* kp = Kb + k * 9;
        float acc = 0.0f;
        #pragma unroll
        for (int d = 0; d < 9; d++) acc += qr[d] * kp[d];
        float p = exp2f(acc);
        l += p;
        const float* vp = Vb + k * 9;
        #pragma unroll
        for (int d = 0; d < 9; d++) outv[d] += p * vp[d];
    }
    float invl = 1.0f / l;
    float* op = tmp2 + (b * 512 + s) * 81 + h * 9;
    #pragma unroll
    for (int d = 0; d < 9; d++) op[d] = outv[d] * invl;
}

// ---------------- h2 = tmp2 @ Wo2 ; xh = tx + h2  (64 rows/block, 4x4 tile) ----------------
__global__ __launch_bounds__(256) void h2xh_kernel(const float* __restrict__ tmp2,
                            const float* __restrict__ Wo2, const float* __restrict__ txall,
                            float* __restrict__ h2, float* __restrict__ xh) {
    __shared__ float rows_[64 * 84];
    __shared__ float Wl[84 * 84];
    int row0 = blockIdx.x * 64;
    int tid = threadIdx.x;
    for (int i = tid; i < 64 * 84; i += 256) {
        int c = i % 84;
        rows_[i] = (c < 81) ? tmp2[(row0 + i / 84) * 81 + c] : 0.0f;
    }
    for (int i = tid; i < 84 * 84; i += 256) {
        int e = i / 84, c = i % 84;
        Wl[i] = (e < 81 && c < 81) ? Wo2[e * 81 + c] : 0.0f;
    }
    __syncthreads();
    for (int o = tid; o < 336; o += 256) {
        int r4 = o / 21, cg = o % 21;
        int c0 = cg * 4;
        const float* rp = rows_ + r4 * 4 * 84;
        vf4 acc0 = 0.0f, acc1 = 0.0f, acc2 = 0.0f, acc3 = 0.0f;
        #pragma unroll 7
        for (int e = 0; e < 84; e += 4) {
            vf4 w0 = *(const vf4*)(Wl + (e + 0) * 84 + c0);
            vf4 w1 = *(const vf4*)(Wl + (e + 1) * 84 + c0);
            vf4 w2 = *(const vf4*)(Wl + (e + 2) * 84 + c0);
            vf4 w3 = *(const vf4*)(Wl + (e + 3) * 84 + c0);
            vf4 r0 = *(const vf4*)(rp + e);
            vf4 r1 = *(const vf4*)(rp + 84 + e);
            vf4 r2 = *(const vf4*)(rp + 168 + e);
            vf4 r3 = *(const vf4*)(rp + 252 + e);
            acc0 += r0[0] * w0 + r0[1] * w1 + r0[2] * w2 + r0[3] * w3;
            acc1 += r1[0] * w0 + r1[1] * w1 + r1[2] * w2 + r1[3] * w3;
            acc2 += r2[0] * w0 + r2[1] * w1 + r2[2] * w2 + r2[3] * w3;
            acc3 += r3[0] * w0 + r3[1] * w1 + r3[2] * w2 + r3[3] * w3;
        }
        vf4 av[4] = {acc0, acc1, acc2, acc3};
        #pragma unroll
        for (int cc = 0; cc < 4; cc++) {
            int col = c0 + cc;
            if (col < 81) {
                #pragma unroll
                for (int rr = 0; rr < 4; rr++) {
                    int idx = (row0 + r4 * 4 + rr) * 81 + col;
                    float v = av[rr][cc];
                    h2[idx] = v;
                    xh[idx] = txall[idx] + v;
                }
            }
        }
    }
}

// ---------------- Qs/Ks (Vs == Qs): 64 rows/block, W-pass split (512 blocks), 4x4 ----------------
__global__ __launch_bounds__(256) void qks_kernel(const float* __restrict__ xh,
                           const float* __restrict__ Wq, const float* __restrict__ Wk,
                           float* __restrict__ Qs, float* __restrict__ Ks) {
    __shared__ float rows_[64 * 84];
    __shared__ float Wl[84 * 84];
    int blk = blockIdx.x;            // 0..511
    int t = blk >> 8;                // 0: Q, 1: K
    int rb = blk & 255;
    int row0 = rb * 64;
    int b = row0 >> 9;
    int s0 = row0 & 511;
    const float* W = (t == 0) ? Wq : Wk;
    int tid = threadIdx.x;
    for (int i = tid; i < 64 * 84; i += 256) {
        int c = i % 84;
        rows_[i] = (c < 81) ? xh[(row0 + i / 84) * 81 + c] : 0.0f;
    }
    for (int i = tid; i < 84 * 84; i += 256) {
        int e = i / 84, hd = i % 84;
        Wl[i] = (e < 81 && hd < 81) ? W[(hd / 9) * 729 + e * 9 + (hd % 9)] : 0.0f;
    }
    __syncthreads();
    float* dst = (t == 0) ? Qs : Ks;
    for (int o = tid; o < 336; o += 256) {
        int r4 = o / 21, cg = o % 21;
        int c0 = cg * 4;
        const float* rp = rows_ + r4 * 4 * 84;
        vf4 acc0 = 0.0f, acc1 = 0.0f, acc2 = 0.0f, acc3 = 0.0f;
        #pragma unroll 7
        for (int e = 0; e < 84; e += 4) {
            vf4 w0 = *(const vf4*)(Wl + (e + 0) * 84 + c0);
            vf4 w1 = *(const vf4*)(Wl + (e + 1) * 84 + c0);
            vf4 w2 = *(const vf4*)(Wl + (e + 2) * 84 + c0);
            vf4 w3 = *(const vf4*)(Wl + (e + 3) * 84 + c0);
            vf4 r0 = *(const vf4*)(rp + e);
            vf4 r1 = *(const vf4*)(rp + 84 + e);
            vf4 r2 = *(const vf4*)(rp + 168 + e);
            vf4 r3 = *(const vf4*)(rp + 252 + e);
            acc0 += r0[0] * w0 + r0[1] * w1 + r0[2] * w2 + r0[3] * w3;
            acc1 += r1[0] * w0 + r1[1] * w1 + r1[2] * w2 + r1[3] * w3;
            acc2 += r2[0] * w0 + r2[1] * w1 + r2[2] * w2 + r2[3] * w3;
            acc3 += r3[0] * w0 + r3[1] * w1 + r3[2] * w2 + r3[3] * w3;
        }
        vf4 av[4] = {acc0, acc1, acc2, acc3};
        #pragma unroll
        for (int cc = 0; cc < 4; cc++) {
            int col = c0 + cc;
            if (col < 81) {
                int h = col / 9, d = col % 9;
                #pragma unroll
                for (int rr = 0; rr < 4; rr++)
                    dst[((b * 9 + h) * 512 + (s0 + r4 * 4 + rr)) * 9 + d] = av[rr][cc];
            }
        }
    }
}

// ---------------- EBT[t*512+s] = exp(cw * (corr @ Cv)^T[t][s] / sqrt(S)) ----------------
__global__ __launch_bounds__(256) void biasmm_kernel(const float* __restrict__ corr,
                              const float* __restrict__ Cv, const float* __restrict__ cwp,
                              float* __restrict__ ebT) {
    __shared__ float As[32][33];
    __shared__ float Bs[32][33];
    int tx = threadIdx.x, ty = threadIdx.y;   // 16 x 16
    int tid = ty * 16 + tx;
    int t0 = blockIdx.y * 32, s0 = blockIdx.x * 32;
    float a00 = 0, a01 = 0, a10 = 0, a11 = 0;
    for (int k0 = 0; k0 < 512; k0 += 32) {
        for (int ii = tid; ii < 1024; ii += 256) {
            int r = ii >> 5, c = ii & 31;
            As[r][c] = Cv[(k0 + r) * 512 + t0 + c];
            Bs[r][c] = corr[(s0 + r) * 512 + k0 + c];
        }
        __syncthreads();
        #pragma unroll
        for (int kk = 0; kk < 32; kk++) {
            float b0 = Bs[tx][kk], b1 = Bs[tx + 16][kk];
            float c0 = As[kk][ty], c1 = As[kk][ty + 16];
            a00 += c0 * b0; a01 += c0 * b1; a10 += c1 * b0; a11 += c1 * b1;
        }
        __syncthreads();
    }
    float cws = cwp[0] * 0.04419417382415922f;   // cw / sqrt(512)
    ebT[(t0 + ty) * 512 + s0 + tx]            = __expf(a00 * cws);
    ebT[(t0 + ty) * 512 + s0 + tx + 16]       = __expf(a01 * cws);
    ebT[(t0 + ty + 16) * 512 + s0 + tx]       = __expf(a10 * cws);
    ebT[(t0 + ty + 16) * 512 + s0 + tx + 16]  = __expf(a11 * cws);
}

// ---------------- attention-1: no-max softmax (exp2), 4-way key split, atomic merge ----------------
// p = exp2(c1*log2e * q.k) * EB[key][q]
// grid 2304: bh = blk>>3, qhalf = (blk>>2)&1, kq4 = blk&3 -- ALL block-uniform (scalar K/V loads)
// each thread: 1 query x 128 keys; partials accumulated into ONE plane set via atomicAdd
// planes: part[e*147456 + (bh*512+q)], e in [0,10)  (zeroed by memset before launch)
__global__ __launch_bounds__(256) void attn1_kernel(const float* __restrict__ Qs,
                                                    const float* __restrict__ Ks,
                                                    const float* __restrict__ ebT,
                                                    const float* __restrict__ cwp,
                                                    float* __restrict__ part) {
    int blk = blockIdx.x;          // 0..2303
    int bh = blk >> 3;             // b*9+h
    int qhalf = (blk >> 2) & 1;
    int kq4 = blk & 3;
    int tid = threadIdx.x;
    const float* Kb = Ks + bh * 4608;
    const float* Qb = Qs + bh * 4608;
    int q = qhalf * 256 + tid;
    float c1 = (1.0f - cwp[0]) * (1.4426950408889634f / 3.0f);   // fold log2e
    vf2 qv[4];
    float q8;
    {
        const float* qp = Qb + q * 9;
        #pragma unroll
        for (int d = 0; d < 4; d++) {
            vf2 t; t.x = c1 * qp[2 * d]; t.y = c1 * qp[2 * d + 1];
            qv[d] = t;
        }
        q8 = c1 * qp[8];
    }
    float l = 0.0f, a8 = 0.0f;
    vf2 acc[4];
    #pragma unroll
    for (int d = 0; d < 4; d++) acc[d] = (vf2)0.0f;
    int k0 = kq4 * 128;            // block-uniform -> K/V scalar loads preserved
    const float* ebp = ebT + q;
    for (int t0 = k0; t0 < k0 + 128; t0 += 8) {
        float eb[8];
        #pragma unroll
        for (int j = 0; j < 8; j++) eb[j] = ebp[(t0 + j) << 9];
        #pragma unroll
        for (int j = 0; j < 8; j++) {
            const float* kr = Kb + (t0 + j) * 9;   // wave-uniform -> scalar loads
            const float* vr = Qb + (t0 + j) * 9;   // Vs == Qs
            vf2 k0v; k0v.x = kr[0]; k0v.y = kr[1];
            vf2 k1v; k1v.x = kr[2]; k1v.y = kr[3];
            vf2 k2v; k2v.x = kr[4]; k2v.y = kr[5];
            vf2 k3v; k3v.x = kr[6]; k3v.y = kr[7];
            vf2 u2 = qv[0] * k0v + qv[1] * k1v + qv[2] * k2v + qv[3] * k3v;
            float u = u2.x + u2.y + q8 * kr[8];
            float p = exp2f(u) * eb[j];
            l += p;
            vf2 p2; p2.x = p; p2.y = p;
            vf2 v0; v0.x = vr[0]; v0.y = vr[1];
            vf2 v1; v1.x = vr[2]; v1.y = vr[3];
            vf2 v2; v2.x = vr[4]; v2.y = vr[5];
            vf2 v3; v3.x = vr[6]; v3.y = vr[7];
            acc[0] += p2 * v0; acc[1] += p2 * v1;
            acc[2] += p2 * v2; acc[3] += p2 * v3;
            a8 += p * vr[8];
        }
    }
    int gidx = bh * 512 + q;
    atomicAdd(&part[gidx], l);
    #pragma unroll
    for (int d = 0; d < 4; d++) {
        atomicAdd(&part[(1 + 2 * d) * 147456 + gidx], acc[d].x);
        atomicAdd(&part[(2 + 2 * d) * 147456 + gidx], acc[d].y);
    }
    atomicAdd(&part[9 * 147456 + gidx], a8);
}

// ---------------- matin = (1-hw)*(h1@Wo1) + hw*h2 + tx ; merge fused, st1 fused ----------------
__global__ __launch_bounds__(256) void h1o_kernel(const float* __restrict__ apart,
                           const float* __restrict__ Wo1, const float* __restrict__ h2,
                           const float* __restrict__ txall, const float* __restrict__ hwp,
                           float* __restrict__ matin, float* __restrict__ st1) {
    __shared__ float rows_[64 * 84];
    __shared__ float Wl[84 * 84];
    __shared__ float ssum[81], ssq[81];
    int row0 = blockIdx.x * 64;
    int tid = threadIdx.x;
    if (tid < 81) { ssum[tid] = 0.0f; ssq[tid] = 0.0f; }
    // stage h1 rows from the (already-merged) atomic plane set
    for (int i = tid; i < 64 * 84; i += 256) {
        int r = i / 84, c = i % 84;
        float v = 0.0f;
        if (c < 81) {
            int row = row0 + r;             // b*512+s
            int b = row >> 9, s = row & 511;
            int h = c / 9, d = c % 9;
            int gidx = (b * 9 + h) * 512 + s;
            float L = apart[gidx];
            float A = apart[(1 + d) * 147456 + gidx];
            v = A / L;
        }
        rows_[i] = v;
    }
    for (int i = tid; i < 84 * 84; i += 256) {
        int e = i / 84, c = i % 84;
        Wl[i] = (e < 81 && c < 81) ? Wo1[e * 81 + c] : 0.0f;
    }
    __syncthreads();
    float hw = hwp[0];
    float onemhw = 1.0f - hw;
    for (int o = tid; o < 336; o += 256) {
        int r4 = o / 21, cg = o % 21;
        int c0 = cg * 4;
        const float* rp = rows_ + r4 * 4 * 84;
        vf4 acc0 = 0.0f, acc1 = 0.0f, acc2 = 0.0f, acc3 = 0.0f;
        #pragma unroll 7
        for (int e = 0; e < 84; e += 4) {
            vf4 w0 = *(const vf4*)(Wl + (e + 0) * 84 + c0);
            vf4 w1 = *(const vf4*)(Wl + (e + 1) * 84 + c0);
            vf4 w2 = *(const vf4*)(Wl + (e + 2) * 84 + c0);
            vf4 w3 = *(const vf4*)(Wl + (e + 3) * 84 + c0);
            vf4 r0 = *(const vf4*)(rp + e);
            vf4 r1 = *(const vf4*)(rp + 84 + e);
            vf4 r2 = *(const vf4*)(rp + 168 + e);
            vf4 r3 = *(const vf4*)(rp + 252 + e);
            acc0 += r0[0] * w0 + r0[1] * w1 + r0[2] * w2 + r0[3] * w3;
            acc1 += r1[0] * w0 + r1[1] * w1 + r1[2] * w2 + r1[3] * w3;
            acc2 += r2[0] * w0 + r2[1] * w1 + r2[2] * w2 + r2[3] * w3;
            acc3 += r3[0] * w0 + r3[1] * w1 + r3[2] * w2 + r3[3] * w3;
        }
        vf4 av[4] = {acc0, acc1, acc2, acc3};
        #pragma unroll
        for (int cc = 0; cc < 4; cc++) {
            int col = c0 + cc;
            if (col < 81) {
                float ls = 0.0f, lq = 0.0f;
                #pragma unroll
                for (int rr = 0; rr < 4; rr++) {
                    int idx = (row0 + r4 * 4 + rr) * 81 + col;
                    float v = onemhw * av[rr][cc] + hw * h2[idx] + txall[idx];
                    matin[idx] = v;
                    ls += v; lq += v * v;
                }
                atomicAdd(&ssum[col], ls);
                atomicAdd(&ssq[col], lq);
            }
        }
    }
    __syncthreads();
    if (tid < 81) {
        atomicAdd(&st1[tid], ssum[tid]);
        atomicAdd(&st1[81 + tid], ssq[tid]);
    }
}

// ---------------- ff1: 64 rows x 64 cols/block, 4x4 tile ; fused st2 ----------------
__global__ __launch_bounds__(256) void ff1_kernel(const float* __restrict__ matin,
                           const float* __restrict__ st1, const float* __restrict__ g1,
                           const float* __restrict__ b1, const float* __restrict__ W,
                           const float* __restrict__ bias, float* __restrict__ f1,
                           float* __restrict__ st2) {
    __shared__ float rows_[64 * 84];
    __shared__ float Wl[84 * 64];       // rows 81..83 zero
    __shared__ float s2s[64], s2q[64];
    int row0 = blockIdx.x * 64;
    int cb = blockIdx.y * 64;
    int tid = threadIdx.x;
    const float invN = 1.0f / 16384.0f;
    if (tid < 64) { s2s[tid] = 0.0f; s2q[tid] = 0.0f; }
    for (int i = tid; i < 64 * 84; i += 256) {
        int c = i % 84;
        float v = 0.0f;
        if (c < 81) {
            float mean = st1[c] * invN;
            float var = st1[81 + c] * invN - mean * mean;
            v = (matin[(row0 + i / 84) * 81 + c] - mean) * rsqrtf(var + EPSV) * g1[c] + b1[c];
        }
        rows_[i] = v;
    }
    for (int i = tid; i < 84 * 64; i += 256) {
        int e = i >> 6, cc = i & 63;
        Wl[i] = (e < 81) ? W[e * 256 + cb + cc] : 0.0f;
    }
    __syncthreads();
    {
        int o = tid;                 // 256 tasks: 16 r-groups x 16 c-groups
        int r4 = o >> 4, cg = o & 15;
        int c0 = cg * 4;
        const float* rp = rows_ + r4 * 4 * 84;
        vf4 acc0 = 0.0f, acc1 = 0.0f, acc2 = 0.0f, acc3 = 0.0f;
        #pragma unroll 7
        for (int e = 0; e < 84; e += 4) {
            vf4 w0 = *(const vf4*)(Wl + ((e + 0) << 6) + c0);
            vf4 w1 = *(const vf4*)(Wl + ((e + 1) << 6) + c0);
            vf4 w2 = *(const vf4*)(Wl + ((e + 2) << 6) + c0);
            vf4 w3 = *(const vf4*)(Wl + ((e + 3) << 6) + c0);
            vf4 r0 = *(const vf4*)(rp + e);
            vf4 r1 = *(const vf4*)(rp + 84 + e);
            vf4 r2 = *(const vf4*)(rp + 168 + e);
            vf4 r3 = *(const vf4*)(rp + 252 + e);
            acc0 += r0[0] * w0 + r0[1] * w1 + r0[2] * w2 + r0[3] * w3;
            acc1 += r1[0] * w0 + r1[1] * w1 + r1[2] * w2 + r1[3] * w3;
            acc2 += r2[0] * w0 + r2[1] * w1 + r2[2] * w2 + r2[3] * w3;
            acc3 += r3[0] * w0 + r3[1] * w1 + r3[2] * w2 + r3[3] * w3;
        }
        vf4 bv = *(const vf4*)(bias + cb + c0);
        acc0 = __builtin_elementwise_max(acc0 + bv, (vf4)0.0f);
        acc1 = __builtin_elementwise_max(acc1 + bv, (vf4)0.0f);
        acc2 = __builtin_elementwise_max(acc2 + bv, (vf4)0.0f);
        acc3 = __builtin_elementwise_max(acc3 + bv, (vf4)0.0f);
        int base = (row0 + r4 * 4) * 256 + cb + c0;
        *(vf4*)(f1 + base)       = acc0;
        *(vf4*)(f1 + base + 256) = acc1;
        *(vf4*)(f1 + base + 512) = acc2;
        *(vf4*)(f1 + base + 768) = acc3;
        vf4 cs = acc0 + acc1 + acc2 + acc3;
        vf4 cq = acc0 * acc0 + acc1 * acc1 + acc2 * acc2 + acc3 * acc3;
        #pragma unroll
        for (int cc = 0; cc < 4; cc++) {
            atomicAdd(&s2s[c0 + cc], cs[cc]);
            atomicAdd(&s2q[c0 + cc], cq[cc]);
        }
    }
    __syncthreads();
    if (tid < 64) {
        atomicAdd(&st2[cb + tid], s2s[tid]);
        atomicAdd(&st2[256 + cb + tid], s2q[tid]);
    }
}

// ---------------- ff2: 32 rows/block, 4 K-quarter passes, 4x4 tile ; fused st3 ----------------
__global__ __launch_bounds__(256) void ff2_kernel(const float* __restrict__ f1,
                           const float* __restrict__ st2, const float* __restrict__ g2,
                           const float* __restrict__ b2, const float* __restrict__ W,
                           const float* __restrict__ bias, const float* __restrict__ matin,
                           const float* __restrict__ st1, const float* __restrict__ g1,
                           const float* __restrict__ b1, float* __restrict__ t3,
                           float* __restrict__ st3) {
    __shared__ float rows_[32 * 64];
    __shared__ float Wl[64 * 84];
    __shared__ float s3s[81], s3q[81];
    int row0 = blockIdx.x * 32;
    int tid = threadIdx.x;
    const float invN = 1.0f / 16384.0f;
    if (tid < 81) { s3s[tid] = 0.0f; s3q[tid] = 0.0f; }
    int o = tid;
    int r4 = o / 21, cg = o % 21;
    int c0 = cg * 4;
    bool active = (o < 168);
    vf4 acc0 = 0.0f, acc1 = 0.0f, acc2 = 0.0f, acc3 = 0.0f;
    for (int kq = 0; kq < 4; kq++) {
        __syncthreads();
        for (int i = tid; i < 32 * 64; i += 256) {
            int r = i >> 6, e = i & 63;
            int c = kq * 64 + e;
            float mean = st2[c] * invN;
            float var = st2[256 + c] * invN - mean * mean;
            rows_[i] = (f1[(row0 + r) * 256 + c] - mean) * rsqrtf(var + EPSV) * g2[c] + b2[c];
        }
        for (int i = tid; i < 64 * 84; i += 256) {
            int e = i / 84, c = i % 84;
            Wl[i] = (c < 81) ? W[(kq * 64 + e) * 81 + c] : 0.0f;
        }
        __syncthreads();
        if (active) {
            const float* rp = rows_ + r4 * 4 * 64;
            #pragma unroll 8
            for (int e = 0; e < 64; e += 4) {
                vf4 w0 = *(const vf4*)(Wl + (e + 0) * 84 + c0);
                vf4 w1 = *(const vf4*)(Wl + (e + 1) * 84 + c0);
                vf4 w2 = *(const vf4*)(Wl + (e + 2) * 84 + c0);
                vf4 w3 = *(const vf4*)(Wl + (e + 3) * 84 + c0);
                vf4 r0 = *(const vf4*)(rp + e);
                vf4 r1 = *(const vf4*)(rp + 64 + e);
                vf4 r2 = *(const vf4*)(rp + 128 + e);
                vf4 r3 = *(const vf4*)(rp + 192 + e);
                acc0 += r0[0] * w0 + r0[1] * w1 + r0[2] * w2 + r0[3] * w3;
                acc1 += r1[0] * w0 + r1[1] * w1 + r1[2] * w2 + r1[3] * w3;
                acc2 += r2[0] * w0 + r2[1] * w1 + r2[2] * w2 + r2[3] * w3;
                acc3 += r3[0] * w0 + r3[1] * w1 + r3[2] * w2 + r3[3] * w3;
            }
        }
    }
    if (active) {
        vf4 av[4] = {acc0, acc1, acc2, acc3};
        #pragma unroll
        for (int cc = 0; cc < 4; cc++) {
            int col = c0 + cc;
            if (col < 81) {
                float mean = st1[col] * invN;
                float var = st1[81 + col] * invN - mean * mean;
                float rstd = rsqrtf(var + EPSV);
                float bval = bias[col];
                float ls = 0.0f, lq = 0.0f;
                #pragma unroll
                for (int rr = 0; rr < 4; rr++) {
                    int idx = (row0 + r4 * 4 + rr) * 81 + col;
                    float ma = (matin[idx] - mean) * rstd * g1[col] + b1[col];
                    float v = ma + fmaxf(av[rr][cc] + bval, 0.0f);
                    t3[idx] = v;
                    ls += v; lq += v * v;
                }
                atomicAdd(&s3s[col], ls);
                atomicAdd(&s3q[col], lq);
            }
        }
    }
    __syncthreads();
    if (tid < 81) {
        atomicAdd(&st3[tid], s3s[tid]);
        atomicAdd(&st3[81 + tid], s3q[tid]);
    }
}

// ---------------- token_mm: u/v dual GEMM (64 rows/block, W-pass split, 4x4 tile) ----------------
__global__ __launch_bounds__(256) void token_mm(const float* __restrict__ t3,
                            const float* __restrict__ st3, const float* __restrict__ g3,
                            const float* __restrict__ b3, const float* __restrict__ tvw,
                            const float* __restrict__ beta1,
                            float* __restrict__ uv0, float* __restrict__ uv1) {
    __shared__ float rows_[64 * 84];
    __shared__ float Wl[84 * 84];
    int blk = blockIdx.x;            // 0..511
    int t = blk >> 8;
    int row0 = (blk & 255) * 64;
    const float* W = (t == 0) ? tvw : beta1;
    float* dst = (t == 0) ? uv0 : uv1;
    int tid = threadIdx.x;
    const float invN = 1.0f / 16384.0f;
    for (int i = tid; i < 64 * 84; i += 256) {
        int c = i % 84;
        float v = 0.0f;
        if (c < 81) {
            float mean = st3[c] * invN;
            float var = st3[81 + c] * invN - mean * mean;
            v = (t3[(row0 + i / 84) * 81 + c] - mean) * rsqrtf(var + EPSV) * g3[c] + b3[c];
        }
        rows_[i] = v;
    }
    for (int i = tid; i < 84 * 84; i += 256) {
        int e = i / 84, c = i % 84;
        Wl[i] = (e < 81 && c < 81) ? W[e * 81 + c] : 0.0f;
    }
    __syncthreads();
    for (int o = tid; o < 336; o += 256) {
        int r4 = o / 21, cg = o % 21;
        int c0 = cg * 4;
        const float* rp = rows_ + r4 * 4 * 84;
        vf4 acc0 = 0.0f, acc1 = 0.0f, acc2 = 0.0f, acc3 = 0.0f;
        #pragma unroll 7
        for (int e = 0; e < 84; e += 4) {
            vf4 w0 = *(const vf4*)(Wl + (e + 0) * 84 + c0);
            vf4 w1 = *(const vf4*)(Wl + (e + 1) * 84 + c0);
            vf4 w2 = *(const vf4*)(Wl + (e + 2) * 84 + c0);
            vf4 w3 = *(const vf4*)(Wl + (e + 3) * 84 + c0);
            vf4 r0 = *(const vf4*)(rp + e);
            vf4 r1 = *(const vf4*)(rp + 84 + e);
            vf4 r2 = *(const vf4*)(rp + 168 + e);
            vf4 r3 = *(const vf4*)(rp + 252 + e);
            acc0 += r0[0] * w0 + r0[1] * w1 + r0[2] * w2 + r0[3] * w3;
            acc1 += r1[0] * w0 + r1[1] * w1 + r1[2] * w2 + r1[3] * w3;
            acc2 += r2[0] * w0 + r2[1] * w1 + r2[2] * w2 + r2[3] * w3;
            acc3 += r3[0] * w0 + r3[1] * w1 + r3[2] * w2 + r3[3] * w3;
        }
        vf4 av[4] = {acc0, acc1, acc2, acc3};
        #pragma unroll
        for (int cc = 0; cc < 4; cc++) {
            int col = c0 + cc;
            if (col < 81) {
                #pragma unroll
                for (int rr = 0; rr < 4; rr++)
                    dst[(row0 + r4 * 4 + rr) * 81 + col] = av[rr][cc];
            }
        }
    }
}

// ---------------- token_pool: softmax-pool over 81, 32 rows/block, 8 lanes/row ----------------
__global__ __launch_bounds__(256) void token_pool(const float* __restrict__ uv0,
                             const float* __restrict__ uv1, const float* __restrict__ tvb,
                             const float* __restrict__ basel, const float* __restrict__ a1p,
                             const float* __restrict__ a2p, float* __restrict__ fea) {
    int tid = threadIdx.x;
    int r = tid >> 3, j = tid & 7;
    int row = blockIdx.x * 32 + r;
    int base = row * 81;
    float u[11], v[11];
    #pragma unroll
    for (int dd = 0; dd < 11; dd++) {
        int d = j + dd * 8;
        if (d < 81) {
            u[dd] = uv0[base + d] + tvb[d];
            v[dd] = uv1[base + d];
        } else {
            u[dd] = 0.0f; v[dd] = -1e30f;
        }
    }
    float mx = -1e30f;
    #pragma unroll
    for (int dd = 0; dd < 11; dd++) mx = fmaxf(mx, v[dd]);
    #pragma unroll
    for (int msk = 1; msk < 8; msk <<= 1) mx = fmaxf(mx, __shfl_xor(mx, msk, 8));
    float sp = 0.0f, sup = 0.0f;
    #pragma unroll
    for (int dd = 0; dd < 11; dd++) {
        float p = __expf(v[dd] - mx);
        sp += p; sup += u[dd] * p;
    }
    #pragma unroll
    for (int msk = 1; msk < 8; msk <<= 1) {
        sp  += __shfl_xor(sp, msk, 8);
        sup += __shfl_xor(sup, msk, 8);
    }
    if (j == 0) {
        int b = row >> 9, s = row & 511;
        fea[row] = a1p[0] * (sup / sp) + a2p[0] * basel[b * 2048 + s * 4];
    }
}

// ---------------- fc1: relu(fea @ W + b), fused st4 ----------------
__global__ void fc1_kernel(const float* __restrict__ in, const float* __restrict__ W,
                           const float* __restrict__ bias, float* __restrict__ out,
                           float* __restrict__ st) {
    int idx = blockIdx.x * blockDim.x + threadIdx.x;
    if (idx >= 32 * 512) return;
    int b = idx >> 9, j = idx & 511;
    float acc = bias[j];
    const float* ip = in + (b << 9);
    #pragma unroll 8
    for (int k = 0; k < 512; k++) acc += ip[k] * W[k * 512 + j];
    acc = fmaxf(acc, 0.0f);
    out[idx] = acc;
    atomicAdd(&st[j], acc);
    atomicAdd(&st[512 + j], acc * acc);
}

// ---------------- fc2: relu(bn(fch1) @ W + b), fused st5 ----------------
__global__ __launch_bounds__(256) void fc2_kernel(const float* __restrict__ in,
                           const float* __restrict__ st4, const float* __restrict__ g,
                           const float* __restrict__ bb, const float* __restrict__ W,
                           const float* __restrict__ bias, float* __restrict__ out,
                           float* __restrict__ st5) {
    __shared__ float scale[512], shift[512];
    int tid = threadIdx.x;
    for (int k = tid; k < 512; k += 256) {
        float mean = st4[k] * (1.0f / 32.0f);
        float var = st4[512 + k] * (1.0f / 32.0f) - mean * mean;
        float sc_ = rsqrtf(var + EPSV) * g[k];
        scale[k] = sc_;
        shift[k] = bb[k] - mean * sc_;
    }
    __syncthreads();
    int idx = blockIdx.x * 256 + tid;
    if (idx >= 32 * 256) return;
    int b = idx >> 8, j = idx & 255;
    float acc = bias[j];
    const float* ip = in + (b << 9);
    #pragma unroll 8
    for (int k = 0; k < 512; k++) acc += (ip[k] * scale[k] + shift[k]) * W[k * 256 + j];
    acc = fmaxf(acc, 0.0f);
    out[idx] = acc;
    atomicAdd(&st5[j], acc);
    atomicAdd(&st5[256 + j], acc * acc);
}

// ---------------- fc3: tanh(bn(fch2) @ W + b) ----------------
__global__ void fc3_kernel(const float* __restrict__ in, const float* __restrict__ st5,
                           const float* __restrict__ g, const float* __restrict__ bb,
                           const float* __restrict__ W, const float* __restrict__ bias,
                           float* __restrict__ out) {
    __shared__ float scale[256], shift[256];
    int tid = threadIdx.x;   // 128
    for (int k = tid; k < 256; k += 128) {
        float mean = st5[k] * (1.0f / 32.0f);
        float var = st5[256 + k] * (1.0f / 32.0f) - mean * mean;
        float sc_ = rsqrtf(var + EPSV) * g[k];
        scale[k] = sc_;
        shift[k] = bb[k] - mean * sc_;
    }
    __syncthreads();
    int b = tid >> 2, j = tid & 3;
    float acc = bias[j];
    const float* ip = in + (b << 8);
    #pragma unroll 8
    for (int k = 0; k < 256; k++) acc += (ip[k] * scale[k] + shift[k]) * W[k * 4 + j];
    out[tid] = tanhf(acc);
}

// =======================================================================
extern "C" void kernel_launch(void* const* d_in, const int* in_sizes, int n_in,
                              void* d_out, int out_size, void* d_ws, size_t ws_size,
                              hipStream_t stream) {
    const float* x       = (const float*)d_in[0];
    const float* basel   = (const float*)d_in[1];
    const float* cali    = (const float*)d_in[2];
    const float* Wq      = (const float*)d_in[3];
    const float* Wk      = (const float*)d_in[4];
    const float* Wq2     = (const float*)d_in[5];
    const float* Wk2     = (const float*)d_in[6];
    const float* Wv2     = (const float*)d_in[7];
    const float* Cv      = (const float*)d_in[8];
    const float* Wo1     = (const float*)d_in[9];
    const float* Wo2     = (const float*)d_in[10];
    const float* corr_w  = (const float*)d_in[11];
    const float* h_w     = (const float*)d_in[12];
    const float* corr    = (const float*)d_in[13];
    const float* g1      = (const float*)d_in[14];
    const float* b1      = (const float*)d_in[15];
    const float* ff1_w   = (const float*)d_in[16];
    const float* ff1_b   = (const float*)d_in[17];
    const float* g2      = (const float*)d_in[18];
    const float* b2      = (const float*)d_in[19];
    const float* ff2_w   = (const float*)d_in[20];
    const float* ff2_b   = (const float*)d_in[21];
    const float* g3      = (const float*)d_in[22];
    const float* b3      = (const float*)d_in[23];
    const float* tvw     = (const float*)d_in[24];
    const float* tvb     = (const float*)d_in[25];
    const float* beta1   = (const float*)d_in[26];
    const float* a1      = (const float*)d_in[27];
    const float* a2      = (const float*)d_in[28];
    const float* fc1_w   = (const float*)d_in[29];
    const float* fc1_b   = (const float*)d_in[30];
    const float* bnf1_g  = (const float*)d_in[31];
    const float* bnf1_b  = (const float*)d_in[32];
    const float* fc2_w   = (const float*)d_in[33];
    const float* fc2_b   = (const float*)d_in[34];
    const float* bnf2_g  = (const float*)d_in[35];
    const float* bnf2_b  = (const float*)d_in[36];
    const float* fc3_w   = (const float*)d_in[37];
    const float* fc3_b   = (const float*)d_in[38];
    float* out = (float*)d_out;
    float* ws = (float*)d_ws;

    // ---- workspace layout (float offsets) ----
    const size_t SCAL  = 0;         // 2
    const size_t PART  = 16;        // 128
    const size_t ST1   = 512;       // 162
    const size_t ST2   = 768;       // 512
    const size_t ST3   = 1536;      // 162
    const size_t ST4   = 1792;      // 1024
    const size_t ST5   = 2880;      // 512
    const size_t FEA   = 4096;      // 16384
    const size_t FCH1  = 20480;     // 16384
    const size_t FCH2  = 36864;     // 8192
    const size_t PEO   = 45056;     // 41472
    const size_t TX    = 90112;     // 1990656
    const size_t Q2O   = 2080768;   // 1327104
    const size_t KCO   = 3407872;   // 1990656   (reused: Qs)
    const size_t VCO   = 5398528;   // 1990656   (reused: Ks)
    const size_t TMP2  = 7389184;   // 1327104   (reused: matin, then uv0)
    const size_t H2O   = 8716288;   // 1327104   (reused: t3)
    const size_t XHO   = 10043392;  // 1327104   (xh, dead after qks -> uv1)
    const size_t BIASO = 11370496;  // 262144    (EBT)
    const size_t F1O   = 11632640;  // 4194304   (f1; also attn1 planes 1474560)

    float* scal  = ws + SCAL;
    float* part  = ws + PART;
    float* st1   = ws + ST1;
    float* st2   = ws + ST2;
    float* st3   = ws + ST3;
    float* st4   = ws + ST4;
    float* st5   = ws + ST5;
    float* fea   = ws + FEA;
    float* fch1  = ws + FCH1;
    float* fch2  = ws + FCH2;
    float* pe    = ws + PEO;
    float* txall = ws + TX;
    float* Q2    = ws + Q2O;
    float* Kc    = ws + KCO;
    float* Vc    = ws + VCO;
    float* tmp2  = ws + TMP2;
    float* h2    = ws + H2O;
    float* xh    = ws + XHO;
    float* ebT   = ws + BIASO;
    float* f1    = ws + F1O;
    float* Qs    = Kc;     // reuse
    float* Ks    = Vc;     // reuse
    float* matin = tmp2;   // reuse (dead after ff2 -> uv0)
    float* t3    = h2;     // reuse
    float* apart = f1;     // attn1 atomic planes (10 x 147456 floats) in f1 region
    float* uv0   = tmp2;   // token u plane (matin dead after ff2)
    float* uv1   = xh;     // token v plane (xh dead after qks)

    // zero scal/part/stats region — capture-safe
    hipMemsetAsync(ws, 0, 4096 * sizeof(float), stream);
    // zero attn1 atomic planes (5.9 MB)
    hipMemsetAsync(apart, 0, 1474560 * sizeof(float), stream);

    minmax_part<<<64, 256, 0, stream>>>(x, part);
    minmax_fin<<<1, 64, 0, stream>>>(part, scal);

    pe_kernel<<<(512 * 81 + 255) / 256, 256, 0, stream>>>(pe);

    tokenize_kernel<<<(48 * 512 * 81 + 255) / 256, 256, 0, stream>>>(x, cali, scal, pe, txall);

    qkv2_kernel<<<1024, 256, 0, stream>>>(txall, Wq2, Wk2, Wv2, Q2, Kc, Vc);

    attn2_kernel<<<(512 * 9 * 32) / 256, 256, 0, stream>>>(Q2, Kc, Vc, tmp2);

    h2xh_kernel<<<256, 256, 0, stream>>>(tmp2, Wo2, txall, h2, xh);

    qks_kernel<<<512, 256, 0, stream>>>(xh, Wq, Wk, Qs, Ks);

    biasmm_kernel<<<dim3(16, 16), dim3(16, 16), 0, stream>>>(corr, Cv, corr_w, ebT);

    attn1_kernel<<<2304, 256, 0, stream>>>(Qs, Ks, ebT, corr_w, apart);

    h1o_kernel<<<256, 256, 0, stream>>>(apart, Wo1, h2, txall, h_w, matin, st1);

    ff1_kernel<<<dim3(256, 4), 256, 0, stream>>>(matin, st1, g1, b1, ff1_w, ff1_b, f1, st2);

    ff2_kernel<<<512, 256, 0, stream>>>(f1, st2, g2, b2, ff2_w, ff2_b,
                                        matin, st1, g1, b1, t3, st3);

    token_mm<<<512, 256, 0, stream>>>(t3, st3, g3, b3, tvw, beta1, uv0, uv1);
    token_pool<<<512, 256, 0, stream>>>(uv0, uv1, tvb, basel, a1, a2, fea);

    fc1_kernel<<<64, 256, 0, stream>>>(fea, fc1_w, fc1_b, fch1, st4);

    fc2_kernel<<<32, 256, 0, stream>>>(fch1, st4, bnf1_g, bnf1_b, fc2_w, fc2_b, fch2, st5);

    fc3_kernel<<<1, 128, 0, stream>>>(fch2, st5, bnf2_g, bnf2_b, fc3_w, fc3_b, out);
}

// Round 17
// 423.394 us; speedup vs baseline: 1.3453x; 1.1237x over previous
//
#include <hip/hip_runtime.h>
#include <hip/hip_bf16.h>
#include <math.h>

#define EPSV 1e-5f

typedef float vf2 __attribute__((ext_vector_type(2)));
typedef float vf4 __attribute__((ext_vector_type(4)));

// ---------------- sizes ----------------
// B=32 Bc=16 L=2048 TOKEN=40 STRIDE=4 D=81 H=9 dk=9 S=512 FF=256 FC1=512 FC2=256 Y=4

// ---------------- minmax: two-stage ----------------
__global__ void minmax_part(const float* __restrict__ x, float* __restrict__ part) {
    __shared__ float smin[256], smax[256];
    int tid = threadIdx.x;
    float mn = 1e30f, mx = -1e30f;
    for (int i = blockIdx.x * 256 + tid; i < 32 * 2008; i += 64 * 256) {
        int b = i / 2008, c = i % 2008 + 20;
        float v = x[b * 2048 + c];
        mn = fminf(mn, v); mx = fmaxf(mx, v);
    }
    smin[tid] = mn; smax[tid] = mx; __syncthreads();
    for (int off = 128; off > 0; off >>= 1) {
        if (tid < off) { smin[tid] = fminf(smin[tid], smin[tid + off]); smax[tid] = fmaxf(smax[tid], smax[tid + off]); }
        __syncthreads();
    }
    if (tid == 0) { part[blockIdx.x] = smin[0]; part[64 + blockIdx.x] = smax[0]; }
}

__global__ void minmax_fin(const float* __restrict__ part, float* __restrict__ scal) {
    __shared__ float smn[64], smx[64];
    int tid = threadIdx.x;
    smn[tid] = part[tid]; smx[tid] = part[64 + tid]; __syncthreads();
    for (int off = 32; off > 0; off >>= 1) {
        if (tid < off) { smn[tid] = fminf(smn[tid], smn[tid + off]); smx[tid] = fmaxf(smx[tid], smx[tid + off]); }
        __syncthreads();
    }
    if (tid == 0) { scal[0] = smn[0]; scal[1] = smx[0] - smn[0]; }
}

// ---------------- PE table (512 x 81) ----------------
__global__ void pe_kernel(float* __restrict__ pe) {
    int idx = blockIdx.x * blockDim.x + threadIdx.x;
    if (idx >= 512 * 81) return;
    int d = idx % 81, s = idx / 81;
    int j = d >> 1;
    float dv = __expf(-9.210340371976184f * (2.0f * (float)j) / 81.0f);
    float ang = (float)s * dv;
    pe[idx] = (d & 1) ? cosf(ang) : sinf(ang);
}

// ---------------- tokenize + add PE ----------------
__global__ void tokenize_kernel(const float* __restrict__ x, const float* __restrict__ cali,
                                const float* __restrict__ scal, const float* __restrict__ pe,
                                float* __restrict__ txall) {
    int idx = blockIdx.x * blockDim.x + threadIdx.x;
    if (idx >= 48 * 512 * 81) return;
    int d = idx % 81;
    int s = (idx / 81) % 512;
    int r = idx / (81 * 512);
    float xm = scal[0], inv_xs = 1.0f / scal[1];
    int oc = s * 4 + d - 40;
    float val = 0.0f;
    if (oc >= 0 && oc < 2048) {
        float sv = (r < 32) ? x[r * 2048 + oc] : cali[(r - 32) * 2048 + oc];
        val = (sv - xm) * inv_xs;
    }
    txall[idx] = val + pe[s * 81 + d];
}

// ======== 4x4-tile 81->81 GEMM pieces (rows stride 84, W [e][col] stride 84) ========
// 512 threads/block: staging strides 512, compute single pass (336 tasks of 512 threads)

// ---------------- qkv2: 64 rows/block, W-pass split (1024 blocks), 4x4 tile ----------------
__global__ __launch_bounds__(512) void qkv2_kernel(const float* __restrict__ txall,
                            const float* __restrict__ Wq2, const float* __restrict__ Wk2,
                            const float* __restrict__ Wv2,
                            float* __restrict__ Q2, float* __restrict__ Kc, float* __restrict__ Vc) {
    __shared__ float rows_[64 * 84];
    __shared__ float Wl[84 * 84];
    int blk = blockIdx.x;            // 0..1023
    int t, rb;
    if (blk < 256)      { t = 0; rb = blk; }
    else if (blk < 640) { t = 1; rb = blk - 256; }
    else                { t = 2; rb = blk - 640; }
    int row0 = rb * 64;
    int k = row0 >> 9;
    int s0 = row0 & 511;
    const float* W = (t == 0) ? Wq2 : (t == 1) ? Wk2 : Wv2;
    int tid = threadIdx.x;
    for (int i = tid; i < 64 * 84; i += 512) {
        int c = i % 84;
        rows_[i] = (c < 81) ? txall[(row0 + i / 84) * 81 + c] : 0.0f;
    }
    for (int i = tid; i < 84 * 84; i += 512) {
        int e = i / 84, hd = i % 84;
        Wl[i] = (e < 81 && hd < 81) ? W[(hd / 9) * 729 + e * 9 + (hd % 9)] : 0.0f;
    }
    __syncthreads();
    for (int o = tid; o < 336; o += 512) {
        int r4 = o / 21, cg = o % 21;
        int c0 = cg * 4;
        const float* rp = rows_ + r4 * 4 * 84;
        vf4 acc0 = 0.0f, acc1 = 0.0f, acc2 = 0.0f, acc3 = 0.0f;
        #pragma unroll 7
        for (int e = 0; e < 84; e += 4) {
            vf4 w0 = *(const vf4*)(Wl + (e + 0) * 84 + c0);
            vf4 w1 = *(const vf4*)(Wl + (e + 1) * 84 + c0);
            vf4 w2 = *(const vf4*)(Wl + (e + 2) * 84 + c0);
            vf4 w3 = *(const vf4*)(Wl + (e + 3) * 84 + c0);
            vf4 r0 = *(const vf4*)(rp + e);
            vf4 r1 = *(const vf4*)(rp + 84 + e);
            vf4 r2 = *(const vf4*)(rp + 168 + e);
            vf4 r3 = *(const vf4*)(rp + 252 + e);
            acc0 += r0[0] * w0 + r0[1] * w1 + r0[2] * w2 + r0[3] * w3;
            acc1 += r1[0] * w0 + r1[1] * w1 + r1[2] * w2 + r1[3] * w3;
            acc2 += r2[0] * w0 + r2[1] * w1 + r2[2] * w2 + r2[3] * w3;
            acc3 += r3[0] * w0 + r3[1] * w1 + r3[2] * w2 + r3[3] * w3;
        }
        vf4 av[4] = {acc0, acc1, acc2, acc3};
        #pragma unroll
        for (int cc = 0; cc < 4; cc++) {
            int col = c0 + cc;
            if (col < 81) {
                int h = col / 9, d = col % 9;
                #pragma unroll
                for (int rr = 0; rr < 4; rr++) {
                    int s = s0 + r4 * 4 + rr;
                    if (t == 0)      Q2[((s * 9 + h) * 32 + k) * 9 + d] = av[rr][cc];
                    else if (t == 1) Kc[((s * 9 + h) * 48 + k) * 9 + d] = av[rr][cc];
                    else             Vc[((s * 9 + h) * 48 + k) * 9 + d] = av[rr][cc];
                }
            }
        }
    }
}

// ---------------- attention-2 (masked: key==b or key>=32), no-max softmax (exp2) ----------------
__global__ void attn2_kernel(const float* __restrict__ Q2, const float* __restrict__ Kc,
                             const float* __restrict__ Vc, float* __restrict__ tmp2) {
    int tid = blockIdx.x * blockDim.x + threadIdx.x;
    if (tid >= 512 * 9 * 32) return;
    int b = tid & 31;
    int h = (tid >> 5) % 9;
    int s = tid / 288;
    const float* q = Q2 + ((s * 9 + h) * 32 + b) * 9;
    float qr[9];
    const float c2 = 1.4426950408889634f / 3.0f;   // log2e / 3
    #pragma unroll
    for (int d = 0; d < 9; d++) qr[d] = q[d] * c2;
    const float* Kb = Kc + (s * 9 + h) * 48 * 9;
    const float* Vb = Vc + (s * 9 + h) * 48 * 9;
    float l = 0.0f, outv[9];
    #pragma unroll
    for (int d = 0; d < 9; d++) outv[d] = 0.0f;
    #pragma unroll
    for (int j = 0; j < 17; j++) {
        int k = (j == 0) ? b : 31 + j;
        const float* kp = Kb + k * 9;
        float acc = 0.0f;
        #pragma unroll
        for (int d = 0; d < 9; d++) acc += qr[d] * kp[d];
        float p = exp2f(acc);
        l += p;
        const float* vp = Vb + k * 9;
        #pragma unroll
        for (int d = 0; d < 9; d++) outv[d] += p * vp[d];
    }
    float invl = 1.0f / l;
    float* op = tmp2 + (b * 512 + s) * 81 + h * 9;
    #pragma unroll
    for (int d = 0; d < 9; d++) op[d] = outv[d] * invl;
}

// ---------------- h2 = tmp2 @ Wo2 ; xh = tx + h2  (64 rows/block, 4x4 tile) ----------------
__global__ __launch_bounds__(512) void h2xh_kernel(const float* __restrict__ tmp2,
                            const float* __restrict__ Wo2, const float* __restrict__ txall,
                            float* __restrict__ h2, float* __restrict__ xh) {
    __shared__ float rows_[64 * 84];
    __shared__ float Wl[84 * 84];
    int row0 = blockIdx.x * 64;
    int tid = threadIdx.x;
    for (int i = tid; i < 64 * 84; i += 512) {
        int c = i % 84;
        rows_[i] = (c < 81) ? tmp2[(row0 + i / 84) * 81 + c] : 0.0f;
    }
    for (int i = tid; i < 84 * 84; i += 512) {
        int e = i / 84, c = i % 84;
        Wl[i] = (e < 81 && c < 81) ? Wo2[e * 81 + c] : 0.0f;
    }
    __syncthreads();
    for (int o = tid; o < 336; o += 512) {
        int r4 = o / 21, cg = o % 21;
        int c0 = cg * 4;
        const float* rp = rows_ + r4 * 4 * 84;
        vf4 acc0 = 0.0f, acc1 = 0.0f, acc2 = 0.0f, acc3 = 0.0f;
        #pragma unroll 7
        for (int e = 0; e < 84; e += 4) {
            vf4 w0 = *(const vf4*)(Wl + (e + 0) * 84 + c0);
            vf4 w1 = *(const vf4*)(Wl + (e + 1) * 84 + c0);
            vf4 w2 = *(const vf4*)(Wl + (e + 2) * 84 + c0);
            vf4 w3 = *(const vf4*)(Wl + (e + 3) * 84 + c0);
            vf4 r0 = *(const vf4*)(rp + e);
            vf4 r1 = *(const vf4*)(rp + 84 + e);
            vf4 r2 = *(const vf4*)(rp + 168 + e);
            vf4 r3 = *(const vf4*)(rp + 252 + e);
            acc0 += r0[0] * w0 + r0[1] * w1 + r0[2] * w2 + r0[3] * w3;
            acc1 += r1[0] * w0 + r1[1] * w1 + r1[2] * w2 + r1[3] * w3;
            acc2 += r2[0] * w0 + r2[1] * w1 + r2[2] * w2 + r2[3] * w3;
            acc3 += r3[0] * w0 + r3[1] * w1 + r3[2] * w2 + r3[3] * w3;
        }
        vf4 av[4] = {acc0, acc1, acc2, acc3};
        #pragma unroll
        for (int cc = 0; cc < 4; cc++) {
            int col = c0 + cc;
            if (col < 81) {
                #pragma unroll
                for (int rr = 0; rr < 4; rr++) {
                    int idx = (row0 + r4 * 4 + rr) * 81 + col;
                    float v = av[rr][cc];
                    h2[idx] = v;
                    xh[idx] = txall[idx] + v;
                }
            }
        }
    }
}

// ---------------- Qs/Ks (Vs == Qs): 64 rows/block, W-pass split (512 blocks), 4x4 ----------------
__global__ __launch_bounds__(512) void qks_kernel(const float* __restrict__ xh,
                           const float* __restrict__ Wq, const float* __restrict__ Wk,
                           float* __restrict__ Qs, float* __restrict__ Ks) {
    __shared__ float rows_[64 * 84];
    __shared__ float Wl[84 * 84];
    int blk = blockIdx.x;            // 0..511
    int t = blk >> 8;                // 0: Q, 1: K
    int rb = blk & 255;
    int row0 = rb * 64;
    int b = row0 >> 9;
    int s0 = row0 & 511;
    const float* W = (t == 0) ? Wq : Wk;
    int tid = threadIdx.x;
    for (int i = tid; i < 64 * 84; i += 512) {
        int c = i % 84;
        rows_[i] = (c < 81) ? xh[(row0 + i / 84) * 81 + c] : 0.0f;
    }
    for (int i = tid; i < 84 * 84; i += 512) {
        int e = i / 84, hd = i % 84;
        Wl[i] = (e < 81 && hd < 81) ? W[(hd / 9) * 729 + e * 9 + (hd % 9)] : 0.0f;
    }
    __syncthreads();
    float* dst = (t == 0) ? Qs : Ks;
    for (int o = tid; o < 336; o += 512) {
        int r4 = o / 21, cg = o % 21;
        int c0 = cg * 4;
        const float* rp = rows_ + r4 * 4 * 84;
        vf4 acc0 = 0.0f, acc1 = 0.0f, acc2 = 0.0f, acc3 = 0.0f;
        #pragma unroll 7
        for (int e = 0; e < 84; e += 4) {
            vf4 w0 = *(const vf4*)(Wl + (e + 0) * 84 + c0);
            vf4 w1 = *(const vf4*)(Wl + (e + 1) * 84 + c0);
            vf4 w2 = *(const vf4*)(Wl + (e + 2) * 84 + c0);
            vf4 w3 = *(const vf4*)(Wl + (e + 3) * 84 + c0);
            vf4 r0 = *(const vf4*)(rp + e);
            vf4 r1 = *(const vf4*)(rp + 84 + e);
            vf4 r2 = *(const vf4*)(rp + 168 + e);
            vf4 r3 = *(const vf4*)(rp + 252 + e);
            acc0 += r0[0] * w0 + r0[1] * w1 + r0[2] * w2 + r0[3] * w3;
            acc1 += r1[0] * w0 + r1[1] * w1 + r1[2] * w2 + r1[3] * w3;
            acc2 += r2[0] * w0 + r2[1] * w1 + r2[2] * w2 + r2[3] * w3;
            acc3 += r3[0] * w0 + r3[1] * w1 + r3[2] * w2 + r3[3] * w3;
        }
        vf4 av[4] = {acc0, acc1, acc2, acc3};
        #pragma unroll
        for (int cc = 0; cc < 4; cc++) {
            int col = c0 + cc;
            if (col < 81) {
                int h = col / 9, d = col % 9;
                #pragma unroll
                for (int rr = 0; rr < 4; rr++)
                    dst[((b * 9 + h) * 512 + (s0 + r4 * 4 + rr)) * 9 + d] = av[rr][cc];
            }
        }
    }
}

// ---------------- EBT[t*512+s] = exp(cw * (corr @ Cv)^T[t][s] / sqrt(S)) ----------------
__global__ __launch_bounds__(256) void biasmm_kernel(const float* __restrict__ corr,
                              const float* __restrict__ Cv, const float* __restrict__ cwp,
                              float* __restrict__ ebT) {
    __shared__ float As[32][33];
    __shared__ float Bs[32][33];
    int tx = threadIdx.x, ty = threadIdx.y;   // 16 x 16
    int tid = ty * 16 + tx;
    int t0 = blockIdx.y * 32, s0 = blockIdx.x * 32;
    float a00 = 0, a01 = 0, a10 = 0, a11 = 0;
    for (int k0 = 0; k0 < 512; k0 += 32) {
        for (int ii = tid; ii < 1024; ii += 256) {
            int r = ii >> 5, c = ii & 31;
            As[r][c] = Cv[(k0 + r) * 512 + t0 + c];
            Bs[r][c] = corr[(s0 + r) * 512 + k0 + c];
        }
        __syncthreads();
        #pragma unroll
        for (int kk = 0; kk < 32; kk++) {
            float b0 = Bs[tx][kk], b1 = Bs[tx + 16][kk];
            float c0 = As[kk][ty], c1 = As[kk][ty + 16];
            a00 += c0 * b0; a01 += c0 * b1; a10 += c1 * b0; a11 += c1 * b1;
        }
        __syncthreads();
    }
    float cws = cwp[0] * 0.04419417382415922f;   // cw / sqrt(512)
    ebT[(t0 + ty) * 512 + s0 + tx]            = __expf(a00 * cws);
    ebT[(t0 + ty) * 512 + s0 + tx + 16]       = __expf(a01 * cws);
    ebT[(t0 + ty + 16) * 512 + s0 + tx]       = __expf(a10 * cws);
    ebT[(t0 + ty + 16) * 512 + s0 + tx + 16]  = __expf(a11 * cws);
}

// ---------------- attention-1: no-max softmax (exp2), 4-way key split, atomic merge ----------------
__global__ __launch_bounds__(256) void attn1_kernel(const float* __restrict__ Qs,
                                                    const float* __restrict__ Ks,
                                                    const float* __restrict__ ebT,
                                                    const float* __restrict__ cwp,
                                                    float* __restrict__ part) {
    int blk = blockIdx.x;          // 0..2303
    int bh = blk >> 3;             // b*9+h
    int qhalf = (blk >> 2) & 1;
    int kq4 = blk & 3;
    int tid = threadIdx.x;
    const float* Kb = Ks + bh * 4608;
    const float* Qb = Qs + bh * 4608;
    int q = qhalf * 256 + tid;
    float c1 = (1.0f - cwp[0]) * (1.4426950408889634f / 3.0f);   // fold log2e
    vf2 qv[4];
    float q8;
    {
        const float* qp = Qb + q * 9;
        #pragma unroll
        for (int d = 0; d < 4; d++) {
            vf2 t; t.x = c1 * qp[2 * d]; t.y = c1 * qp[2 * d + 1];
            qv[d] = t;
        }
        q8 = c1 * qp[8];
    }
    float l = 0.0f, a8 = 0.0f;
    vf2 acc[4];
    #pragma unroll
    for (int d = 0; d < 4; d++) acc[d] = (vf2)0.0f;
    int k0 = kq4 * 128;            // block-uniform -> K/V scalar loads preserved
    const float* ebp = ebT + q;
    for (int t0 = k0; t0 < k0 + 128; t0 += 8) {
        float eb[8];
        #pragma unroll
        for (int j = 0; j < 8; j++) eb[j] = ebp[(t0 + j) << 9];
        #pragma unroll
        for (int j = 0; j < 8; j++) {
            const float* kr = Kb + (t0 + j) * 9;   // wave-uniform -> scalar loads
            const float* vr = Qb + (t0 + j) * 9;   // Vs == Qs
            vf2 k0v; k0v.x = kr[0]; k0v.y = kr[1];
            vf2 k1v; k1v.x = kr[2]; k1v.y = kr[3];
            vf2 k2v; k2v.x = kr[4]; k2v.y = kr[5];
            vf2 k3v; k3v.x = kr[6]; k3v.y = kr[7];
            vf2 u2 = qv[0] * k0v + qv[1] * k1v + qv[2] * k2v + qv[3] * k3v;
            float u = u2.x + u2.y + q8 * kr[8];
            float p = exp2f(u) * eb[j];
            l += p;
            vf2 p2; p2.x = p; p2.y = p;
            vf2 v0; v0.x = vr[0]; v0.y = vr[1];
            vf2 v1; v1.x = vr[2]; v1.y = vr[3];
            vf2 v2; v2.x = vr[4]; v2.y = vr[5];
            vf2 v3; v3.x = vr[6]; v3.y = vr[7];
            acc[0] += p2 * v0; acc[1] += p2 * v1;
            acc[2] += p2 * v2; acc[3] += p2 * v3;
            a8 += p * vr[8];
        }
    }
    int gidx = bh * 512 + q;
    atomicAdd(&part[gidx], l);
    #pragma unroll
    for (int d = 0; d < 4; d++) {
        atomicAdd(&part[(1 + 2 * d) * 147456 + gidx], acc[d].x);
        atomicAdd(&part[(2 + 2 * d) * 147456 + gidx], acc[d].y);
    }
    atomicAdd(&part[9 * 147456 + gidx], a8);
}

// ---------------- matin = (1-hw)*(h1@Wo1) + hw*h2 + tx ; merge fused, st1 fused ----------------
__global__ __launch_bounds__(512) void h1o_kernel(const float* __restrict__ apart,
                           const float* __restrict__ Wo1, const float* __restrict__ h2,
                           const float* __restrict__ txall, const float* __restrict__ hwp,
                           float* __restrict__ matin, float* __restrict__ st1) {
    __shared__ float rows_[64 * 84];
    __shared__ float Wl[84 * 84];
    __shared__ float ssum[81], ssq[81];
    int row0 = blockIdx.x * 64;
    int tid = threadIdx.x;
    if (tid < 81) { ssum[tid] = 0.0f; ssq[tid] = 0.0f; }
    // stage h1 rows from the (already-merged) atomic plane set
    for (int i = tid; i < 64 * 84; i += 512) {
        int r = i / 84, c = i % 84;
        float v = 0.0f;
        if (c < 81) {
            int row = row0 + r;             // b*512+s
            int b = row >> 9, s = row & 511;
            int h = c / 9, d = c % 9;
            int gidx = (b * 9 + h) * 512 + s;
            float L = apart[gidx];
            float A = apart[(1 + d) * 147456 + gidx];
            v = A / L;
        }
        rows_[i] = v;
    }
    for (int i = tid; i < 84 * 84; i += 512) {
        int e = i / 84, c = i % 84;
        Wl[i] = (e < 81 && c < 81) ? Wo1[e * 81 + c] : 0.0f;
    }
    __syncthreads();
    float hw = hwp[0];
    float onemhw = 1.0f - hw;
    for (int o = tid; o < 336; o += 512) {
        int r4 = o / 21, cg = o % 21;
        int c0 = cg * 4;
        const float* rp = rows_ + r4 * 4 * 84;
        vf4 acc0 = 0.0f, acc1 = 0.0f, acc2 = 0.0f, acc3 = 0.0f;
        #pragma unroll 7
        for (int e = 0; e < 84; e += 4) {
            vf4 w0 = *(const vf4*)(Wl + (e + 0) * 84 + c0);
            vf4 w1 = *(const vf4*)(Wl + (e + 1) * 84 + c0);
            vf4 w2 = *(const vf4*)(Wl + (e + 2) * 84 + c0);
            vf4 w3 = *(const vf4*)(Wl + (e + 3) * 84 + c0);
            vf4 r0 = *(const vf4*)(rp + e);
            vf4 r1 = *(const vf4*)(rp + 84 + e);
            vf4 r2 = *(const vf4*)(rp + 168 + e);
            vf4 r3 = *(const vf4*)(rp + 252 + e);
            acc0 += r0[0] * w0 + r0[1] * w1 + r0[2] * w2 + r0[3] * w3;
            acc1 += r1[0] * w0 + r1[1] * w1 + r1[2] * w2 + r1[3] * w3;
            acc2 += r2[0] * w0 + r2[1] * w1 + r2[2] * w2 + r2[3] * w3;
            acc3 += r3[0] * w0 + r3[1] * w1 + r3[2] * w2 + r3[3] * w3;
        }
        vf4 av[4] = {acc0, acc1, acc2, acc3};
        #pragma unroll
        for (int cc = 0; cc < 4; cc++) {
            int col = c0 + cc;
            if (col < 81) {
                float ls = 0.0f, lq = 0.0f;
                #pragma unroll
                for (int rr = 0; rr < 4; rr++) {
                    int idx = (row0 + r4 * 4 + rr) * 81 + col;
                    float v = onemhw * av[rr][cc] + hw * h2[idx] + txall[idx];
                    matin[idx] = v;
                    ls += v; lq += v * v;
                }
                atomicAdd(&ssum[col], ls);
                atomicAdd(&ssq[col], lq);
            }
        }
    }
    __syncthreads();
    if (tid < 81) {
        atomicAdd(&st1[tid], ssum[tid]);
        atomicAdd(&st1[81 + tid], ssq[tid]);
    }
}

// ---------------- ff1: 64 rows x 64 cols/block, 4x4 tile ; fused st2 ----------------
__global__ __launch_bounds__(512) void ff1_kernel(const float* __restrict__ matin,
                           const float* __restrict__ st1, const float* __restrict__ g1,
                           const float* __restrict__ b1, const float* __restrict__ W,
                           const float* __restrict__ bias, float* __restrict__ f1,
                           float* __restrict__ st2) {
    __shared__ float rows_[64 * 84];
    __shared__ float Wl[84 * 64];       // rows 81..83 zero
    __shared__ float s2s[64], s2q[64];
    int row0 = blockIdx.x * 64;
    int cb = blockIdx.y * 64;
    int tid = threadIdx.x;
    const float invN = 1.0f / 16384.0f;
    if (tid < 64) { s2s[tid] = 0.0f; s2q[tid] = 0.0f; }
    for (int i = tid; i < 64 * 84; i += 512) {
        int c = i % 84;
        float v = 0.0f;
        if (c < 81) {
            float mean = st1[c] * invN;
            float var = st1[81 + c] * invN - mean * mean;
            v = (matin[(row0 + i / 84) * 81 + c] - mean) * rsqrtf(var + EPSV) * g1[c] + b1[c];
        }
        rows_[i] = v;
    }
    for (int i = tid; i < 84 * 64; i += 512) {
        int e = i >> 6, cc = i & 63;
        Wl[i] = (e < 81) ? W[e * 256 + cb + cc] : 0.0f;
    }
    __syncthreads();
    if (tid < 256) {
        int o = tid;                 // 256 tasks: 16 r-groups x 16 c-groups
        int r4 = o >> 4, cg = o & 15;
        int c0 = cg * 4;
        const float* rp = rows_ + r4 * 4 * 84;
        vf4 acc0 = 0.0f, acc1 = 0.0f, acc2 = 0.0f, acc3 = 0.0f;
        #pragma unroll 7
        for (int e = 0; e < 84; e += 4) {
            vf4 w0 = *(const vf4*)(Wl + ((e + 0) << 6) + c0);
            vf4 w1 = *(const vf4*)(Wl + ((e + 1) << 6) + c0);
            vf4 w2 = *(const vf4*)(Wl + ((e + 2) << 6) + c0);
            vf4 w3 = *(const vf4*)(Wl + ((e + 3) << 6) + c0);
            vf4 r0 = *(const vf4*)(rp + e);
            vf4 r1 = *(const vf4*)(rp + 84 + e);
            vf4 r2 = *(const vf4*)(rp + 168 + e);
            vf4 r3 = *(const vf4*)(rp + 252 + e);
            acc0 += r0[0] * w0 + r0[1] * w1 + r0[2] * w2 + r0[3] * w3;
            acc1 += r1[0] * w0 + r1[1] * w1 + r1[2] * w2 + r1[3] * w3;
            acc2 += r2[0] * w0 + r2[1] * w1 + r2[2] * w2 + r2[3] * w3;
            acc3 += r3[0] * w0 + r3[1] * w1 + r3[2] * w2 + r3[3] * w3;
        }
        vf4 bv = *(const vf4*)(bias + cb + c0);
        acc0 = __builtin_elementwise_max(acc0 + bv, (vf4)0.0f);
        acc1 = __builtin_elementwise_max(acc1 + bv, (vf4)0.0f);
        acc2 = __builtin_elementwise_max(acc2 + bv, (vf4)0.0f);
        acc3 = __builtin_elementwise_max(acc3 + bv, (vf4)0.0f);
        int base = (row0 + r4 * 4) * 256 + cb + c0;
        *(vf4*)(f1 + base)       = acc0;
        *(vf4*)(f1 + base + 256) = acc1;
        *(vf4*)(f1 + base + 512) = acc2;
        *(vf4*)(f1 + base + 768) = acc3;
        vf4 cs = acc0 + acc1 + acc2 + acc3;
        vf4 cq = acc0 * acc0 + acc1 * acc1 + acc2 * acc2 + acc3 * acc3;
        #pragma unroll
        for (int cc = 0; cc < 4; cc++) {
            atomicAdd(&s2s[c0 + cc], cs[cc]);
            atomicAdd(&s2q[c0 + cc], cq[cc]);
        }
    }
    __syncthreads();
    if (tid < 64) {
        atomicAdd(&st2[cb + tid], s2s[tid]);
        atomicAdd(&st2[256 + cb + tid], s2q[tid]);
    }
}

// ---------------- ff2: 32 rows/block, 4 K-quarter passes, 4x4 tile ; fused st3 ----------------
__global__ __launch_bounds__(256) void ff2_kernel(const float* __restrict__ f1,
                           const float* __restrict__ st2, const float* __restrict__ g2,
                           const float* __restrict__ b2, const float* __restrict__ W,
                           const float* __restrict__ bias, const float* __restrict__ matin,
                           const float* __restrict__ st1, const float* __restrict__ g1,
                           const float* __restrict__ b1, float* __restrict__ t3,
                           float* __restrict__ st3) {
    __shared__ float rows_[32 * 64];
    __shared__ float Wl[64 * 84];
    __shared__ float s3s[81], s3q[81];
    int row0 = blockIdx.x * 32;
    int tid = threadIdx.x;
    const float invN = 1.0f / 16384.0f;
    if (tid < 81) { s3s[tid] = 0.0f; s3q[tid] = 0.0f; }
    int o = tid;
    int r4 = o / 21, cg = o % 21;
    int c0 = cg * 4;
    bool active = (o < 168);
    vf4 acc0 = 0.0f, acc1 = 0.0f, acc2 = 0.0f, acc3 = 0.0f;
    for (int kq = 0; kq < 4; kq++) {
        __syncthreads();
        for (int i = tid; i < 32 * 64; i += 256) {
            int r = i >> 6, e = i & 63;
            int c = kq * 64 + e;
            float mean = st2[c] * invN;
            float var = st2[256 + c] * invN - mean * mean;
            rows_[i] = (f1[(row0 + r) * 256 + c] - mean) * rsqrtf(var + EPSV) * g2[c] + b2[c];
        }
        for (int i = tid; i < 64 * 84; i += 256) {
            int e = i / 84, c = i % 84;
            Wl[i] = (c < 81) ? W[(kq * 64 + e) * 81 + c] : 0.0f;
        }
        __syncthreads();
        if (active) {
            const float* rp = rows_ + r4 * 4 * 64;
            #pragma unroll 8
            for (int e = 0; e < 64; e += 4) {
                vf4 w0 = *(const vf4*)(Wl + (e + 0) * 84 + c0);
                vf4 w1 = *(const vf4*)(Wl + (e + 1) * 84 + c0);
                vf4 w2 = *(const vf4*)(Wl + (e + 2) * 84 + c0);
                vf4 w3 = *(const vf4*)(Wl + (e + 3) * 84 + c0);
                vf4 r0 = *(const vf4*)(rp + e);
                vf4 r1 = *(const vf4*)(rp + 64 + e);
                vf4 r2 = *(const vf4*)(rp + 128 + e);
                vf4 r3 = *(const vf4*)(rp + 192 + e);
                acc0 += r0[0] * w0 + r0[1] * w1 + r0[2] * w2 + r0[3] * w3;
                acc1 += r1[0] * w0 + r1[1] * w1 + r1[2] * w2 + r1[3] * w3;
                acc2 += r2[0] * w0 + r2[1] * w1 + r2[2] * w2 + r2[3] * w3;
                acc3 += r3[0] * w0 + r3[1] * w1 + r3[2] * w2 + r3[3] * w3;
            }
        }
    }
    if (active) {
        vf4 av[4] = {acc0, acc1, acc2, acc3};
        #pragma unroll
        for (int cc = 0; cc < 4; cc++) {
            int col = c0 + cc;
            if (col < 81) {
                float mean = st1[col] * invN;
                float var = st1[81 + col] * invN - mean * mean;
                float rstd = rsqrtf(var + EPSV);
                float bval = bias[col];
                float ls = 0.0f, lq = 0.0f;
                #pragma unroll
                for (int rr = 0; rr < 4; rr++) {
                    int idx = (row0 + r4 * 4 + rr) * 81 + col;
                    float ma = (matin[idx] - mean) * rstd * g1[col] + b1[col];
                    float v = ma + fmaxf(av[rr][cc] + bval, 0.0f);
                    t3[idx] = v;
                    ls += v; lq += v * v;
                }
                atomicAdd(&s3s[col], ls);
                atomicAdd(&s3q[col], lq);
            }
        }
    }
    __syncthreads();
    if (tid < 81) {
        atomicAdd(&st3[tid], s3s[tid]);
        atomicAdd(&st3[81 + tid], s3q[tid]);
    }
}

// ---------------- token_mm: u/v dual GEMM (64 rows/block, W-pass split, 4x4 tile) ----------------
__global__ __launch_bounds__(512) void token_mm(const float* __restrict__ t3,
                            const float* __restrict__ st3, const float* __restrict__ g3,
                            const float* __restrict__ b3, const float* __restrict__ tvw,
                            const float* __restrict__ beta1,
                            float* __restrict__ uv0, float* __restrict__ uv1) {
    __shared__ float rows_[64 * 84];
    __shared__ float Wl[84 * 84];
    int blk = blockIdx.x;            // 0..511
    int t = blk >> 8;
    int row0 = (blk & 255) * 64;
    const float* W = (t == 0) ? tvw : beta1;
    float* dst = (t == 0) ? uv0 : uv1;
    int tid = threadIdx.x;
    const float invN = 1.0f / 16384.0f;
    for (int i = tid; i < 64 * 84; i += 512) {
        int c = i % 84;
        float v = 0.0f;
        if (c < 81) {
            float mean = st3[c] * invN;
            float var = st3[81 + c] * invN - mean * mean;
            v = (t3[(row0 + i / 84) * 81 + c] - mean) * rsqrtf(var + EPSV) * g3[c] + b3[c];
        }
        rows_[i] = v;
    }
    for (int i = tid; i < 84 * 84; i += 512) {
        int e = i / 84, c = i % 84;
        Wl[i] = (e < 81 && c < 81) ? W[e * 81 + c] : 0.0f;
    }
    __syncthreads();
    for (int o = tid; o < 336; o += 512) {
        int r4 = o / 21, cg = o % 21;
        int c0 = cg * 4;
        const float* rp = rows_ + r4 * 4 * 84;
        vf4 acc0 = 0.0f, acc1 = 0.0f, acc2 = 0.0f, acc3 = 0.0f;
        #pragma unroll 7
        for (int e = 0; e < 84; e += 4) {
            vf4 w0 = *(const vf4*)(Wl + (e + 0) * 84 + c0);
            vf4 w1 = *(const vf4*)(Wl + (e + 1) * 84 + c0);
            vf4 w2 = *(const vf4*)(Wl + (e + 2) * 84 + c0);
            vf4 w3 = *(const vf4*)(Wl + (e + 3) * 84 + c0);
            vf4 r0 = *(const vf4*)(rp + e);
            vf4 r1 = *(const vf4*)(rp + 84 + e);
            vf4 r2 = *(const vf4*)(rp + 168 + e);
            vf4 r3 = *(const vf4*)(rp + 252 + e);
            acc0 += r0[0] * w0 + r0[1] * w1 + r0[2] * w2 + r0[3] * w3;
            acc1 += r1[0] * w0 + r1[1] * w1 + r1[2] * w2 + r1[3] * w3;
            acc2 += r2[0] * w0 + r2[1] * w1 + r2[2] * w2 + r2[3] * w3;
            acc3 += r3[0] * w0 + r3[1] * w1 + r3[2] * w2 + r3[3] * w3;
        }
        vf4 av[4] = {acc0, acc1, acc2, acc3};
        #pragma unroll
        for (int cc = 0; cc < 4; cc++) {
            int col = c0 + cc;
            if (col < 81) {
                #pragma unroll
                for (int rr = 0; rr < 4; rr++)
                    dst[(row0 + r4 * 4 + rr) * 81 + col] = av[rr][cc];
            }
        }
    }
}

// ---------------- token_pool: softmax-pool over 81, 32 rows/block, 8 lanes/row ----------------
__global__ __launch_bounds__(256) void token_pool(const float* __restrict__ uv0,
                             const float* __restrict__ uv1, const float* __restrict__ tvb,
                             const float* __restrict__ basel, const float* __restrict__ a1p,
                             const float* __restrict__ a2p, float* __restrict__ fea) {
    int tid = threadIdx.x;
    int r = tid >> 3, j = tid & 7;
    int row = blockIdx.x * 32 + r;
    int base = row * 81;
    float u[11], v[11];
    #pragma unroll
    for (int dd = 0; dd < 11; dd++) {
        int d = j + dd * 8;
        if (d < 81) {
            u[dd] = uv0[base + d] + tvb[d];
            v[dd] = uv1[base + d];
        } else {
            u[dd] = 0.0f; v[dd] = -1e30f;
        }
    }
    float mx = -1e30f;
    #pragma unroll
    for (int dd = 0; dd < 11; dd++) mx = fmaxf(mx, v[dd]);
    #pragma unroll
    for (int msk = 1; msk < 8; msk <<= 1) mx = fmaxf(mx, __shfl_xor(mx, msk, 8));
    float sp = 0.0f, sup = 0.0f;
    #pragma unroll
    for (int dd = 0; dd < 11; dd++) {
        float p = __expf(v[dd] - mx);
        sp += p; sup += u[dd] * p;
    }
    #pragma unroll
    for (int msk = 1; msk < 8; msk <<= 1) {
        sp  += __shfl_xor(sp, msk, 8);
        sup += __shfl_xor(sup, msk, 8);
    }
    if (j == 0) {
        int b = row >> 9, s = row & 511;
        fea[row] = a1p[0] * (sup / sp) + a2p[0] * basel[b * 2048 + s * 4];
    }
}

// ---------------- fc1: relu(fea @ W + b), fused st4 ----------------
__global__ void fc1_kernel(const float* __restrict__ in, const float* __restrict__ W,
                           const float* __restrict__ bias, float* __restrict__ out,
                           float* __restrict__ st) {
    int idx = blockIdx.x * blockDim.x + threadIdx.x;
    if (idx >= 32 * 512) return;
    int b = idx >> 9, j = idx & 511;
    float acc = bias[j];
    const float* ip = in + (b << 9);
    #pragma unroll 8
    for (int k = 0; k < 512; k++) acc += ip[k] * W[k * 512 + j];
    acc = fmaxf(acc, 0.0f);
    out[idx] = acc;
    atomicAdd(&st[j], acc);
    atomicAdd(&st[512 + j], acc * acc);
}

// ---------------- fc2: relu(bn(fch1) @ W + b), fused st5 ----------------
__global__ __launch_bounds__(256) void fc2_kernel(const float* __restrict__ in,
                           const float* __restrict__ st4, const float* __restrict__ g,
                           const float* __restrict__ bb, const float* __restrict__ W,
                           const float* __restrict__ bias, float* __restrict__ out,
                           float* __restrict__ st5) {
    __shared__ float scale[512], shift[512];
    int tid = threadIdx.x;
    for (int k = tid; k < 512; k += 256) {
        float mean = st4[k] * (1.0f / 32.0f);
        float var = st4[512 + k] * (1.0f / 32.0f) - mean * mean;
        float sc_ = rsqrtf(var + EPSV) * g[k];
        scale[k] = sc_;
        shift[k] = bb[k] - mean * sc_;
    }
    __syncthreads();
    int idx = blockIdx.x * 256 + tid;
    if (idx >= 32 * 256) return;
    int b = idx >> 8, j = idx & 255;
    float acc = bias[j];
    const float* ip = in + (b << 9);
    #pragma unroll 8
    for (int k = 0; k < 512; k++) acc += (ip[k] * scale[k] + shift[k]) * W[k * 256 + j];
    acc = fmaxf(acc, 0.0f);
    out[idx] = acc;
    atomicAdd(&st5[j], acc);
    atomicAdd(&st5[256 + j], acc * acc);
}

// ---------------- fc3: tanh(bn(fch2) @ W + b) ----------------
__global__ void fc3_kernel(const float* __restrict__ in, const float* __restrict__ st5,
                           const float* __restrict__ g, const float* __restrict__ bb,
                           const float* __restrict__ W, const float* __restrict__ bias,
                           float* __restrict__ out) {
    __shared__ float scale[256], shift[256];
    int tid = threadIdx.x;   // 128
    for (int k = tid; k < 256; k += 128) {
        float mean = st5[k] * (1.0f / 32.0f);
        float var = st5[256 + k] * (1.0f / 32.0f) - mean * mean;
        float sc_ = rsqrtf(var + EPSV) * g[k];
        scale[k] = sc_;
        shift[k] = bb[k] - mean * sc_;
    }
    __syncthreads();
    int b = tid >> 2, j = tid & 3;
    float acc = bias[j];
    const float* ip = in + (b << 8);
    #pragma unroll 8
    for (int k = 0; k < 256; k++) acc += (ip[k] * scale[k] + shift[k]) * W[k * 4 + j];
    out[tid] = tanhf(acc);
}

// =======================================================================
extern "C" void kernel_launch(void* const* d_in, const int* in_sizes, int n_in,
                              void* d_out, int out_size, void* d_ws, size_t ws_size,
                              hipStream_t stream) {
    const float* x       = (const float*)d_in[0];
    const float* basel   = (const float*)d_in[1];
    const float* cali    = (const float*)d_in[2];
    const float* Wq      = (const float*)d_in[3];
    const float* Wk      = (const float*)d_in[4];
    const float* Wq2     = (const float*)d_in[5];
    const float* Wk2     = (const float*)d_in[6];
    const float* Wv2     = (const float*)d_in[7];
    const float* Cv      = (const float*)d_in[8];
    const float* Wo1     = (const float*)d_in[9];
    const float* Wo2     = (const float*)d_in[10];
    const float* corr_w  = (const float*)d_in[11];
    const float* h_w     = (const float*)d_in[12];
    const float* corr    = (const float*)d_in[13];
    const float* g1      = (const float*)d_in[14];
    const float* b1      = (const float*)d_in[15];
    const float* ff1_w   = (const float*)d_in[16];
    const float* ff1_b   = (const float*)d_in[17];
    const float* g2      = (const float*)d_in[18];
    const float* b2      = (const float*)d_in[19];
    const float* ff2_w   = (const float*)d_in[20];
    const float* ff2_b   = (const float*)d_in[21];
    const float* g3      = (const float*)d_in[22];
    const float* b3      = (const float*)d_in[23];
    const float* tvw     = (const float*)d_in[24];
    const float* tvb     = (const float*)d_in[25];
    const float* beta1   = (const float*)d_in[26];
    const float* a1      = (const float*)d_in[27];
    const float* a2      = (const float*)d_in[28];
    const float* fc1_w   = (const float*)d_in[29];
    const float* fc1_b   = (const float*)d_in[30];
    const float* bnf1_g  = (const float*)d_in[31];
    const float* bnf1_b  = (const float*)d_in[32];
    const float* fc2_w   = (const float*)d_in[33];
    const float* fc2_b   = (const float*)d_in[34];
    const float* bnf2_g  = (const float*)d_in[35];
    const float* bnf2_b  = (const float*)d_in[36];
    const float* fc3_w   = (const float*)d_in[37];
    const float* fc3_b   = (const float*)d_in[38];
    float* out = (float*)d_out;
    float* ws = (float*)d_ws;

    // ---- workspace layout (float offsets) ----
    const size_t SCAL  = 0;         // 2
    const size_t PART  = 16;        // 128
    const size_t ST1   = 512;       // 162
    const size_t ST2   = 768;       // 512
    const size_t ST3   = 1536;      // 162
    const size_t ST4   = 1792;      // 1024
    const size_t ST5   = 2880;      // 512
    const size_t FEA   = 4096;      // 16384
    const size_t FCH1  = 20480;     // 16384
    const size_t FCH2  = 36864;     // 8192
    const size_t PEO   = 45056;     // 41472
    const size_t TX    = 90112;     // 1990656
    const size_t Q2O   = 2080768;   // 1327104
    const size_t KCO   = 3407872;   // 1990656   (reused: Qs)
    const size_t VCO   = 5398528;   // 1990656   (reused: Ks)
    const size_t TMP2  = 7389184;   // 1327104   (reused: matin, then uv0)
    const size_t H2O   = 8716288;   // 1327104   (reused: t3)
    const size_t XHO   = 10043392;  // 1327104   (xh, dead after qks -> uv1)
    const size_t BIASO = 11370496;  // 262144    (EBT)
    const size_t F1O   = 11632640;  // 4194304   (f1; also attn1 planes 1474560)

    float* scal  = ws + SCAL;
    float* part  = ws + PART;
    float* st1   = ws + ST1;
    float* st2   = ws + ST2;
    float* st3   = ws + ST3;
    float* st4   = ws + ST4;
    float* st5   = ws + ST5;
    float* fea   = ws + FEA;
    float* fch1  = ws + FCH1;
    float* fch2  = ws + FCH2;
    float* pe    = ws + PEO;
    float* txall = ws + TX;
    float* Q2    = ws + Q2O;
    float* Kc    = ws + KCO;
    float* Vc    = ws + VCO;
    float* tmp2  = ws + TMP2;
    float* h2    = ws + H2O;
    float* xh    = ws + XHO;
    float* ebT   = ws + BIASO;
    float* f1    = ws + F1O;
    float* Qs    = Kc;     // reuse
    float* Ks    = Vc;     // reuse
    float* matin = tmp2;   // reuse (dead after ff2 -> uv0)
    float* t3    = h2;     // reuse
    float* apart = f1;     // attn1 atomic planes (10 x 147456 floats) in f1 region
    float* uv0   = tmp2;   // token u plane (matin dead after ff2)
    float* uv1   = xh;     // token v plane (xh dead after qks)

    // zero scal/part/stats region — capture-safe
    hipMemsetAsync(ws, 0, 4096 * sizeof(float), stream);
    // zero attn1 atomic planes (5.9 MB)
    hipMemsetAsync(apart, 0, 1474560 * sizeof(float), stream);

    minmax_part<<<64, 256, 0, stream>>>(x, part);
    minmax_fin<<<1, 64, 0, stream>>>(part, scal);

    pe_kernel<<<(512 * 81 + 255) / 256, 256, 0, stream>>>(pe);

    tokenize_kernel<<<(48 * 512 * 81 + 255) / 256, 256, 0, stream>>>(x, cali, scal, pe, txall);

    qkv2_kernel<<<1024, 512, 0, stream>>>(txall, Wq2, Wk2, Wv2, Q2, Kc, Vc);

    attn2_kernel<<<(512 * 9 * 32) / 256, 256, 0, stream>>>(Q2, Kc, Vc, tmp2);

    h2xh_kernel<<<256, 512, 0, stream>>>(tmp2, Wo2, txall, h2, xh);

    qks_kernel<<<512, 512, 0, stream>>>(xh, Wq, Wk, Qs, Ks);

    biasmm_kernel<<<dim3(16, 16), dim3(16, 16), 0, stream>>>(corr, Cv, corr_w, ebT);

    attn1_kernel<<<2304, 256, 0, stream>>>(Qs, Ks, ebT, corr_w, apart);

    h1o_kernel<<<256, 512, 0, stream>>>(apart, Wo1, h2, txall, h_w, matin, st1);

    ff1_kernel<<<dim3(256, 4), 512, 0, stream>>>(matin, st1, g1, b1, ff1_w, ff1_b, f1, st2);

    ff2_kernel<<<512, 256, 0, stream>>>(f1, st2, g2, b2, ff2_w, ff2_b,
                                        matin, st1, g1, b1, t3, st3);

    token_mm<<<512, 512, 0, stream>>>(t3, st3, g3, b3, tvw, beta1, uv0, uv1);
    token_pool<<<512, 256, 0, stream>>>(uv0, uv1, tvb, basel, a1, a2, fea);

    fc1_kernel<<<64, 256, 0, stream>>>(fea, fc1_w, fc1_b, fch1, st4);

    fc2_kernel<<<32, 256, 0, stream>>>(fch1, st4, bnf1_g, bnf1_b, fc2_w, fc2_b, fch2, st5);

    fc3_kernel<<<1, 128, 0, stream>>>(fch2, st5, bnf2_g, bnf2_b, fc3_w, fc3_b, out);
}

// Round 18
// 410.261 us; speedup vs baseline: 1.3883x; 1.0320x over previous
//
#include <hip/hip_runtime.h>
#include <hip/hip_bf16.h>
#include <math.h>

#define EPSV 1e-5f

typedef float vf2 __attribute__((ext_vector_type(2)));
typedef float vf4 __attribute__((ext_vector_type(4)));

// ---------------- sizes ----------------
// B=32 Bc=16 L=2048 TOKEN=40 STRIDE=4 D=81 H=9 dk=9 S=512 FF=256 FC1=512 FC2=256 Y=4

// ---------------- minmax: two-stage ----------------
__global__ void minmax_part(const float* __restrict__ x, float* __restrict__ part) {
    __shared__ float smin[256], smax[256];
    int tid = threadIdx.x;
    float mn = 1e30f, mx = -1e30f;
    for (int i = blockIdx.x * 256 + tid; i < 32 * 2008; i += 64 * 256) {
        int b = i / 2008, c = i % 2008 + 20;
        float v = x[b * 2048 + c];
        mn = fminf(mn, v); mx = fmaxf(mx, v);
    }
    smin[tid] = mn; smax[tid] = mx; __syncthreads();
    for (int off = 128; off > 0; off >>= 1) {
        if (tid < off) { smin[tid] = fminf(smin[tid], smin[tid + off]); smax[tid] = fmaxf(smax[tid], smax[tid + off]); }
        __syncthreads();
    }
    if (tid == 0) { part[blockIdx.x] = smin[0]; part[64 + blockIdx.x] = smax[0]; }
}

__global__ void minmax_fin(const float* __restrict__ part, float* __restrict__ scal) {
    __shared__ float smn[64], smx[64];
    int tid = threadIdx.x;
    smn[tid] = part[tid]; smx[tid] = part[64 + tid]; __syncthreads();
    for (int off = 32; off > 0; off >>= 1) {
        if (tid < off) { smn[tid] = fminf(smn[tid], smn[tid + off]); smx[tid] = fmaxf(smx[tid], smx[tid + off]); }
        __syncthreads();
    }
    if (tid == 0) { scal[0] = smn[0]; scal[1] = smx[0] - smn[0]; }
}

// ---------------- PE table (512 x 81) ----------------
__global__ void pe_kernel(float* __restrict__ pe) {
    int idx = blockIdx.x * blockDim.x + threadIdx.x;
    if (idx >= 512 * 81) return;
    int d = idx % 81, s = idx / 81;
    int j = d >> 1;
    float dv = __expf(-9.210340371976184f * (2.0f * (float)j) / 81.0f);
    float ang = (float)s * dv;
    pe[idx] = (d & 1) ? cosf(ang) : sinf(ang);
}

// ---------------- tokenize + add PE ----------------
__global__ void tokenize_kernel(const float* __restrict__ x, const float* __restrict__ cali,
                                const float* __restrict__ scal, const float* __restrict__ pe,
                                float* __restrict__ txall) {
    int idx = blockIdx.x * blockDim.x + threadIdx.x;
    if (idx >= 48 * 512 * 81) return;
    int d = idx % 81;
    int s = (idx / 81) % 512;
    int r = idx / (81 * 512);
    float xm = scal[0], inv_xs = 1.0f / scal[1];
    int oc = s * 4 + d - 40;
    float val = 0.0f;
    if (oc >= 0 && oc < 2048) {
        float sv = (r < 32) ? x[r * 2048 + oc] : cali[(r - 32) * 2048 + oc];
        val = (sv - xm) * inv_xs;
    }
    txall[idx] = val + pe[s * 81 + d];
}

// ======== 4x4-tile 81->81 GEMM pieces (rows stride 84, W [e][col] stride 84) ========
// 512 threads/block: staging strides 512, compute single pass (336 tasks of 512 threads)

// ---------------- qkv2: 64 rows/block, W-pass split (1024 blocks), 4x4 tile ----------------
__global__ __launch_bounds__(512) void qkv2_kernel(const float* __restrict__ txall,
                            const float* __restrict__ Wq2, const float* __restrict__ Wk2,
                            const float* __restrict__ Wv2,
                            float* __restrict__ Q2, float* __restrict__ Kc, float* __restrict__ Vc) {
    __shared__ float rows_[64 * 84];
    __shared__ float Wl[84 * 84];
    int blk = blockIdx.x;            // 0..1023
    int t, rb;
    if (blk < 256)      { t = 0; rb = blk; }
    else if (blk < 640) { t = 1; rb = blk - 256; }
    else                { t = 2; rb = blk - 640; }
    int row0 = rb * 64;
    int k = row0 >> 9;
    int s0 = row0 & 511;
    const float* W = (t == 0) ? Wq2 : (t == 1) ? Wk2 : Wv2;
    int tid = threadIdx.x;
    for (int i = tid; i < 64 * 84; i += 512) {
        int c = i % 84;
        rows_[i] = (c < 81) ? txall[(row0 + i / 84) * 81 + c] : 0.0f;
    }
    for (int i = tid; i < 84 * 84; i += 512) {
        int e = i / 84, hd = i % 84;
        Wl[i] = (e < 81 && hd < 81) ? W[(hd / 9) * 729 + e * 9 + (hd % 9)] : 0.0f;
    }
    __syncthreads();
    for (int o = tid; o < 336; o += 512) {
        int r4 = o / 21, cg = o % 21;
        int c0 = cg * 4;
        const float* rp = rows_ + r4 * 4 * 84;
        vf4 acc0 = 0.0f, acc1 = 0.0f, acc2 = 0.0f, acc3 = 0.0f;
        #pragma unroll 7
        for (int e = 0; e < 84; e += 4) {
            vf4 w0 = *(const vf4*)(Wl + (e + 0) * 84 + c0);
            vf4 w1 = *(const vf4*)(Wl + (e + 1) * 84 + c0);
            vf4 w2 = *(const vf4*)(Wl + (e + 2) * 84 + c0);
            vf4 w3 = *(const vf4*)(Wl + (e + 3) * 84 + c0);
            vf4 r0 = *(const vf4*)(rp + e);
            vf4 r1 = *(const vf4*)(rp + 84 + e);
            vf4 r2 = *(const vf4*)(rp + 168 + e);
            vf4 r3 = *(const vf4*)(rp + 252 + e);
            acc0 += r0[0] * w0 + r0[1] * w1 + r0[2] * w2 + r0[3] * w3;
            acc1 += r1[0] * w0 + r1[1] * w1 + r1[2] * w2 + r1[3] * w3;
            acc2 += r2[0] * w0 + r2[1] * w1 + r2[2] * w2 + r2[3] * w3;
            acc3 += r3[0] * w0 + r3[1] * w1 + r3[2] * w2 + r3[3] * w3;
        }
        vf4 av[4] = {acc0, acc1, acc2, acc3};
        #pragma unroll
        for (int cc = 0; cc < 4; cc++) {
            int col = c0 + cc;
            if (col < 81) {
                int h = col / 9, d = col % 9;
                #pragma unroll
                for (int rr = 0; rr < 4; rr++) {
                    int s = s0 + r4 * 4 + rr;
                    if (t == 0)      Q2[((s * 9 + h) * 32 + k) * 9 + d] = av[rr][cc];
                    else if (t == 1) Kc[((s * 9 + h) * 48 + k) * 9 + d] = av[rr][cc];
                    else             Vc[((s * 9 + h) * 48 + k) * 9 + d] = av[rr][cc];
                }
            }
        }
    }
}

// ---------------- attention-2 (masked: key==b or key>=32), no-max softmax (exp2) ----------------
__global__ void attn2_kernel(const float* __restrict__ Q2, const float* __restrict__ Kc,
                             const float* __restrict__ Vc, float* __restrict__ tmp2) {
    int tid = blockIdx.x * blockDim.x + threadIdx.x;
    if (tid >= 512 * 9 * 32) return;
    int b = tid & 31;
    int h = (tid >> 5) % 9;
    int s = tid / 288;
    const float* q = Q2 + ((s * 9 + h) * 32 + b) * 9;
    float qr[9];
    const float c2 = 1.4426950408889634f / 3.0f;   // log2e / 3
    #pragma unroll
    for (int d = 0; d < 9; d++) qr[d] = q[d] * c2;
    const float* Kb = Kc + (s * 9 + h) * 48 * 9;
    const float* Vb = Vc + (s * 9 + h) * 48 * 9;
    float l = 0.0f, outv[9];
    #pragma unroll
    for (int d = 0; d < 9; d++) outv[d] = 0.0f;
    #pragma unroll
    for (int j = 0; j < 17; j++) {
        int k = (j == 0) ? b : 31 + j;
        const float* kp = Kb + k * 9;
        float acc = 0.0f;
        #pragma unroll
        for (int d = 0; d < 9; d++) acc += qr[d] * kp[d];
        float p = exp2f(acc);
        l += p;
        const float* vp = Vb + k * 9;
        #pragma unroll
        for (int d = 0; d < 9; d++) outv[d] += p * vp[d];
    }
    float invl = 1.0f / l;
    float* op = tmp2 + (b * 512 + s) * 81 + h * 9;
    #pragma unroll
    for (int d = 0; d < 9; d++) op[d] = outv[d] * invl;
}

// ---------------- h2 = tmp2 @ Wo2 ; xh = tx + h2  (64 rows/block, 4x4 tile) ----------------
__global__ __launch_bounds__(512) void h2xh_kernel(const float* __restrict__ tmp2,
                            const float* __restrict__ Wo2, const float* __restrict__ txall,
                            float* __restrict__ h2, float* __restrict__ xh) {
    __shared__ float rows_[64 * 84];
    __shared__ float Wl[84 * 84];
    int row0 = blockIdx.x * 64;
    int tid = threadIdx.x;
    for (int i = tid; i < 64 * 84; i += 512) {
        int c = i % 84;
        rows_[i] = (c < 81) ? tmp2[(row0 + i / 84) * 81 + c] : 0.0f;
    }
    for (int i = tid; i < 84 * 84; i += 512) {
        int e = i / 84, c = i % 84;
        Wl[i] = (e < 81 && c < 81) ? Wo2[e * 81 + c] : 0.0f;
    }
    __syncthreads();
    for (int o = tid; o < 336; o += 512) {
        int r4 = o / 21, cg = o % 21;
        int c0 = cg * 4;
        const float* rp = rows_ + r4 * 4 * 84;
        vf4 acc0 = 0.0f, acc1 = 0.0f, acc2 = 0.0f, acc3 = 0.0f;
        #pragma unroll 7
        for (int e = 0; e < 84; e += 4) {
            vf4 w0 = *(const vf4*)(Wl + (e + 0) * 84 + c0);
            vf4 w1 = *(const vf4*)(Wl + (e + 1) * 84 + c0);
            vf4 w2 = *(const vf4*)(Wl + (e + 2) * 84 + c0);
            vf4 w3 = *(const vf4*)(Wl + (e + 3) * 84 + c0);
            vf4 r0 = *(const vf4*)(rp + e);
            vf4 r1 = *(const vf4*)(rp + 84 + e);
            vf4 r2 = *(const vf4*)(rp + 168 + e);
            vf4 r3 = *(const vf4*)(rp + 252 + e);
            acc0 += r0[0] * w0 + r0[1] * w1 + r0[2] * w2 + r0[3] * w3;
            acc1 += r1[0] * w0 + r1[1] * w1 + r1[2] * w2 + r1[3] * w3;
            acc2 += r2[0] * w0 + r2[1] * w1 + r2[2] * w2 + r2[3] * w3;
            acc3 += r3[0] * w0 + r3[1] * w1 + r3[2] * w2 + r3[3] * w3;
        }
        vf4 av[4] = {acc0, acc1, acc2, acc3};
        #pragma unroll
        for (int cc = 0; cc < 4; cc++) {
            int col = c0 + cc;
            if (col < 81) {
                #pragma unroll
                for (int rr = 0; rr < 4; rr++) {
                    int idx = (row0 + r4 * 4 + rr) * 81 + col;
                    float v = av[rr][cc];
                    h2[idx] = v;
                    xh[idx] = txall[idx] + v;
                }
            }
        }
    }
}

// ---------------- Qs/Ks (Vs == Qs): 64 rows/block, W-pass split (512 blocks), 4x4 ----------------
__global__ __launch_bounds__(512) void qks_kernel(const float* __restrict__ xh,
                           const float* __restrict__ Wq, const float* __restrict__ Wk,
                           float* __restrict__ Qs, float* __restrict__ Ks) {
    __shared__ float rows_[64 * 84];
    __shared__ float Wl[84 * 84];
    int blk = blockIdx.x;            // 0..511
    int t = blk >> 8;                // 0: Q, 1: K
    int rb = blk & 255;
    int row0 = rb * 64;
    int b = row0 >> 9;
    int s0 = row0 & 511;
    const float* W = (t == 0) ? Wq : Wk;
    int tid = threadIdx.x;
    for (int i = tid; i < 64 * 84; i += 512) {
        int c = i % 84;
        rows_[i] = (c < 81) ? xh[(row0 + i / 84) * 81 + c] : 0.0f;
    }
    for (int i = tid; i < 84 * 84; i += 512) {
        int e = i / 84, hd = i % 84;
        Wl[i] = (e < 81 && hd < 81) ? W[(hd / 9) * 729 + e * 9 + (hd % 9)] : 0.0f;
    }
    __syncthreads();
    float* dst = (t == 0) ? Qs : Ks;
    for (int o = tid; o < 336; o += 512) {
        int r4 = o / 21, cg = o % 21;
        int c0 = cg * 4;
        const float* rp = rows_ + r4 * 4 * 84;
        vf4 acc0 = 0.0f, acc1 = 0.0f, acc2 = 0.0f, acc3 = 0.0f;
        #pragma unroll 7
        for (int e = 0; e < 84; e += 4) {
            vf4 w0 = *(const vf4*)(Wl + (e + 0) * 84 + c0);
            vf4 w1 = *(const vf4*)(Wl + (e + 1) * 84 + c0);
            vf4 w2 = *(const vf4*)(Wl + (e + 2) * 84 + c0);
            vf4 w3 = *(const vf4*)(Wl + (e + 3) * 84 + c0);
            vf4 r0 = *(const vf4*)(rp + e);
            vf4 r1 = *(const vf4*)(rp + 84 + e);
            vf4 r2 = *(const vf4*)(rp + 168 + e);
            vf4 r3 = *(const vf4*)(rp + 252 + e);
            acc0 += r0[0] * w0 + r0[1] * w1 + r0[2] * w2 + r0[3] * w3;
            acc1 += r1[0] * w0 + r1[1] * w1 + r1[2] * w2 + r1[3] * w3;
            acc2 += r2[0] * w0 + r2[1] * w1 + r2[2] * w2 + r2[3] * w3;
            acc3 += r3[0] * w0 + r3[1] * w1 + r3[2] * w2 + r3[3] * w3;
        }
        vf4 av[4] = {acc0, acc1, acc2, acc3};
        #pragma unroll
        for (int cc = 0; cc < 4; cc++) {
            int col = c0 + cc;
            if (col < 81) {
                int h = col / 9, d = col % 9;
                #pragma unroll
                for (int rr = 0; rr < 4; rr++)
                    dst[((b * 9 + h) * 512 + (s0 + r4 * 4 + rr)) * 9 + d] = av[rr][cc];
            }
        }
    }
}

// ---------------- EBT[t*512+s] = exp(cw * (corr @ Cv)^T[t][s] / sqrt(S)) ----------------
__global__ __launch_bounds__(256) void biasmm_kernel(const float* __restrict__ corr,
                              const float* __restrict__ Cv, const float* __restrict__ cwp,
                              float* __restrict__ ebT) {
    __shared__ float As[32][33];
    __shared__ float Bs[32][33];
    int tx = threadIdx.x, ty = threadIdx.y;   // 16 x 16
    int tid = ty * 16 + tx;
    int t0 = blockIdx.y * 32, s0 = blockIdx.x * 32;
    float a00 = 0, a01 = 0, a10 = 0, a11 = 0;
    for (int k0 = 0; k0 < 512; k0 += 32) {
        for (int ii = tid; ii < 1024; ii += 256) {
            int r = ii >> 5, c = ii & 31;
            As[r][c] = Cv[(k0 + r) * 512 + t0 + c];
            Bs[r][c] = corr[(s0 + r) * 512 + k0 + c];
        }
        __syncthreads();
        #pragma unroll
        for (int kk = 0; kk < 32; kk++) {
            float b0 = Bs[tx][kk], b1 = Bs[tx + 16][kk];
            float c0 = As[kk][ty], c1 = As[kk][ty + 16];
            a00 += c0 * b0; a01 += c0 * b1; a10 += c1 * b0; a11 += c1 * b1;
        }
        __syncthreads();
    }
    float cws = cwp[0] * 0.04419417382415922f;   // cw / sqrt(512)
    ebT[(t0 + ty) * 512 + s0 + tx]            = __expf(a00 * cws);
    ebT[(t0 + ty) * 512 + s0 + tx + 16]       = __expf(a01 * cws);
    ebT[(t0 + ty + 16) * 512 + s0 + tx]       = __expf(a10 * cws);
    ebT[(t0 + ty + 16) * 512 + s0 + tx + 16]  = __expf(a11 * cws);
}

// ---------------- attention-1: no-max softmax (exp2), 8-way key split, atomic merge ----------------
// p = exp2(c1*log2e * q.k) * EB[key][q]
// grid 4608: bh = blk>>4, qhalf = (blk>>3)&1, kq8 = blk&7 -- ALL block-uniform (scalar K/V loads)
// each thread: 1 query x 64 keys; partials accumulated into ONE plane set via atomicAdd
// planes: part[e*147456 + (bh*512+q)], e in [0,10)  (zeroed by memset before launch)
__global__ __launch_bounds__(256) void attn1_kernel(const float* __restrict__ Qs,
                                                    const float* __restrict__ Ks,
                                                    const float* __restrict__ ebT,
                                                    const float* __restrict__ cwp,
                                                    float* __restrict__ part) {
    int blk = blockIdx.x;          // 0..4607
    int bh = blk >> 4;             // b*9+h
    int qhalf = (blk >> 3) & 1;
    int kq8 = blk & 7;
    int tid = threadIdx.x;
    const float* Kb = Ks + bh * 4608;
    const float* Qb = Qs + bh * 4608;
    int q = qhalf * 256 + tid;
    float c1 = (1.0f - cwp[0]) * (1.4426950408889634f / 3.0f);   // fold log2e
    vf2 qv[4];
    float q8;
    {
        const float* qp = Qb + q * 9;
        #pragma unroll
        for (int d = 0; d < 4; d++) {
            vf2 t; t.x = c1 * qp[2 * d]; t.y = c1 * qp[2 * d + 1];
            qv[d] = t;
        }
        q8 = c1 * qp[8];
    }
    float l = 0.0f, a8 = 0.0f;
    vf2 acc[4];
    #pragma unroll
    for (int d = 0; d < 4; d++) acc[d] = (vf2)0.0f;
    int k0 = kq8 * 64;             // block-uniform -> K/V scalar loads preserved
    const float* ebp = ebT + q;
    for (int t0 = k0; t0 < k0 + 64; t0 += 8) {
        float eb[8];
        #pragma unroll
        for (int j = 0; j < 8; j++) eb[j] = ebp[(t0 + j) << 9];
        #pragma unroll
        for (int j = 0; j < 8; j++) {
            const float* kr = Kb + (t0 + j) * 9;   // wave-uniform -> scalar loads
            const float* vr = Qb + (t0 + j) * 9;   // Vs == Qs
            vf2 k0v; k0v.x = kr[0]; k0v.y = kr[1];
            vf2 k1v; k1v.x = kr[2]; k1v.y = kr[3];
            vf2 k2v; k2v.x = kr[4]; k2v.y = kr[5];
            vf2 k3v; k3v.x = kr[6]; k3v.y = kr[7];
            vf2 u2 = qv[0] * k0v + qv[1] * k1v + qv[2] * k2v + qv[3] * k3v;
            float u = u2.x + u2.y + q8 * kr[8];
            float p = exp2f(u) * eb[j];
            l += p;
            vf2 p2; p2.x = p; p2.y = p;
            vf2 v0; v0.x = vr[0]; v0.y = vr[1];
            vf2 v1; v1.x = vr[2]; v1.y = vr[3];
            vf2 v2; v2.x = vr[4]; v2.y = vr[5];
            vf2 v3; v3.x = vr[6]; v3.y = vr[7];
            acc[0] += p2 * v0; acc[1] += p2 * v1;
            acc[2] += p2 * v2; acc[3] += p2 * v3;
            a8 += p * vr[8];
        }
    }
    int gidx = bh * 512 + q;
    atomicAdd(&part[gidx], l);
    #pragma unroll
    for (int d = 0; d < 4; d++) {
        atomicAdd(&part[(1 + 2 * d) * 147456 + gidx], acc[d].x);
        atomicAdd(&part[(2 + 2 * d) * 147456 + gidx], acc[d].y);
    }
    atomicAdd(&part[9 * 147456 + gidx], a8);
}

// ---------------- matin = (1-hw)*(h1@Wo1) + hw*h2 + tx ; merge fused, st1 fused ----------------
__global__ __launch_bounds__(512) void h1o_kernel(const float* __restrict__ apart,
                           const float* __restrict__ Wo1, const float* __restrict__ h2,
                           const float* __restrict__ txall, const float* __restrict__ hwp,
                           float* __restrict__ matin, float* __restrict__ st1) {
    __shared__ float rows_[64 * 84];
    __shared__ float Wl[84 * 84];
    __shared__ float ssum[81], ssq[81];
    int row0 = blockIdx.x * 64;
    int tid = threadIdx.x;
    if (tid < 81) { ssum[tid] = 0.0f; ssq[tid] = 0.0f; }
    // stage h1 rows from the (already-merged) atomic plane set
    for (int i = tid; i < 64 * 84; i += 512) {
        int r = i / 84, c = i % 84;
        float v = 0.0f;
        if (c < 81) {
            int row = row0 + r;             // b*512+s
            int b = row >> 9, s = row & 511;
            int h = c / 9, d = c % 9;
            int gidx = (b * 9 + h) * 512 + s;
            float L = apart[gidx];
            float A = apart[(1 + d) * 147456 + gidx];
            v = A / L;
        }
        rows_[i] = v;
    }
    for (int i = tid; i < 84 * 84; i += 512) {
        int e = i / 84, c = i % 84;
        Wl[i] = (e < 81 && c < 81) ? Wo1[e * 81 + c] : 0.0f;
    }
    __syncthreads();
    float hw = hwp[0];
    float onemhw = 1.0f - hw;
    for (int o = tid; o < 336; o += 512) {
        int r4 = o / 21, cg = o % 21;
        int c0 = cg * 4;
        const float* rp = rows_ + r4 * 4 * 84;
        vf4 acc0 = 0.0f, acc1 = 0.0f, acc2 = 0.0f, acc3 = 0.0f;
        #pragma unroll 7
        for (int e = 0; e < 84; e += 4) {
            vf4 w0 = *(const vf4*)(Wl + (e + 0) * 84 + c0);
            vf4 w1 = *(const vf4*)(Wl + (e + 1) * 84 + c0);
            vf4 w2 = *(const vf4*)(Wl + (e + 2) * 84 + c0);
            vf4 w3 = *(const vf4*)(Wl + (e + 3) * 84 + c0);
            vf4 r0 = *(const vf4*)(rp + e);
            vf4 r1 = *(const vf4*)(rp + 84 + e);
            vf4 r2 = *(const vf4*)(rp + 168 + e);
            vf4 r3 = *(const vf4*)(rp + 252 + e);
            acc0 += r0[0] * w0 + r0[1] * w1 + r0[2] * w2 + r0[3] * w3;
            acc1 += r1[0] * w0 + r1[1] * w1 + r1[2] * w2 + r1[3] * w3;
            acc2 += r2[0] * w0 + r2[1] * w1 + r2[2] * w2 + r2[3] * w3;
            acc3 += r3[0] * w0 + r3[1] * w1 + r3[2] * w2 + r3[3] * w3;
        }
        vf4 av[4] = {acc0, acc1, acc2, acc3};
        #pragma unroll
        for (int cc = 0; cc < 4; cc++) {
            int col = c0 + cc;
            if (col < 81) {
                float ls = 0.0f, lq = 0.0f;
                #pragma unroll
                for (int rr = 0; rr < 4; rr++) {
                    int idx = (row0 + r4 * 4 + rr) * 81 + col;
                    float v = onemhw * av[rr][cc] + hw * h2[idx] + txall[idx];
                    matin[idx] = v;
                    ls += v; lq += v * v;
                }
                atomicAdd(&ssum[col], ls);
                atomicAdd(&ssq[col], lq);
            }
        }
    }
    __syncthreads();
    if (tid < 81) {
        atomicAdd(&st1[tid], ssum[tid]);
        atomicAdd(&st1[81 + tid], ssq[tid]);
    }
}

// ---------------- ff1: 64 rows x 64 cols/block, 4x4 tile ; fused st2 ----------------
__global__ __launch_bounds__(512) void ff1_kernel(const float* __restrict__ matin,
                           const float* __restrict__ st1, const float* __restrict__ g1,
                           const float* __restrict__ b1, const float* __restrict__ W,
                           const float* __restrict__ bias, float* __restrict__ f1,
                           float* __restrict__ st2) {
    __shared__ float rows_[64 * 84];
    __shared__ float Wl[84 * 64];       // rows 81..83 zero
    __shared__ float s2s[64], s2q[64];
    int row0 = blockIdx.x * 64;
    int cb = blockIdx.y * 64;
    int tid = threadIdx.x;
    const float invN = 1.0f / 16384.0f;
    if (tid < 64) { s2s[tid] = 0.0f; s2q[tid] = 0.0f; }
    for (int i = tid; i < 64 * 84; i += 512) {
        int c = i % 84;
        float v = 0.0f;
        if (c < 81) {
            float mean = st1[c] * invN;
            float var = st1[81 + c] * invN - mean * mean;
            v = (matin[(row0 + i / 84) * 81 + c] - mean) * rsqrtf(var + EPSV) * g1[c] + b1[c];
        }
        rows_[i] = v;
    }
    for (int i = tid; i < 84 * 64; i += 512) {
        int e = i >> 6, cc = i & 63;
        Wl[i] = (e < 81) ? W[e * 256 + cb + cc] : 0.0f;
    }
    __syncthreads();
    if (tid < 256) {
        int o = tid;                 // 256 tasks: 16 r-groups x 16 c-groups
        int r4 = o >> 4, cg = o & 15;
        int c0 = cg * 4;
        const float* rp = rows_ + r4 * 4 * 84;
        vf4 acc0 = 0.0f, acc1 = 0.0f, acc2 = 0.0f, acc3 = 0.0f;
        #pragma unroll 7
        for (int e = 0; e < 84; e += 4) {
            vf4 w0 = *(const vf4*)(Wl + ((e + 0) << 6) + c0);
            vf4 w1 = *(const vf4*)(Wl + ((e + 1) << 6) + c0);
            vf4 w2 = *(const vf4*)(Wl + ((e + 2) << 6) + c0);
            vf4 w3 = *(const vf4*)(Wl + ((e + 3) << 6) + c0);
            vf4 r0 = *(const vf4*)(rp + e);
            vf4 r1 = *(const vf4*)(rp + 84 + e);
            vf4 r2 = *(const vf4*)(rp + 168 + e);
            vf4 r3 = *(const vf4*)(rp + 252 + e);
            acc0 += r0[0] * w0 + r0[1] * w1 + r0[2] * w2 + r0[3] * w3;
            acc1 += r1[0] * w0 + r1[1] * w1 + r1[2] * w2 + r1[3] * w3;
            acc2 += r2[0] * w0 + r2[1] * w1 + r2[2] * w2 + r2[3] * w3;
            acc3 += r3[0] * w0 + r3[1] * w1 + r3[2] * w2 + r3[3] * w3;
        }
        vf4 bv = *(const vf4*)(bias + cb + c0);
        acc0 = __builtin_elementwise_max(acc0 + bv, (vf4)0.0f);
        acc1 = __builtin_elementwise_max(acc1 + bv, (vf4)0.0f);
        acc2 = __builtin_elementwise_max(acc2 + bv, (vf4)0.0f);
        acc3 = __builtin_elementwise_max(acc3 + bv, (vf4)0.0f);
        int base = (row0 + r4 * 4) * 256 + cb + c0;
        *(vf4*)(f1 + base)       = acc0;
        *(vf4*)(f1 + base + 256) = acc1;
        *(vf4*)(f1 + base + 512) = acc2;
        *(vf4*)(f1 + base + 768) = acc3;
        vf4 cs = acc0 + acc1 + acc2 + acc3;
        vf4 cq = acc0 * acc0 + acc1 * acc1 + acc2 * acc2 + acc3 * acc3;
        #pragma unroll
        for (int cc = 0; cc < 4; cc++) {
            atomicAdd(&s2s[c0 + cc], cs[cc]);
            atomicAdd(&s2q[c0 + cc], cq[cc]);
        }
    }
    __syncthreads();
    if (tid < 64) {
        atomicAdd(&st2[cb + tid], s2s[tid]);
        atomicAdd(&st2[256 + cb + tid], s2q[tid]);
    }
}

// ---------------- ff2: 32 rows/block, 4 K-quarter passes, 4x4 tile ; fused st3 ----------------
__global__ __launch_bounds__(256) void ff2_kernel(const float* __restrict__ f1,
                           const float* __restrict__ st2, const float* __restrict__ g2,
                           const float* __restrict__ b2, const float* __restrict__ W,
                           const float* __restrict__ bias, const float* __restrict__ matin,
                           const float* __restrict__ st1, const float* __restrict__ g1,
                           const float* __restrict__ b1, float* __restrict__ t3,
                           float* __restrict__ st3) {
    __shared__ float rows_[32 * 64];
    __shared__ float Wl[64 * 84];
    __shared__ float s3s[81], s3q[81];
    int row0 = blockIdx.x * 32;
    int tid = threadIdx.x;
    const float invN = 1.0f / 16384.0f;
    if (tid < 81) { s3s[tid] = 0.0f; s3q[tid] = 0.0f; }
    int o = tid;
    int r4 = o / 21, cg = o % 21;
    int c0 = cg * 4;
    bool active = (o < 168);
    vf4 acc0 = 0.0f, acc1 = 0.0f, acc2 = 0.0f, acc3 = 0.0f;
    for (int kq = 0; kq < 4; kq++) {
        __syncthreads();
        for (int i = tid; i < 32 * 64; i += 256) {
            int r = i >> 6, e = i & 63;
            int c = kq * 64 + e;
            float mean = st2[c] * invN;
            float var = st2[256 + c] * invN - mean * mean;
            rows_[i] = (f1[(row0 + r) * 256 + c] - mean) * rsqrtf(var + EPSV) * g2[c] + b2[c];
        }
        for (int i = tid; i < 64 * 84; i += 256) {
            int e = i / 84, c = i % 84;
            Wl[i] = (c < 81) ? W[(kq * 64 + e) * 81 + c] : 0.0f;
        }
        __syncthreads();
        if (active) {
            const float* rp = rows_ + r4 * 4 * 64;
            #pragma unroll 8
            for (int e = 0; e < 64; e += 4) {
                vf4 w0 = *(const vf4*)(Wl + (e + 0) * 84 + c0);
                vf4 w1 = *(const vf4*)(Wl + (e + 1) * 84 + c0);
                vf4 w2 = *(const vf4*)(Wl + (e + 2) * 84 + c0);
                vf4 w3 = *(const vf4*)(Wl + (e + 3) * 84 + c0);
                vf4 r0 = *(const vf4*)(rp + e);
                vf4 r1 = *(const vf4*)(rp + 64 + e);
                vf4 r2 = *(const vf4*)(rp + 128 + e);
                vf4 r3 = *(const vf4*)(rp + 192 + e);
                acc0 += r0[0] * w0 + r0[1] * w1 + r0[2] * w2 + r0[3] * w3;
                acc1 += r1[0] * w0 + r1[1] * w1 + r1[2] * w2 + r1[3] * w3;
                acc2 += r2[0] * w0 + r2[1] * w1 + r2[2] * w2 + r2[3] * w3;
                acc3 += r3[0] * w0 + r3[1] * w1 + r3[2] * w2 + r3[3] * w3;
            }
        }
    }
    if (active) {
        vf4 av[4] = {acc0, acc1, acc2, acc3};
        #pragma unroll
        for (int cc = 0; cc < 4; cc++) {
            int col = c0 + cc;
            if (col < 81) {
                float mean = st1[col] * invN;
                float var = st1[81 + col] * invN - mean * mean;
                float rstd = rsqrtf(var + EPSV);
                float bval = bias[col];
                float ls = 0.0f, lq = 0.0f;
                #pragma unroll
                for (int rr = 0; rr < 4; rr++) {
                    int idx = (row0 + r4 * 4 + rr) * 81 + col;
                    float ma = (matin[idx] - mean) * rstd * g1[col] + b1[col];
                    float v = ma + fmaxf(av[rr][cc] + bval, 0.0f);
                    t3[idx] = v;
                    ls += v; lq += v * v;
                }
                atomicAdd(&s3s[col], ls);
                atomicAdd(&s3q[col], lq);
            }
        }
    }
    __syncthreads();
    if (tid < 81) {
        atomicAdd(&st3[tid], s3s[tid]);
        atomicAdd(&st3[81 + tid], s3q[tid]);
    }
}

// ---------------- token_mm: u/v dual GEMM (64 rows/block, W-pass split, 4x4 tile) ----------------
__global__ __launch_bounds__(512) void token_mm(const float* __restrict__ t3,
                            const float* __restrict__ st3, const float* __restrict__ g3,
                            const float* __restrict__ b3, const float* __restrict__ tvw,
                            const float* __restrict__ beta1,
                            float* __restrict__ uv0, float* __restrict__ uv1) {
    __shared__ float rows_[64 * 84];
    __shared__ float Wl[84 * 84];
    int blk = blockIdx.x;            // 0..511
    int t = blk >> 8;
    int row0 = (blk & 255) * 64;
    const float* W = (t == 0) ? tvw : beta1;
    float* dst = (t == 0) ? uv0 : uv1;
    int tid = threadIdx.x;
    const float invN = 1.0f / 16384.0f;
    for (int i = tid; i < 64 * 84; i += 512) {
        int c = i % 84;
        float v = 0.0f;
        if (c < 81) {
            float mean = st3[c] * invN;
            float var = st3[81 + c] * invN - mean * mean;
            v = (t3[(row0 + i / 84) * 81 + c] - mean) * rsqrtf(var + EPSV) * g3[c] + b3[c];
        }
        rows_[i] = v;
    }
    for (int i = tid; i < 84 * 84; i += 512) {
        int e = i / 84, c = i % 84;
        Wl[i] = (e < 81 && c < 81) ? W[e * 81 + c] : 0.0f;
    }
    __syncthreads();
    for (int o = tid; o < 336; o += 512) {
        int r4 = o / 21, cg = o % 21;
        int c0 = cg * 4;
        const float* rp = rows_ + r4 * 4 * 84;
        vf4 acc0 = 0.0f, acc1 = 0.0f, acc2 = 0.0f, acc3 = 0.0f;
        #pragma unroll 7
        for (int e = 0; e < 84; e += 4) {
            vf4 w0 = *(const vf4*)(Wl + (e + 0) * 84 + c0);
            vf4 w1 = *(const vf4*)(Wl + (e + 1) * 84 + c0);
            vf4 w2 = *(const vf4*)(Wl + (e + 2) * 84 + c0);
            vf4 w3 = *(const vf4*)(Wl + (e + 3) * 84 + c0);
            vf4 r0 = *(const vf4*)(rp + e);
            vf4 r1 = *(const vf4*)(rp + 84 + e);
            vf4 r2 = *(const vf4*)(rp + 168 + e);
            vf4 r3 = *(const vf4*)(rp + 252 + e);
            acc0 += r0[0] * w0 + r0[1] * w1 + r0[2] * w2 + r0[3] * w3;
            acc1 += r1[0] * w0 + r1[1] * w1 + r1[2] * w2 + r1[3] * w3;
            acc2 += r2[0] * w0 + r2[1] * w1 + r2[2] * w2 + r2[3] * w3;
            acc3 += r3[0] * w0 + r3[1] * w1 + r3[2] * w2 + r3[3] * w3;
        }
        vf4 av[4] = {acc0, acc1, acc2, acc3};
        #pragma unroll
        for (int cc = 0; cc < 4; cc++) {
            int col = c0 + cc;
            if (col < 81) {
                #pragma unroll
                for (int rr = 0; rr < 4; rr++)
                    dst[(row0 + r4 * 4 + rr) * 81 + col] = av[rr][cc];
            }
        }
    }
}

// ---------------- token_pool: softmax-pool over 81, 32 rows/block, 8 lanes/row ----------------
__global__ __launch_bounds__(256) void token_pool(const float* __restrict__ uv0,
                             const float* __restrict__ uv1, const float* __restrict__ tvb,
                             const float* __restrict__ basel, const float* __restrict__ a1p,
                             const float* __restrict__ a2p, float* __restrict__ fea) {
    int tid = threadIdx.x;
    int r = tid >> 3, j = tid & 7;
    int row = blockIdx.x * 32 + r;
    int base = row * 81;
    float u[11], v[11];
    #pragma unroll
    for (int dd = 0; dd < 11; dd++) {
        int d = j + dd * 8;
        if (d < 81) {
            u[dd] = uv0[base + d] + tvb[d];
            v[dd] = uv1[base + d];
        } else {
            u[dd] = 0.0f; v[dd] = -1e30f;
        }
    }
    float mx = -1e30f;
    #pragma unroll
    for (int dd = 0; dd < 11; dd++) mx = fmaxf(mx, v[dd]);
    #pragma unroll
    for (int msk = 1; msk < 8; msk <<= 1) mx = fmaxf(mx, __shfl_xor(mx, msk, 8));
    float sp = 0.0f, sup = 0.0f;
    #pragma unroll
    for (int dd = 0; dd < 11; dd++) {
        float p = __expf(v[dd] - mx);
        sp += p; sup += u[dd] * p;
    }
    #pragma unroll
    for (int msk = 1; msk < 8; msk <<= 1) {
        sp  += __shfl_xor(sp, msk, 8);
        sup += __shfl_xor(sup, msk, 8);
    }
    if (j == 0) {
        int b = row >> 9, s = row & 511;
        fea[row] = a1p[0] * (sup / sp) + a2p[0] * basel[b * 2048 + s * 4];
    }
}

// ---------------- fc1: relu(fea @ W + b), fused st4 ----------------
__global__ void fc1_kernel(const float* __restrict__ in, const float* __restrict__ W,
                           const float* __restrict__ bias, float* __restrict__ out,
                           float* __restrict__ st) {
    int idx = blockIdx.x * blockDim.x + threadIdx.x;
    if (idx >= 32 * 512) return;
    int b = idx >> 9, j = idx & 511;
    float acc = bias[j];
    const float* ip = in + (b << 9);
    #pragma unroll 8
    for (int k = 0; k < 512; k++) acc += ip[k] * W[k * 512 + j];
    acc = fmaxf(acc, 0.0f);
    out[idx] = acc;
    atomicAdd(&st[j], acc);
    atomicAdd(&st[512 + j], acc * acc);
}

// ---------------- fc2: relu(bn(fch1) @ W + b), fused st5 ----------------
__global__ __launch_bounds__(256) void fc2_kernel(const float* __restrict__ in,
                           const float* __restrict__ st4, const float* __restrict__ g,
                           const float* __restrict__ bb, const float* __restrict__ W,
                           const float* __restrict__ bias, float* __restrict__ out,
                           float* __restrict__ st5) {
    __shared__ float scale[512], shift[512];
    int tid = threadIdx.x;
    for (int k = tid; k < 512; k += 256) {
        float mean = st4[k] * (1.0f / 32.0f);
        float var = st4[512 + k] * (1.0f / 32.0f) - mean * mean;
        float sc_ = rsqrtf(var + EPSV) * g[k];
        scale[k] = sc_;
        shift[k] = bb[k] - mean * sc_;
    }
    __syncthreads();
    int idx = blockIdx.x * 256 + tid;
    if (idx >= 32 * 256) return;
    int b = idx >> 8, j = idx & 255;
    float acc = bias[j];
    const float* ip = in + (b << 9);
    #pragma unroll 8
    for (int k = 0; k < 512; k++) acc += (ip[k] * scale[k] + shift[k]) * W[k * 256 + j];
    acc = fmaxf(acc, 0.0f);
    out[idx] = acc;
    atomicAdd(&st5[j], acc);
    atomicAdd(&st5[256 + j], acc * acc);
}

// ---------------- fc3: tanh(bn(fch2) @ W + b) ----------------
__global__ void fc3_kernel(const float* __restrict__ in, const float* __restrict__ st5,
                           const float* __restrict__ g, const float* __restrict__ bb,
                           const float* __restrict__ W, const float* __restrict__ bias,
                           float* __restrict__ out) {
    __shared__ float scale[256], shift[256];
    int tid = threadIdx.x;   // 128
    for (int k = tid; k < 256; k += 128) {
        float mean = st5[k] * (1.0f / 32.0f);
        float var = st5[256 + k] * (1.0f / 32.0f) - mean * mean;
        float sc_ = rsqrtf(var + EPSV) * g[k];
        scale[k] = sc_;
        shift[k] = bb[k] - mean * sc_;
    }
    __syncthreads();
    int b = tid >> 2, j = tid & 3;
    float acc = bias[j];
    const float* ip = in + (b << 8);
    #pragma unroll 8
    for (int k = 0; k < 256; k++) acc += (ip[k] * scale[k] + shift[k]) * W[k * 4 + j];
    out[tid] = tanhf(acc);
}

// =======================================================================
extern "C" void kernel_launch(void* const* d_in, const int* in_sizes, int n_in,
                              void* d_out, int out_size, void* d_ws, size_t ws_size,
                              hipStream_t stream) {
    const float* x       = (const float*)d_in[0];
    const float* basel   = (const float*)d_in[1];
    const float* cali    = (const float*)d_in[2];
    const float* Wq      = (const float*)d_in[3];
    const float* Wk      = (const float*)d_in[4];
    const float* Wq2     = (const float*)d_in[5];
    const float* Wk2     = (const float*)d_in[6];
    const float* Wv2     = (const float*)d_in[7];
    const float* Cv      = (const float*)d_in[8];
    const float* Wo1     = (const float*)d_in[9];
    const float* Wo2     = (const float*)d_in[10];
    const float* corr_w  = (const float*)d_in[11];
    const float* h_w     = (const float*)d_in[12];
    const float* corr    = (const float*)d_in[13];
    const float* g1      = (const float*)d_in[14];
    const float* b1      = (const float*)d_in[15];
    const float* ff1_w   = (const float*)d_in[16];
    const float* ff1_b   = (const float*)d_in[17];
    const float* g2      = (const float*)d_in[18];
    const float* b2      = (const float*)d_in[19];
    const float* ff2_w   = (const float*)d_in[20];
    const float* ff2_b   = (const float*)d_in[21];
    const float* g3      = (const float*)d_in[22];
    const float* b3      = (const float*)d_in[23];
    const float* tvw     = (const float*)d_in[24];
    const float* tvb     = (const float*)d_in[25];
    const float* beta1   = (const float*)d_in[26];
    const float* a1      = (const float*)d_in[27];
    const float* a2      = (const float*)d_in[28];
    const float* fc1_w   = (const float*)d_in[29];
    const float* fc1_b   = (const float*)d_in[30];
    const float* bnf1_g  = (const float*)d_in[31];
    const float* bnf1_b  = (const float*)d_in[32];
    const float* fc2_w   = (const float*)d_in[33];
    const float* fc2_b   = (const float*)d_in[34];
    const float* bnf2_g  = (const float*)d_in[35];
    const float* bnf2_b  = (const float*)d_in[36];
    const float* fc3_w   = (const float*)d_in[37];
    const float* fc3_b   = (const float*)d_in[38];
    float* out = (float*)d_out;
    float* ws = (float*)d_ws;

    // ---- workspace layout (float offsets) ----
    const size_t SCAL  = 0;         // 2
    const size_t PART  = 16;        // 128
    const size_t ST1   = 512;       // 162
    const size_t ST2   = 768;       // 512
    const size_t ST3   = 1536;      // 162
    const size_t ST4   = 1792;      // 1024
    const size_t ST5   = 2880;      // 512
    const size_t FEA   = 4096;      // 16384
    const size_t FCH1  = 20480;     // 16384
    const size_t FCH2  = 36864;     // 8192
    const size_t PEO   = 45056;     // 41472
    const size_t TX    = 90112;     // 1990656
    const size_t Q2O   = 2080768;   // 1327104
    const size_t KCO   = 3407872;   // 1990656   (reused: Qs)
    const size_t VCO   = 5398528;   // 1990656   (reused: Ks)
    const size_t TMP2  = 7389184;   // 1327104   (reused: matin, then uv0)
    const size_t H2O   = 8716288;   // 1327104   (reused: t3)
    const size_t XHO   = 10043392;  // 1327104   (xh, dead after qks -> uv1)
    const size_t BIASO = 11370496;  // 262144    (EBT)
    const size_t F1O   = 11632640;  // 4194304   (f1; also attn1 planes 1474560)

    float* scal  = ws + SCAL;
    float* part  = ws + PART;
    float* st1   = ws + ST1;
    float* st2   = ws + ST2;
    float* st3   = ws + ST3;
    float* st4   = ws + ST4;
    float* st5   = ws + ST5;
    float* fea   = ws + FEA;
    float* fch1  = ws + FCH1;
    float* fch2  = ws + FCH2;
    float* pe    = ws + PEO;
    float* txall = ws + TX;
    float* Q2    = ws + Q2O;
    float* Kc    = ws + KCO;
    float* Vc    = ws + VCO;
    float* tmp2  = ws + TMP2;
    float* h2    = ws + H2O;
    float* xh    = ws + XHO;
    float* ebT   = ws + BIASO;
    float* f1    = ws + F1O;
    float* Qs    = Kc;     // reuse
    float* Ks    = Vc;     // reuse
    float* matin = tmp2;   // reuse (dead after ff2 -> uv0)
    float* t3    = h2;     // reuse
    float* apart = f1;     // attn1 atomic planes (10 x 147456 floats) in f1 region
    float* uv0   = tmp2;   // token u plane (matin dead after ff2)
    float* uv1   = xh;     // token v plane (xh dead after qks)

    // zero scal/part/stats region — capture-safe
    hipMemsetAsync(ws, 0, 4096 * sizeof(float), stream);
    // zero attn1 atomic planes (5.9 MB)
    hipMemsetAsync(apart, 0, 1474560 * sizeof(float), stream);

    minmax_part<<<64, 256, 0, stream>>>(x, part);
    minmax_fin<<<1, 64, 0, stream>>>(part, scal);

    pe_kernel<<<(512 * 81 + 255) / 256, 256, 0, stream>>>(pe);

    tokenize_kernel<<<(48 * 512 * 81 + 255) / 256, 256, 0, stream>>>(x, cali, scal, pe, txall);

    qkv2_kernel<<<1024, 512, 0, stream>>>(txall, Wq2, Wk2, Wv2, Q2, Kc, Vc);

    attn2_kernel<<<(512 * 9 * 32) / 256, 256, 0, stream>>>(Q2, Kc, Vc, tmp2);

    h2xh_kernel<<<256, 512, 0, stream>>>(tmp2, Wo2, txall, h2, xh);

    qks_kernel<<<512, 512, 0, stream>>>(xh, Wq, Wk, Qs, Ks);

    biasmm_kernel<<<dim3(16, 16), dim3(16, 16), 0, stream>>>(corr, Cv, corr_w, ebT);

    attn1_kernel<<<4608, 256, 0, stream>>>(Qs, Ks, ebT, corr_w, apart);

    h1o_kernel<<<256, 512, 0, stream>>>(apart, Wo1, h2, txall, h_w, matin, st1);

    ff1_kernel<<<dim3(256, 4), 512, 0, stream>>>(matin, st1, g1, b1, ff1_w, ff1_b, f1, st2);

    ff2_kernel<<<512, 256, 0, stream>>>(f1, st2, g2, b2, ff2_w, ff2_b,
                                        matin, st1, g1, b1, t3, st3);

    token_mm<<<512, 512, 0, stream>>>(t3, st3, g3, b3, tvw, beta1, uv0, uv1);
    token_pool<<<512, 256, 0, stream>>>(uv0, uv1, tvb, basel, a1, a2, fea);

    fc1_kernel<<<64, 256, 0, stream>>>(fea, fc1_w, fc1_b, fch1, st4);

    fc2_kernel<<<32, 256, 0, stream>>>(fch1, st4, bnf1_g, bnf1_b, fc2_w, fc2_b, fch2, st5);

    fc3_kernel<<<1, 128, 0, stream>>>(fch2, st5, bnf2_g, bnf2_b, fc3_w, fc3_b, out);
}

// Round 19
// 409.215 us; speedup vs baseline: 1.3919x; 1.0026x over previous
//
#include <hip/hip_runtime.h>
#include <hip/hip_bf16.h>
#include <math.h>

#define EPSV 1e-5f

typedef float vf2 __attribute__((ext_vector_type(2)));
typedef float vf4 __attribute__((ext_vector_type(4)));

// ---------------- sizes ----------------
// B=32 Bc=16 L=2048 TOKEN=40 STRIDE=4 D=81 H=9 dk=9 S=512 FF=256 FC1=512 FC2=256 Y=4

// ---------------- minmax: two-stage ----------------
__global__ void minmax_part(const float* __restrict__ x, float* __restrict__ part) {
    __shared__ float smin[256], smax[256];
    int tid = threadIdx.x;
    float mn = 1e30f, mx = -1e30f;
    for (int i = blockIdx.x * 256 + tid; i < 32 * 2008; i += 64 * 256) {
        int b = i / 2008, c = i % 2008 + 20;
        float v = x[b * 2048 + c];
        mn = fminf(mn, v); mx = fmaxf(mx, v);
    }
    smin[tid] = mn; smax[tid] = mx; __syncthreads();
    for (int off = 128; off > 0; off >>= 1) {
        if (tid < off) { smin[tid] = fminf(smin[tid], smin[tid + off]); smax[tid] = fmaxf(smax[tid], smax[tid + off]); }
        __syncthreads();
    }
    if (tid == 0) { part[blockIdx.x] = smin[0]; part[64 + blockIdx.x] = smax[0]; }
}

__global__ void minmax_fin(const float* __restrict__ part, float* __restrict__ scal) {
    __shared__ float smn[64], smx[64];
    int tid = threadIdx.x;
    smn[tid] = part[tid]; smx[tid] = part[64 + tid]; __syncthreads();
    for (int off = 32; off > 0; off >>= 1) {
        if (tid < off) { smn[tid] = fminf(smn[tid], smn[tid + off]); smx[tid] = fmaxf(smx[tid], smx[tid + off]); }
        __syncthreads();
    }
    if (tid == 0) { scal[0] = smn[0]; scal[1] = smx[0] - smn[0]; }
}

// ---------------- PE table (512 x 81) ----------------
__global__ void pe_kernel(float* __restrict__ pe) {
    int idx = blockIdx.x * blockDim.x + threadIdx.x;
    if (idx >= 512 * 81) return;
    int d = idx % 81, s = idx / 81;
    int j = d >> 1;
    float dv = __expf(-9.210340371976184f * (2.0f * (float)j) / 81.0f);
    float ang = (float)s * dv;
    pe[idx] = (d & 1) ? cosf(ang) : sinf(ang);
}

// ---------------- tokenize + add PE ----------------
__global__ void tokenize_kernel(const float* __restrict__ x, const float* __restrict__ cali,
                                const float* __restrict__ scal, const float* __restrict__ pe,
                                float* __restrict__ txall) {
    int idx = blockIdx.x * blockDim.x + threadIdx.x;
    if (idx >= 48 * 512 * 81) return;
    int d = idx % 81;
    int s = (idx / 81) % 512;
    int r = idx / (81 * 512);
    float xm = scal[0], inv_xs = 1.0f / scal[1];
    int oc = s * 4 + d - 40;
    float val = 0.0f;
    if (oc >= 0 && oc < 2048) {
        float sv = (r < 32) ? x[r * 2048 + oc] : cali[(r - 32) * 2048 + oc];
        val = (sv - xm) * inv_xs;
    }
    txall[idx] = val + pe[s * 81 + d];
}

// ======== 4x4-tile 81->81 GEMM pieces (rows stride 84, W [e][col] stride 84) ========
// 512 threads/block: staging strides 512, compute single pass (336 tasks of 512 threads)

// ---------------- qkv2: 64 rows/block, W-pass split (1024 blocks), 4x4 tile ----------------
__global__ __launch_bounds__(512) void qkv2_kernel(const float* __restrict__ txall,
                            const float* __restrict__ Wq2, const float* __restrict__ Wk2,
                            const float* __restrict__ Wv2,
                            float* __restrict__ Q2, float* __restrict__ Kc, float* __restrict__ Vc) {
    __shared__ float rows_[64 * 84];
    __shared__ float Wl[84 * 84];
    int blk = blockIdx.x;            // 0..1023
    int t, rb;
    if (blk < 256)      { t = 0; rb = blk; }
    else if (blk < 640) { t = 1; rb = blk - 256; }
    else                { t = 2; rb = blk - 640; }
    int row0 = rb * 64;
    int k = row0 >> 9;
    int s0 = row0 & 511;
    const float* W = (t == 0) ? Wq2 : (t == 1) ? Wk2 : Wv2;
    int tid = threadIdx.x;
    for (int i = tid; i < 64 * 84; i += 512) {
        int c = i % 84;
        rows_[i] = (c < 81) ? txall[(row0 + i / 84) * 81 + c] : 0.0f;
    }
    for (int i = tid; i < 84 * 84; i += 512) {
        int e = i / 84, hd = i % 84;
        Wl[i] = (e < 81 && hd < 81) ? W[(hd / 9) * 729 + e * 9 + (hd % 9)] : 0.0f;
    }
    __syncthreads();
    for (int o = tid; o < 336; o += 512) {
        int r4 = o / 21, cg = o % 21;
        int c0 = cg * 4;
        const float* rp = rows_ + r4 * 4 * 84;
        vf4 acc0 = 0.0f, acc1 = 0.0f, acc2 = 0.0f, acc3 = 0.0f;
        #pragma unroll 7
        for (int e = 0; e < 84; e += 4) {
            vf4 w0 = *(const vf4*)(Wl + (e + 0) * 84 + c0);
            vf4 w1 = *(const vf4*)(Wl + (e + 1) * 84 + c0);
            vf4 w2 = *(const vf4*)(Wl + (e + 2) * 84 + c0);
            vf4 w3 = *(const vf4*)(Wl + (e + 3) * 84 + c0);
            vf4 r0 = *(const vf4*)(rp + e);
            vf4 r1 = *(const vf4*)(rp + 84 + e);
            vf4 r2 = *(const vf4*)(rp + 168 + e);
            vf4 r3 = *(const vf4*)(rp + 252 + e);
            acc0 += r0[0] * w0 + r0[1] * w1 + r0[2] * w2 + r0[3] * w3;
            acc1 += r1[0] * w0 + r1[1] * w1 + r1[2] * w2 + r1[3] * w3;
            acc2 += r2[0] * w0 + r2[1] * w1 + r2[2] * w2 + r2[3] * w3;
            acc3 += r3[0] * w0 + r3[1] * w1 + r3[2] * w2 + r3[3] * w3;
        }
        vf4 av[4] = {acc0, acc1, acc2, acc3};
        #pragma unroll
        for (int cc = 0; cc < 4; cc++) {
            int col = c0 + cc;
            if (col < 81) {
                int h = col / 9, d = col % 9;
                #pragma unroll
                for (int rr = 0; rr < 4; rr++) {
                    int s = s0 + r4 * 4 + rr;
                    if (t == 0)      Q2[((s * 9 + h) * 32 + k) * 9 + d] = av[rr][cc];
                    else if (t == 1) Kc[((s * 9 + h) * 48 + k) * 9 + d] = av[rr][cc];
                    else             Vc[((s * 9 + h) * 48 + k) * 9 + d] = av[rr][cc];
                }
            }
        }
    }
}

// ---------------- attention-2 (masked: key==b or key>=32), no-max softmax (exp2) ----------------
__global__ void attn2_kernel(const float* __restrict__ Q2, const float* __restrict__ Kc,
                             const float* __restrict__ Vc, float* __restrict__ tmp2) {
    int tid = blockIdx.x * blockDim.x + threadIdx.x;
    if (tid >= 512 * 9 * 32) return;
    int b = tid & 31;
    int h = (tid >> 5) % 9;
    int s = tid / 288;
    const float* q = Q2 + ((s * 9 + h) * 32 + b) * 9;
    float qr[9];
    const float c2 = 1.4426950408889634f / 3.0f;   // log2e / 3
    #pragma unroll
    for (int d = 0; d < 9; d++) qr[d] = q[d] * c2;
    const float* Kb = Kc + (s * 9 + h) * 48 * 9;
    const float* Vb = Vc + (s * 9 + h) * 48 * 9;
    float l = 0.0f, outv[9];
    #pragma unroll
    for (int d = 0; d < 9; d++) outv[d] = 0.0f;
    #pragma unroll
    for (int j = 0; j < 17; j++) {
        int k = (j == 0) ? b : 31 + j;
        const float* kp = Kb + k * 9;
        float acc = 0.0f;
        #pragma unroll
        for (int d = 0; d < 9; d++) acc += qr[d] * kp[d];
        float p = exp2f(acc);
        l += p;
        const float* vp = Vb + k * 9;
        #pragma unroll
        for (int d = 0; d < 9; d++) outv[d] += p * vp[d];
    }
    float invl = 1.0f / l;
    float* op = tmp2 + (b * 512 + s) * 81 + h * 9;
    #pragma unroll
    for (int d = 0; d < 9; d++) op[d] = outv[d] * invl;
}

// ---------------- h2 = tmp2 @ Wo2 ; xh = tx + h2  (64 rows/block, 4x4 tile) ----------------
__global__ __launch_bounds__(512) void h2xh_kernel(const float* __restrict__ tmp2,
                            const float* __restrict__ Wo2, const float* __restrict__ txall,
                            float* __restrict__ h2, float* __restrict__ xh) {
    __shared__ float rows_[64 * 84];
    __shared__ float Wl[84 * 84];
    int row0 = blockIdx.x * 64;
    int tid = threadIdx.x;
    for (int i = tid; i < 64 * 84; i += 512) {
        int c = i % 84;
        rows_[i] = (c < 81) ? tmp2[(row0 + i / 84) * 81 + c] : 0.0f;
    }
    for (int i = tid; i < 84 * 84; i += 512) {
        int e = i / 84, c = i % 84;
        Wl[i] = (e < 81 && c < 81) ? Wo2[e * 81 + c] : 0.0f;
    }
    __syncthreads();
    for (int o = tid; o < 336; o += 512) {
        int r4 = o / 21, cg = o % 21;
        int c0 = cg * 4;
        const float* rp = rows_ + r4 * 4 * 84;
        vf4 acc0 = 0.0f, acc1 = 0.0f, acc2 = 0.0f, acc3 = 0.0f;
        #pragma unroll 7
        for (int e = 0; e < 84; e += 4) {
            vf4 w0 = *(const vf4*)(Wl + (e + 0) * 84 + c0);
            vf4 w1 = *(const vf4*)(Wl + (e + 1) * 84 + c0);
            vf4 w2 = *(const vf4*)(Wl + (e + 2) * 84 + c0);
            vf4 w3 = *(const vf4*)(Wl + (e + 3) * 84 + c0);
            vf4 r0 = *(const vf4*)(rp + e);
            vf4 r1 = *(const vf4*)(rp + 84 + e);
            vf4 r2 = *(const vf4*)(rp + 168 + e);
            vf4 r3 = *(const vf4*)(rp + 252 + e);
            acc0 += r0[0] * w0 + r0[1] * w1 + r0[2] * w2 + r0[3] * w3;
            acc1 += r1[0] * w0 + r1[1] * w1 + r1[2] * w2 + r1[3] * w3;
            acc2 += r2[0] * w0 + r2[1] * w1 + r2[2] * w2 + r2[3] * w3;
            acc3 += r3[0] * w0 + r3[1] * w1 + r3[2] * w2 + r3[3] * w3;
        }
        vf4 av[4] = {acc0, acc1, acc2, acc3};
        #pragma unroll
        for (int cc = 0; cc < 4; cc++) {
            int col = c0 + cc;
            if (col < 81) {
                #pragma unroll
                for (int rr = 0; rr < 4; rr++) {
                    int idx = (row0 + r4 * 4 + rr) * 81 + col;
                    float v = av[rr][cc];
                    h2[idx] = v;
                    xh[idx] = txall[idx] + v;
                }
            }
        }
    }
}

// ---------------- Qs/Ks (Vs == Qs): 64 rows/block, W-pass split (512 blocks), 4x4 ----------------
__global__ __launch_bounds__(512) void qks_kernel(const float* __restrict__ xh,
                           const float* __restrict__ Wq, const float* __restrict__ Wk,
                           float* __restrict__ Qs, float* __restrict__ Ks) {
    __shared__ float rows_[64 * 84];
    __shared__ float Wl[84 * 84];
    int blk = blockIdx.x;            // 0..511
    int t = blk >> 8;                // 0: Q, 1: K
    int rb = blk & 255;
    int row0 = rb * 64;
    int b = row0 >> 9;
    int s0 = row0 & 511;
    const float* W = (t == 0) ? Wq : Wk;
    int tid = threadIdx.x;
    for (int i = tid; i < 64 * 84; i += 512) {
        int c = i % 84;
        rows_[i] = (c < 81) ? xh[(row0 + i / 84) * 81 + c] : 0.0f;
    }
    for (int i = tid; i < 84 * 84; i += 512) {
        int e = i / 84, hd = i % 84;
        Wl[i] = (e < 81 && hd < 81) ? W[(hd / 9) * 729 + e * 9 + (hd % 9)] : 0.0f;
    }
    __syncthreads();
    float* dst = (t == 0) ? Qs : Ks;
    for (int o = tid; o < 336; o += 512) {
        int r4 = o / 21, cg = o % 21;
        int c0 = cg * 4;
        const float* rp = rows_ + r4 * 4 * 84;
        vf4 acc0 = 0.0f, acc1 = 0.0f, acc2 = 0.0f, acc3 = 0.0f;
        #pragma unroll 7
        for (int e = 0; e < 84; e += 4) {
            vf4 w0 = *(const vf4*)(Wl + (e + 0) * 84 + c0);
            vf4 w1 = *(const vf4*)(Wl + (e + 1) * 84 + c0);
            vf4 w2 = *(const vf4*)(Wl + (e + 2) * 84 + c0);
            vf4 w3 = *(const vf4*)(Wl + (e + 3) * 84 + c0);
            vf4 r0 = *(const vf4*)(rp + e);
            vf4 r1 = *(const vf4*)(rp + 84 + e);
            vf4 r2 = *(const vf4*)(rp + 168 + e);
            vf4 r3 = *(const vf4*)(rp + 252 + e);
            acc0 += r0[0] * w0 + r0[1] * w1 + r0[2] * w2 + r0[3] * w3;
            acc1 += r1[0] * w0 + r1[1] * w1 + r1[2] * w2 + r1[3] * w3;
            acc2 += r2[0] * w0 + r2[1] * w1 + r2[2] * w2 + r2[3] * w3;
            acc3 += r3[0] * w0 + r3[1] * w1 + r3[2] * w2 + r3[3] * w3;
        }
        vf4 av[4] = {acc0, acc1, acc2, acc3};
        #pragma unroll
        for (int cc = 0; cc < 4; cc++) {
            int col = c0 + cc;
            if (col < 81) {
                int h = col / 9, d = col % 9;
                #pragma unroll
                for (int rr = 0; rr < 4; rr++)
                    dst[((b * 9 + h) * 512 + (s0 + r4 * 4 + rr)) * 9 + d] = av[rr][cc];
            }
        }
    }
}

// ---------------- EBT[t*512+s] = exp(cw * (corr @ Cv)^T[t][s] / sqrt(S)) ----------------
__global__ __launch_bounds__(256) void biasmm_kernel(const float* __restrict__ corr,
                              const float* __restrict__ Cv, const float* __restrict__ cwp,
                              float* __restrict__ ebT) {
    __shared__ float As[32][33];
    __shared__ float Bs[32][33];
    int tx = threadIdx.x, ty = threadIdx.y;   // 16 x 16
    int tid = ty * 16 + tx;
    int t0 = blockIdx.y * 32, s0 = blockIdx.x * 32;
    float a00 = 0, a01 = 0, a10 = 0, a11 = 0;
    for (int k0 = 0; k0 < 512; k0 += 32) {
        for (int ii = tid; ii < 1024; ii += 256) {
            int r = ii >> 5, c = ii & 31;
            As[r][c] = Cv[(k0 + r) * 512 + t0 + c];
            Bs[r][c] = corr[(s0 + r) * 512 + k0 + c];
        }
        __syncthreads();
        #pragma unroll
        for (int kk = 0; kk < 32; kk++) {
            float b0 = Bs[tx][kk], b1 = Bs[tx + 16][kk];
            float c0 = As[kk][ty], c1 = As[kk][ty + 16];
            a00 += c0 * b0; a01 += c0 * b1; a10 += c1 * b0; a11 += c1 * b1;
        }
        __syncthreads();
    }
    float cws = cwp[0] * 0.04419417382415922f;   // cw / sqrt(512)
    ebT[(t0 + ty) * 512 + s0 + tx]            = __expf(a00 * cws);
    ebT[(t0 + ty) * 512 + s0 + tx + 16]       = __expf(a01 * cws);
    ebT[(t0 + ty + 16) * 512 + s0 + tx]       = __expf(a10 * cws);
    ebT[(t0 + ty + 16) * 512 + s0 + tx + 16]  = __expf(a11 * cws);
}

// ---------------- attention-1: no-max softmax (exp2), 8-way key split, atomic merge ----------------
// p = exp2(c1*log2e * q.k) * EB[key][q]
// grid 4608: bh = blk>>4, qhalf = (blk>>3)&1, kq8 = blk&7 -- ALL block-uniform (scalar K/V loads)
// each thread: 1 query x 64 keys; partials accumulated into ONE plane set via atomicAdd
// planes: part[e*147456 + (bh*512+q)], e in [0,10)  (zeroed by memset before launch)
__global__ __launch_bounds__(256) void attn1_kernel(const float* __restrict__ Qs,
                                                    const float* __restrict__ Ks,
                                                    const float* __restrict__ ebT,
                                                    const float* __restrict__ cwp,
                                                    float* __restrict__ part) {
    int blk = blockIdx.x;          // 0..4607
    int bh = blk >> 4;             // b*9+h
    int qhalf = (blk >> 3) & 1;
    int kq8 = blk & 7;
    int tid = threadIdx.x;
    const float* Kb = Ks + bh * 4608;
    const float* Qb = Qs + bh * 4608;
    int q = qhalf * 256 + tid;
    float c1 = (1.0f - cwp[0]) * (1.4426950408889634f / 3.0f);   // fold log2e
    vf2 qv[4];
    float q8;
    {
        const float* qp = Qb + q * 9;
        #pragma unroll
        for (int d = 0; d < 4; d++) {
            vf2 t; t.x = c1 * qp[2 * d]; t.y = c1 * qp[2 * d + 1];
            qv[d] = t;
        }
        q8 = c1 * qp[8];
    }
    float l = 0.0f, a8 = 0.0f;
    vf2 acc[4];
    #pragma unroll
    for (int d = 0; d < 4; d++) acc[d] = (vf2)0.0f;
    int k0 = kq8 * 64;             // block-uniform -> K/V scalar loads preserved
    const float* ebp = ebT + q;
    for (int t0 = k0; t0 < k0 + 64; t0 += 8) {
        float eb[8];
        #pragma unroll
        for (int j = 0; j < 8; j++) eb[j] = ebp[(t0 + j) << 9];
        #pragma unroll
        for (int j = 0; j < 8; j++) {
            const float* kr = Kb + (t0 + j) * 9;   // wave-uniform -> scalar loads
            const float* vr = Qb + (t0 + j) * 9;   // Vs == Qs
            vf2 k0v; k0v.x = kr[0]; k0v.y = kr[1];
            vf2 k1v; k1v.x = kr[2]; k1v.y = kr[3];
            vf2 k2v; k2v.x = kr[4]; k2v.y = kr[5];
            vf2 k3v; k3v.x = kr[6]; k3v.y = kr[7];
            vf2 u2 = qv[0] * k0v + qv[1] * k1v + qv[2] * k2v + qv[3] * k3v;
            float u = u2.x + u2.y + q8 * kr[8];
            float p = exp2f(u) * eb[j];
            l += p;
            vf2 p2; p2.x = p; p2.y = p;
            vf2 v0; v0.x = vr[0]; v0.y = vr[1];
            vf2 v1; v1.x = vr[2]; v1.y = vr[3];
            vf2 v2; v2.x = vr[4]; v2.y = vr[5];
            vf2 v3; v3.x = vr[6]; v3.y = vr[7];
            acc[0] += p2 * v0; acc[1] += p2 * v1;
            acc[2] += p2 * v2; acc[3] += p2 * v3;
            a8 += p * vr[8];
        }
    }
    int gidx = bh * 512 + q;
    atomicAdd(&part[gidx], l);
    #pragma unroll
    for (int d = 0; d < 4; d++) {
        atomicAdd(&part[(1 + 2 * d) * 147456 + gidx], acc[d].x);
        atomicAdd(&part[(2 + 2 * d) * 147456 + gidx], acc[d].y);
    }
    atomicAdd(&part[9 * 147456 + gidx], a8);
}

// ---------------- matin = (1-hw)*(h1@Wo1) + hw*h2 + tx ; merge fused, st1 fused ----------------
__global__ __launch_bounds__(512) void h1o_kernel(const float* __restrict__ apart,
                           const float* __restrict__ Wo1, const float* __restrict__ h2,
                           const float* __restrict__ txall, const float* __restrict__ hwp,
                           float* __restrict__ matin, float* __restrict__ st1) {
    __shared__ float rows_[64 * 84];
    __shared__ float Wl[84 * 84];
    __shared__ float ssum[81], ssq[81];
    int row0 = blockIdx.x * 64;
    int tid = threadIdx.x;
    if (tid < 81) { ssum[tid] = 0.0f; ssq[tid] = 0.0f; }
    // stage h1 rows from the (already-merged) atomic plane set
    for (int i = tid; i < 64 * 84; i += 512) {
        int r = i / 84, c = i % 84;
        float v = 0.0f;
        if (c < 81) {
            int row = row0 + r;             // b*512+s
            int b = row >> 9, s = row & 511;
            int h = c / 9, d = c % 9;
            int gidx = (b * 9 + h) * 512 + s;
            float L = apart[gidx];
            float A = apart[(1 + d) * 147456 + gidx];
            v = A / L;
        }
        rows_[i] = v;
    }
    for (int i = tid; i < 84 * 84; i += 512) {
        int e = i / 84, c = i % 84;
        Wl[i] = (e < 81 && c < 81) ? Wo1[e * 81 + c] : 0.0f;
    }
    __syncthreads();
    float hw = hwp[0];
    float onemhw = 1.0f - hw;
    for (int o = tid; o < 336; o += 512) {
        int r4 = o / 21, cg = o % 21;
        int c0 = cg * 4;
        const float* rp = rows_ + r4 * 4 * 84;
        vf4 acc0 = 0.0f, acc1 = 0.0f, acc2 = 0.0f, acc3 = 0.0f;
        #pragma unroll 7
        for (int e = 0; e < 84; e += 4) {
            vf4 w0 = *(const vf4*)(Wl + (e + 0) * 84 + c0);
            vf4 w1 = *(const vf4*)(Wl + (e + 1) * 84 + c0);
            vf4 w2 = *(const vf4*)(Wl + (e + 2) * 84 + c0);
            vf4 w3 = *(const vf4*)(Wl + (e + 3) * 84 + c0);
            vf4 r0 = *(const vf4*)(rp + e);
            vf4 r1 = *(const vf4*)(rp + 84 + e);
            vf4 r2 = *(const vf4*)(rp + 168 + e);
            vf4 r3 = *(const vf4*)(rp + 252 + e);
            acc0 += r0[0] * w0 + r0[1] * w1 + r0[2] * w2 + r0[3] * w3;
            acc1 += r1[0] * w0 + r1[1] * w1 + r1[2] * w2 + r1[3] * w3;
            acc2 += r2[0] * w0 + r2[1] * w1 + r2[2] * w2 + r2[3] * w3;
            acc3 += r3[0] * w0 + r3[1] * w1 + r3[2] * w2 + r3[3] * w3;
        }
        vf4 av[4] = {acc0, acc1, acc2, acc3};
        #pragma unroll
        for (int cc = 0; cc < 4; cc++) {
            int col = c0 + cc;
            if (col < 81) {
                float ls = 0.0f, lq = 0.0f;
                #pragma unroll
                for (int rr = 0; rr < 4; rr++) {
                    int idx = (row0 + r4 * 4 + rr) * 81 + col;
                    float v = onemhw * av[rr][cc] + hw * h2[idx] + txall[idx];
                    matin[idx] = v;
                    ls += v; lq += v * v;
                }
                atomicAdd(&ssum[col], ls);
                atomicAdd(&ssq[col], lq);
            }
        }
    }
    __syncthreads();
    if (tid < 81) {
        atomicAdd(&st1[tid], ssum[tid]);
        atomicAdd(&st1[81 + tid], ssq[tid]);
    }
}

// ---------------- ff1: 64 rows x 64 cols/block, 4x4 tile ; fused st2 ----------------
__global__ __launch_bounds__(512) void ff1_kernel(const float* __restrict__ matin,
                           const float* __restrict__ st1, const float* __restrict__ g1,
                           const float* __restrict__ b1, const float* __restrict__ W,
                           const float* __restrict__ bias, float* __restrict__ f1,
                           float* __restrict__ st2) {
    __shared__ float rows_[64 * 84];
    __shared__ float Wl[84 * 64];       // rows 81..83 zero
    __shared__ float s2s[64], s2q[64];
    int row0 = blockIdx.x * 64;
    int cb = blockIdx.y * 64;
    int tid = threadIdx.x;
    const float invN = 1.0f / 16384.0f;
    if (tid < 64) { s2s[tid] = 0.0f; s2q[tid] = 0.0f; }
    for (int i = tid; i < 64 * 84; i += 512) {
        int c = i % 84;
        float v = 0.0f;
        if (c < 81) {
            float mean = st1[c] * invN;
            float var = st1[81 + c] * invN - mean * mean;
            v = (matin[(row0 + i / 84) * 81 + c] - mean) * rsqrtf(var + EPSV) * g1[c] + b1[c];
        }
        rows_[i] = v;
    }
    for (int i = tid; i < 84 * 64; i += 512) {
        int e = i >> 6, cc = i & 63;
        Wl[i] = (e < 81) ? W[e * 256 + cb + cc] : 0.0f;
    }
    __syncthreads();
    if (tid < 256) {
        int o = tid;                 // 256 tasks: 16 r-groups x 16 c-groups
        int r4 = o >> 4, cg = o & 15;
        int c0 = cg * 4;
        const float* rp = rows_ + r4 * 4 * 84;
        vf4 acc0 = 0.0f, acc1 = 0.0f, acc2 = 0.0f, acc3 = 0.0f;
        #pragma unroll 7
        for (int e = 0; e < 84; e += 4) {
            vf4 w0 = *(const vf4*)(Wl + ((e + 0) << 6) + c0);
            vf4 w1 = *(const vf4*)(Wl + ((e + 1) << 6) + c0);
            vf4 w2 = *(const vf4*)(Wl + ((e + 2) << 6) + c0);
            vf4 w3 = *(const vf4*)(Wl + ((e + 3) << 6) + c0);
            vf4 r0 = *(const vf4*)(rp + e);
            vf4 r1 = *(const vf4*)(rp + 84 + e);
            vf4 r2 = *(const vf4*)(rp + 168 + e);
            vf4 r3 = *(const vf4*)(rp + 252 + e);
            acc0 += r0[0] * w0 + r0[1] * w1 + r0[2] * w2 + r0[3] * w3;
            acc1 += r1[0] * w0 + r1[1] * w1 + r1[2] * w2 + r1[3] * w3;
            acc2 += r2[0] * w0 + r2[1] * w1 + r2[2] * w2 + r2[3] * w3;
            acc3 += r3[0] * w0 + r3[1] * w1 + r3[2] * w2 + r3[3] * w3;
        }
        vf4 bv = *(const vf4*)(bias + cb + c0);
        acc0 = __builtin_elementwise_max(acc0 + bv, (vf4)0.0f);
        acc1 = __builtin_elementwise_max(acc1 + bv, (vf4)0.0f);
        acc2 = __builtin_elementwise_max(acc2 + bv, (vf4)0.0f);
        acc3 = __builtin_elementwise_max(acc3 + bv, (vf4)0.0f);
        int base = (row0 + r4 * 4) * 256 + cb + c0;
        *(vf4*)(f1 + base)       = acc0;
        *(vf4*)(f1 + base + 256) = acc1;
        *(vf4*)(f1 + base + 512) = acc2;
        *(vf4*)(f1 + base + 768) = acc3;
        vf4 cs = acc0 + acc1 + acc2 + acc3;
        vf4 cq = acc0 * acc0 + acc1 * acc1 + acc2 * acc2 + acc3 * acc3;
        #pragma unroll
        for (int cc = 0; cc < 4; cc++) {
            atomicAdd(&s2s[c0 + cc], cs[cc]);
            atomicAdd(&s2q[c0 + cc], cq[cc]);
        }
    }
    __syncthreads();
    if (tid < 64) {
        atomicAdd(&st2[cb + tid], s2s[tid]);
        atomicAdd(&st2[256 + cb + tid], s2q[tid]);
    }
}

// ---------------- ff2: 32 rows/block, 4 K-quarter passes, 4x4 tile ; fused st3 ----------------
__global__ __launch_bounds__(256) void ff2_kernel(const float* __restrict__ f1,
                           const float* __restrict__ st2, const float* __restrict__ g2,
                           const float* __restrict__ b2, const float* __restrict__ W,
                           const float* __restrict__ bias, const float* __restrict__ matin,
                           const float* __restrict__ st1, const float* __restrict__ g1,
                           const float* __restrict__ b1, float* __restrict__ t3,
                           float* __restrict__ st3) {
    __shared__ float rows_[32 * 64];
    __shared__ float Wl[64 * 84];
    __shared__ float s3s[81], s3q[81];
    int row0 = blockIdx.x * 32;
    int tid = threadIdx.x;
    const float invN = 1.0f / 16384.0f;
    if (tid < 81) { s3s[tid] = 0.0f; s3q[tid] = 0.0f; }
    int o = tid;
    int r4 = o / 21, cg = o % 21;
    int c0 = cg * 4;
    bool active = (o < 168);
    vf4 acc0 = 0.0f, acc1 = 0.0f, acc2 = 0.0f, acc3 = 0.0f;
    for (int kq = 0; kq < 4; kq++) {
        __syncthreads();
        for (int i = tid; i < 32 * 64; i += 256) {
            int r = i >> 6, e = i & 63;
            int c = kq * 64 + e;
            float mean = st2[c] * invN;
            float var = st2[256 + c] * invN - mean * mean;
            rows_[i] = (f1[(row0 + r) * 256 + c] - mean) * rsqrtf(var + EPSV) * g2[c] + b2[c];
        }
        for (int i = tid; i < 64 * 84; i += 256) {
            int e = i / 84, c = i % 84;
            Wl[i] = (c < 81) ? W[(kq * 64 + e) * 81 + c] : 0.0f;
        }
        __syncthreads();
        if (active) {
            const float* rp = rows_ + r4 * 4 * 64;
            #pragma unroll 8
            for (int e = 0; e < 64; e += 4) {
                vf4 w0 = *(const vf4*)(Wl + (e + 0) * 84 + c0);
                vf4 w1 = *(const vf4*)(Wl + (e + 1) * 84 + c0);
                vf4 w2 = *(const vf4*)(Wl + (e + 2) * 84 + c0);
                vf4 w3 = *(const vf4*)(Wl + (e + 3) * 84 + c0);
                vf4 r0 = *(const vf4*)(rp + e);
                vf4 r1 = *(const vf4*)(rp + 64 + e);
                vf4 r2 = *(const vf4*)(rp + 128 + e);
                vf4 r3 = *(const vf4*)(rp + 192 + e);
                acc0 += r0[0] * w0 + r0[1] * w1 + r0[2] * w2 + r0[3] * w3;
                acc1 += r1[0] * w0 + r1[1] * w1 + r1[2] * w2 + r1[3] * w3;
                acc2 += r2[0] * w0 + r2[1] * w1 + r2[2] * w2 + r2[3] * w3;
                acc3 += r3[0] * w0 + r3[1] * w1 + r3[2] * w2 + r3[3] * w3;
            }
        }
    }
    if (active) {
        vf4 av[4] = {acc0, acc1, acc2, acc3};
        #pragma unroll
        for (int cc = 0; cc < 4; cc++) {
            int col = c0 + cc;
            if (col < 81) {
                float mean = st1[col] * invN;
                float var = st1[81 + col] * invN - mean * mean;
                float rstd = rsqrtf(var + EPSV);
                float bval = bias[col];
                float ls = 0.0f, lq = 0.0f;
                #pragma unroll
                for (int rr = 0; rr < 4; rr++) {
                    int idx = (row0 + r4 * 4 + rr) * 81 + col;
                    float ma = (matin[idx] - mean) * rstd * g1[col] + b1[col];
                    float v = ma + fmaxf(av[rr][cc] + bval, 0.0f);
                    t3[idx] = v;
                    ls += v; lq += v * v;
                }
                atomicAdd(&s3s[col], ls);
                atomicAdd(&s3q[col], lq);
            }
        }
    }
    __syncthreads();
    if (tid < 81) {
        atomicAdd(&st3[tid], s3s[tid]);
        atomicAdd(&st3[81 + tid], s3q[tid]);
    }
}

// ---------------- token_mm: u/v dual GEMM (64 rows/block, W-pass split, 4x4 tile) ----------------
__global__ __launch_bounds__(512) void token_mm(const float* __restrict__ t3,
                            const float* __restrict__ st3, const float* __restrict__ g3,
                            const float* __restrict__ b3, const float* __restrict__ tvw,
                            const float* __restrict__ beta1,
                            float* __restrict__ uv0, float* __restrict__ uv1) {
    __shared__ float rows_[64 * 84];
    __shared__ float Wl[84 * 84];
    int blk = blockIdx.x;            // 0..511
    int t = blk >> 8;
    int row0 = (blk & 255) * 64;
    const float* W = (t == 0) ? tvw : beta1;
    float* dst = (t == 0) ? uv0 : uv1;
    int tid = threadIdx.x;
    const float invN = 1.0f / 16384.0f;
    for (int i = tid; i < 64 * 84; i += 512) {
        int c = i % 84;
        float v = 0.0f;
        if (c < 81) {
            float mean = st3[c] * invN;
            float var = st3[81 + c] * invN - mean * mean;
            v = (t3[(row0 + i / 84) * 81 + c] - mean) * rsqrtf(var + EPSV) * g3[c] + b3[c];
        }
        rows_[i] = v;
    }
    for (int i = tid; i < 84 * 84; i += 512) {
        int e = i / 84, c = i % 84;
        Wl[i] = (e < 81 && c < 81) ? W[e * 81 + c] : 0.0f;
    }
    __syncthreads();
    for (int o = tid; o < 336; o += 512) {
        int r4 = o / 21, cg = o % 21;
        int c0 = cg * 4;
        const float* rp = rows_ + r4 * 4 * 84;
        vf4 acc0 = 0.0f, acc1 = 0.0f, acc2 = 0.0f, acc3 = 0.0f;
        #pragma unroll 7
        for (int e = 0; e < 84; e += 4) {
            vf4 w0 = *(const vf4*)(Wl + (e + 0) * 84 + c0);
            vf4 w1 = *(const vf4*)(Wl + (e + 1) * 84 + c0);
            vf4 w2 = *(const vf4*)(Wl + (e + 2) * 84 + c0);
            vf4 w3 = *(const vf4*)(Wl + (e + 3) * 84 + c0);
            vf4 r0 = *(const vf4*)(rp + e);
            vf4 r1 = *(const vf4*)(rp + 84 + e);
            vf4 r2 = *(const vf4*)(rp + 168 + e);
            vf4 r3 = *(const vf4*)(rp + 252 + e);
            acc0 += r0[0] * w0 + r0[1] * w1 + r0[2] * w2 + r0[3] * w3;
            acc1 += r1[0] * w0 + r1[1] * w1 + r1[2] * w2 + r1[3] * w3;
            acc2 += r2[0] * w0 + r2[1] * w1 + r2[2] * w2 + r2[3] * w3;
            acc3 += r3[0] * w0 + r3[1] * w1 + r3[2] * w2 + r3[3] * w3;
        }
        vf4 av[4] = {acc0, acc1, acc2, acc3};
        #pragma unroll
        for (int cc = 0; cc < 4; cc++) {
            int col = c0 + cc;
            if (col < 81) {
                #pragma unroll
                for (int rr = 0; rr < 4; rr++)
                    dst[(row0 + r4 * 4 + rr) * 81 + col] = av[rr][cc];
            }
        }
    }
}

// ---------------- token_pool: softmax-pool over 81, 32 rows/block, 8 lanes/row ----------------
__global__ __launch_bounds__(256) void token_pool(const float* __restrict__ uv0,
                             const float* __restrict__ uv1, const float* __restrict__ tvb,
                             const float* __restrict__ basel, const float* __restrict__ a1p,
                             const float* __restrict__ a2p, float* __restrict__ fea) {
    int tid = threadIdx.x;
    int r = tid >> 3, j = tid & 7;
    int row = blockIdx.x * 32 + r;
    int base = row * 81;
    float u[11], v[11];
    #pragma unroll
    for (int dd = 0; dd < 11; dd++) {
        int d = j + dd * 8;
        if (d < 81) {
            u[dd] = uv0[base + d] + tvb[d];
            v[dd] = uv1[base + d];
        } else {
            u[dd] = 0.0f; v[dd] = -1e30f;
        }
    }
    float mx = -1e30f;
    #pragma unroll
    for (int dd = 0; dd < 11; dd++) mx = fmaxf(mx, v[dd]);
    #pragma unroll
    for (int msk = 1; msk < 8; msk <<= 1) mx = fmaxf(mx, __shfl_xor(mx, msk, 8));
    float sp = 0.0f, sup = 0.0f;
    #pragma unroll
    for (int dd = 0; dd < 11; dd++) {
        float p = __expf(v[dd] - mx);
        sp += p; sup += u[dd] * p;
    }
    #pragma unroll
    for (int msk = 1; msk < 8; msk <<= 1) {
        sp  += __shfl_xor(sp, msk, 8);
        sup += __shfl_xor(sup, msk, 8);
    }
    if (j == 0) {
        int b = row >> 9, s = row & 511;
        fea[row] = a1p[0] * (sup / sp) + a2p[0] * basel[b * 2048 + s * 4];
    }
}

// ---------------- fc1: relu(fea @ W + b), fused st4 ----------------
__global__ void fc1_kernel(const float* __restrict__ in, const float* __restrict__ W,
                           const float* __restrict__ bias, float* __restrict__ out,
                           float* __restrict__ st) {
    int idx = blockIdx.x * blockDim.x + threadIdx.x;
    if (idx >= 32 * 512) return;
    int b = idx >> 9, j = idx & 511;
    float acc = bias[j];
    const float* ip = in + (b << 9);
    #pragma unroll 8
    for (int k = 0; k < 512; k++) acc += ip[k] * W[k * 512 + j];
    acc = fmaxf(acc, 0.0f);
    out[idx] = acc;
    atomicAdd(&st[j], acc);
    atomicAdd(&st[512 + j], acc * acc);
}

// ---------------- fc2: relu(bn(fch1) @ W + b), fused st5 ----------------
__global__ __launch_bounds__(256) void fc2_kernel(const float* __restrict__ in,
                           const float* __restrict__ st4, const float* __restrict__ g,
                           const float* __restrict__ bb, const float* __restrict__ W,
                           const float* __restrict__ bias, float* __restrict__ out,
                           float* __restrict__ st5) {
    __shared__ float scale[512], shift[512];
    int tid = threadIdx.x;
    for (int k = tid; k < 512; k += 256) {
        float mean = st4[k] * (1.0f / 32.0f);
        float var = st4[512 + k] * (1.0f / 32.0f) - mean * mean;
        float sc_ = rsqrtf(var + EPSV) * g[k];
        scale[k] = sc_;
        shift[k] = bb[k] - mean * sc_;
    }
    __syncthreads();
    int idx = blockIdx.x * 256 + tid;
    if (idx >= 32 * 256) return;
    int b = idx >> 8, j = idx & 255;
    float acc = bias[j];
    const float* ip = in + (b << 9);
    #pragma unroll 8
    for (int k = 0; k < 512; k++) acc += (ip[k] * scale[k] + shift[k]) * W[k * 256 + j];
    acc = fmaxf(acc, 0.0f);
    out[idx] = acc;
    atomicAdd(&st5[j], acc);
    atomicAdd(&st5[256 + j], acc * acc);
}

// ---------------- fc3: tanh(bn(fch2) @ W + b) ----------------
__global__ void fc3_kernel(const float* __restrict__ in, const float* __restrict__ st5,
                           const float* __restrict__ g, const float* __restrict__ bb,
                           const float* __restrict__ W, const float* __restrict__ bias,
                           float* __restrict__ out) {
    __shared__ float scale[256], shift[256];
    int tid = threadIdx.x;   // 128
    for (int k = tid; k < 256; k += 128) {
        float mean = st5[k] * (1.0f / 32.0f);
        float var = st5[256 + k] * (1.0f / 32.0f) - mean * mean;
        float sc_ = rsqrtf(var + EPSV) * g[k];
        scale[k] = sc_;
        shift[k] = bb[k] - mean * sc_;
    }
    __syncthreads();
    int b = tid >> 2, j = tid & 3;
    float acc = bias[j];
    const float* ip = in + (b << 8);
    #pragma unroll 8
    for (int k = 0; k < 256; k++) acc += (ip[k] * scale[k] + shift[k]) * W[k * 4 + j];
    out[tid] = tanhf(acc);
}

// =======================================================================
extern "C" void kernel_launch(void* const* d_in, const int* in_sizes, int n_in,
                              void* d_out, int out_size, void* d_ws, size_t ws_size,
                              hipStream_t stream) {
    const float* x       = (const float*)d_in[0];
    const float* basel   = (const float*)d_in[1];
    const float* cali    = (const float*)d_in[2];
    const float* Wq      = (const float*)d_in[3];
    const float* Wk      = (const float*)d_in[4];
    const float* Wq2     = (const float*)d_in[5];
    const float* Wk2     = (const float*)d_in[6];
    const float* Wv2     = (const float*)d_in[7];
    const float* Cv      = (const float*)d_in[8];
    const float* Wo1     = (const float*)d_in[9];
    const float* Wo2     = (const float*)d_in[10];
    const float* corr_w  = (const float*)d_in[11];
    const float* h_w     = (const float*)d_in[12];
    const float* corr    = (const float*)d_in[13];
    const float* g1      = (const float*)d_in[14];
    const float* b1      = (const float*)d_in[15];
    const float* ff1_w   = (const float*)d_in[16];
    const float* ff1_b   = (const float*)d_in[17];
    const float* g2      = (const float*)d_in[18];
    const float* b2      = (const float*)d_in[19];
    const float* ff2_w   = (const float*)d_in[20];
    const float* ff2_b   = (const float*)d_in[21];
    const float* g3      = (const float*)d_in[22];
    const float* b3      = (const float*)d_in[23];
    const float* tvw     = (const float*)d_in[24];
    const float* tvb     = (const float*)d_in[25];
    const float* beta1   = (const float*)d_in[26];
    const float* a1      = (const float*)d_in[27];
    const float* a2      = (const float*)d_in[28];
    const float* fc1_w   = (const float*)d_in[29];
    const float* fc1_b   = (const float*)d_in[30];
    const float* bnf1_g  = (const float*)d_in[31];
    const float* bnf1_b  = (const float*)d_in[32];
    const float* fc2_w   = (const float*)d_in[33];
    const float* fc2_b   = (const float*)d_in[34];
    const float* bnf2_g  = (const float*)d_in[35];
    const float* bnf2_b  = (const float*)d_in[36];
    const float* fc3_w   = (const float*)d_in[37];
    const float* fc3_b   = (const float*)d_in[38];
    float* out = (float*)d_out;
    float* ws = (float*)d_ws;

    // ---- workspace layout (float offsets) ----
    const size_t SCAL  = 0;         // 2
    const size_t PART  = 16;        // 128
    const size_t ST1   = 512;       // 162
    const size_t ST2   = 768;       // 512
    const size_t ST3   = 1536;      // 162
    const size_t ST4   = 1792;      // 1024
    const size_t ST5   = 2880;      // 512
    const size_t FEA   = 4096;      // 16384
    const size_t FCH1  = 20480;     // 16384
    const size_t FCH2  = 36864;     // 8192
    const size_t PEO   = 45056;     // 41472
    const size_t TX    = 90112;     // 1990656
    const size_t Q2O   = 2080768;   // 1327104
    const size_t KCO   = 3407872;   // 1990656   (reused: Qs)
    const size_t VCO   = 5398528;   // 1990656   (reused: Ks)
    const size_t TMP2  = 7389184;   // 1327104   (reused: matin, then uv0)
    const size_t H2O   = 8716288;   // 1327104   (reused: t3)
    const size_t XHO   = 10043392;  // 1327104   (xh, dead after qks -> uv1)
    const size_t BIASO = 11370496;  // 262144    (EBT)
    const size_t F1O   = 11632640;  // 4194304   (f1; also attn1 planes 1474560)

    float* scal  = ws + SCAL;
    float* part  = ws + PART;
    float* st1   = ws + ST1;
    float* st2   = ws + ST2;
    float* st3   = ws + ST3;
    float* st4   = ws + ST4;
    float* st5   = ws + ST5;
    float* fea   = ws + FEA;
    float* fch1  = ws + FCH1;
    float* fch2  = ws + FCH2;
    float* pe    = ws + PEO;
    float* txall = ws + TX;
    float* Q2    = ws + Q2O;
    float* Kc    = ws + KCO;
    float* Vc    = ws + VCO;
    float* tmp2  = ws + TMP2;
    float* h2    = ws + H2O;
    float* xh    = ws + XHO;
    float* ebT   = ws + BIASO;
    float* f1    = ws + F1O;
    float* Qs    = Kc;     // reuse
    float* Ks    = Vc;     // reuse
    float* matin = tmp2;   // reuse (dead after ff2 -> uv0)
    float* t3    = h2;     // reuse
    float* apart = f1;     // attn1 atomic planes (10 x 147456 floats) in f1 region
    float* uv0   = tmp2;   // token u plane (matin dead after ff2)
    float* uv1   = xh;     // token v plane (xh dead after qks)

    // zero scal/part/stats region — capture-safe
    hipMemsetAsync(ws, 0, 4096 * sizeof(float), stream);
    // zero attn1 atomic planes (5.9 MB)
    hipMemsetAsync(apart, 0, 1474560 * sizeof(float), stream);

    minmax_part<<<64, 256, 0, stream>>>(x, part);
    minmax_fin<<<1, 64, 0, stream>>>(part, scal);

    pe_kernel<<<(512 * 81 + 255) / 256, 256, 0, stream>>>(pe);

    tokenize_kernel<<<(48 * 512 * 81 + 255) / 256, 256, 0, stream>>>(x, cali, scal, pe, txall);

    qkv2_kernel<<<1024, 512, 0, stream>>>(txall, Wq2, Wk2, Wv2, Q2, Kc, Vc);

    attn2_kernel<<<(512 * 9 * 32) / 256, 256, 0, stream>>>(Q2, Kc, Vc, tmp2);

    h2xh_kernel<<<256, 512, 0, stream>>>(tmp2, Wo2, txall, h2, xh);

    qks_kernel<<<512, 512, 0, stream>>>(xh, Wq, Wk, Qs, Ks);

    biasmm_kernel<<<dim3(16, 16), dim3(16, 16), 0, stream>>>(corr, Cv, corr_w, ebT);

    attn1_kernel<<<4608, 256, 0, stream>>>(Qs, Ks, ebT, corr_w, apart);

    h1o_kernel<<<256, 512, 0, stream>>>(apart, Wo1, h2, txall, h_w, matin, st1);

    ff1_kernel<<<dim3(256, 4), 512, 0, stream>>>(matin, st1, g1, b1, ff1_w, ff1_b, f1, st2);

    ff2_kernel<<<512, 256, 0, stream>>>(f1, st2, g2, b2, ff2_w, ff2_b,
                                        matin, st1, g1, b1, t3, st3);

    token_mm<<<512, 512, 0, stream>>>(t3, st3, g3, b3, tvw, beta1, uv0, uv1);
    token_pool<<<512, 256, 0, stream>>>(uv0, uv1, tvb, basel, a1, a2, fea);

    fc1_kernel<<<64, 256, 0, stream>>>(fea, fc1_w, fc1_b, fch1, st4);

    fc2_kernel<<<32, 256, 0, stream>>>(fch1, st4, bnf1_g, bnf1_b, fc2_w, fc2_b, fch2, st5);

    fc3_kernel<<<1, 128, 0, stream>>>(fch2, st5, bnf2_g, bnf2_b, fc3_w, fc3_b, out);
}

// Round 20
// 403.461 us; speedup vs baseline: 1.4117x; 1.0143x over previous
//
#include <hip/hip_runtime.h>
#include <hip/hip_bf16.h>
#include <math.h>

#define EPSV 1e-5f

typedef float vf2 __attribute__((ext_vector_type(2)));
typedef float vf4 __attribute__((ext_vector_type(4)));

// ---------------- sizes ----------------
// B=32 Bc=16 L=2048 TOKEN=40 STRIDE=4 D=81 H=9 dk=9 S=512 FF=256 FC1=512 FC2=256 Y=4

// ---------------- minmax: two-stage ----------------
__global__ void minmax_part(const float* __restrict__ x, float* __restrict__ part) {
    __shared__ float smin[256], smax[256];
    int tid = threadIdx.x;
    float mn = 1e30f, mx = -1e30f;
    for (int i = blockIdx.x * 256 + tid; i < 32 * 2008; i += 64 * 256) {
        int b = i / 2008, c = i % 2008 + 20;
        float v = x[b * 2048 + c];
        mn = fminf(mn, v); mx = fmaxf(mx, v);
    }
    smin[tid] = mn; smax[tid] = mx; __syncthreads();
    for (int off = 128; off > 0; off >>= 1) {
        if (tid < off) { smin[tid] = fminf(smin[tid], smin[tid + off]); smax[tid] = fmaxf(smax[tid], smax[tid + off]); }
        __syncthreads();
    }
    if (tid == 0) { part[blockIdx.x] = smin[0]; part[64 + blockIdx.x] = smax[0]; }
}

__global__ void minmax_fin(const float* __restrict__ part, float* __restrict__ scal) {
    __shared__ float smn[64], smx[64];
    int tid = threadIdx.x;
    smn[tid] = part[tid]; smx[tid] = part[64 + tid]; __syncthreads();
    for (int off = 32; off > 0; off >>= 1) {
        if (tid < off) { smn[tid] = fminf(smn[tid], smn[tid + off]); smx[tid] = fmaxf(smx[tid], smx[tid + off]); }
        __syncthreads();
    }
    if (tid == 0) { scal[0] = smn[0]; scal[1] = smx[0] - smn[0]; }
}

// ---------------- PE table (512 x 81) ----------------
__global__ void pe_kernel(float* __restrict__ pe) {
    int idx = blockIdx.x * blockDim.x + threadIdx.x;
    if (idx >= 512 * 81) return;
    int d = idx % 81, s = idx / 81;
    int j = d >> 1;
    float dv = __expf(-9.210340371976184f * (2.0f * (float)j) / 81.0f);
    float ang = (float)s * dv;
    pe[idx] = (d & 1) ? cosf(ang) : sinf(ang);
}

// ---------------- tokenize + add PE ----------------
__global__ void tokenize_kernel(const float* __restrict__ x, const float* __restrict__ cali,
                                const float* __restrict__ scal, const float* __restrict__ pe,
                                float* __restrict__ txall) {
    int idx = blockIdx.x * blockDim.x + threadIdx.x;
    if (idx >= 48 * 512 * 81) return;
    int d = idx % 81;
    int s = (idx / 81) % 512;
    int r = idx / (81 * 512);
    float xm = scal[0], inv_xs = 1.0f / scal[1];
    int oc = s * 4 + d - 40;
    float val = 0.0f;
    if (oc >= 0 && oc < 2048) {
        float sv = (r < 32) ? x[r * 2048 + oc] : cali[(r - 32) * 2048 + oc];
        val = (sv - xm) * inv_xs;
    }
    txall[idx] = val + pe[s * 81 + d];
}

// ======== 4x4-tile 81->81 GEMM pieces (rows stride 84, W [e][col] stride 84) ========
// 512 threads/block: staging strides 512, compute single pass (336 tasks of 512 threads)

// ---------------- qkv2: 64 rows/block, W-pass split (1024 blocks), 4x4 tile ----------------
__global__ __launch_bounds__(512) void qkv2_kernel(const float* __restrict__ txall,
                            const float* __restrict__ Wq2, const float* __restrict__ Wk2,
                            const float* __restrict__ Wv2,
                            float* __restrict__ Q2, float* __restrict__ Kc, float* __restrict__ Vc) {
    __shared__ float rows_[64 * 84];
    __shared__ float Wl[84 * 84];
    int blk = blockIdx.x;            // 0..1023
    int t, rb;
    if (blk < 256)      { t = 0; rb = blk; }
    else if (blk < 640) { t = 1; rb = blk - 256; }
    else                { t = 2; rb = blk - 640; }
    int row0 = rb * 64;
    int k = row0 >> 9;
    int s0 = row0 & 511;
    const float* W = (t == 0) ? Wq2 : (t == 1) ? Wk2 : Wv2;
    int tid = threadIdx.x;
    for (int i = tid; i < 64 * 84; i += 512) {
        int c = i % 84;
        rows_[i] = (c < 81) ? txall[(row0 + i / 84) * 81 + c] : 0.0f;
    }
    for (int i = tid; i < 84 * 84; i += 512) {
        int e = i / 84, hd = i % 84;
        Wl[i] = (e < 81 && hd < 81) ? W[(hd / 9) * 729 + e * 9 + (hd % 9)] : 0.0f;
    }
    __syncthreads();
    for (int o = tid; o < 336; o += 512) {
        int r4 = o / 21, cg = o % 21;
        int c0 = cg * 4;
        const float* rp = rows_ + r4 * 4 * 84;
        vf4 acc0 = 0.0f, acc1 = 0.0f, acc2 = 0.0f, acc3 = 0.0f;
        #pragma unroll 7
        for (int e = 0; e < 84; e += 4) {
            vf4 w0 = *(const vf4*)(Wl + (e + 0) * 84 + c0);
            vf4 w1 = *(const vf4*)(Wl + (e + 1) * 84 + c0);
            vf4 w2 = *(const vf4*)(Wl + (e + 2) * 84 + c0);
            vf4 w3 = *(const vf4*)(Wl + (e + 3) * 84 + c0);
            vf4 r0 = *(const vf4*)(rp + e);
            vf4 r1 = *(const vf4*)(rp + 84 + e);
            vf4 r2 = *(const vf4*)(rp + 168 + e);
            vf4 r3 = *(const vf4*)(rp + 252 + e);
            acc0 += r0[0] * w0 + r0[1] * w1 + r0[2] * w2 + r0[3] * w3;
            acc1 += r1[0] * w0 + r1[1] * w1 + r1[2] * w2 + r1[3] * w3;
            acc2 += r2[0] * w0 + r2[1] * w1 + r2[2] * w2 + r2[3] * w3;
            acc3 += r3[0] * w0 + r3[1] * w1 + r3[2] * w2 + r3[3] * w3;
        }
        vf4 av[4] = {acc0, acc1, acc2, acc3};
        #pragma unroll
        for (int cc = 0; cc < 4; cc++) {
            int col = c0 + cc;
            if (col < 81) {
                int h = col / 9, d = col % 9;
                #pragma unroll
                for (int rr = 0; rr < 4; rr++) {
                    int s = s0 + r4 * 4 + rr;
                    if (t == 0)      Q2[((s * 9 + h) * 32 + k) * 9 + d] = av[rr][cc];
                    else if (t == 1) Kc[((s * 9 + h) * 48 + k) * 9 + d] = av[rr][cc];
                    else             Vc[((s * 9 + h) * 48 + k) * 9 + d] = av[rr][cc];
                }
            }
        }
    }
}

// ---------------- attention-2 (masked: key==b or key>=32), no-max softmax (exp2) ----------------
__global__ void attn2_kernel(const float* __restrict__ Q2, const float* __restrict__ Kc,
                             const float* __restrict__ Vc, float* __restrict__ tmp2) {
    int tid = blockIdx.x * blockDim.x + threadIdx.x;
    if (tid >= 512 * 9 * 32) return;
    int b = tid & 31;
    int h = (tid >> 5) % 9;
    int s = tid / 288;
    const float* q = Q2 + ((s * 9 + h) * 32 + b) * 9;
    float qr[9];
    const float c2 = 1.4426950408889634f / 3.0f;   // log2e / 3
    #pragma unroll
    for (int d = 0; d < 9; d++) qr[d] = q[d] * c2;
    const float* Kb = Kc + (s * 9 + h) * 48 * 9;
    const float* Vb = Vc + (s * 9 + h) * 48 * 9;
    float l = 0.0f, outv[9];
    #pragma unroll
    for (int d = 0; d < 9; d++) outv[d] = 0.0f;
    #pragma unroll
    for (int j = 0; j < 17; j++) {
        int k = (j == 0) ? b : 31 + j;
        const float* kp = Kb + k * 9;
        float acc = 0.0f;
        #pragma unroll
        for (int d = 0; d < 9; d++) acc += qr[d] * kp[d];
        float p = exp2f(acc);
        l += p;
        const float* vp = Vb + k * 9;
        #pragma unroll
        for (int d = 0; d < 9; d++) outv[d] += p * vp[d];
    }
    float invl = 1.0f / l;
    float* op = tmp2 + (b * 512 + s) * 81 + h * 9;
    #pragma unroll
    for (int d = 0; d < 9; d++) op[d] = outv[d] * invl;
}

// ---------------- h2 = tmp2 @ Wo2 ; xh = tx + h2  (64 rows/block, 4x4 tile) ----------------
__global__ __launch_bounds__(512) void h2xh_kernel(const float* __restrict__ tmp2,
                            const float* __restrict__ Wo2, const float* __restrict__ txall,
                            float* __restrict__ h2, float* __restrict__ xh) {
    __shared__ float rows_[64 * 84];
    __shared__ float Wl[84 * 84];
    int row0 = blockIdx.x * 64;
    int tid = threadIdx.x;
    for (int i = tid; i < 64 * 84; i += 512) {
        int c = i % 84;
        rows_[i] = (c < 81) ? tmp2[(row0 + i / 84) * 81 + c] : 0.0f;
    }
    for (int i = tid; i < 84 * 84; i += 512) {
        int e = i / 84, c = i % 84;
        Wl[i] = (e < 81 && c < 81) ? Wo2[e * 81 + c] : 0.0f;
    }
    __syncthreads();
    for (int o = tid; o < 336; o += 512) {
        int r4 = o / 21, cg = o % 21;
        int c0 = cg * 4;
        const float* rp = rows_ + r4 * 4 * 84;
        vf4 acc0 = 0.0f, acc1 = 0.0f, acc2 = 0.0f, acc3 = 0.0f;
        #pragma unroll 7
        for (int e = 0; e < 84; e += 4) {
            vf4 w0 = *(const vf4*)(Wl + (e + 0) * 84 + c0);
            vf4 w1 = *(const vf4*)(Wl + (e + 1) * 84 + c0);
            vf4 w2 = *(const vf4*)(Wl + (e + 2) * 84 + c0);
            vf4 w3 = *(const vf4*)(Wl + (e + 3) * 84 + c0);
            vf4 r0 = *(const vf4*)(rp + e);
            vf4 r1 = *(const vf4*)(rp + 84 + e);
            vf4 r2 = *(const vf4*)(rp + 168 + e);
            vf4 r3 = *(const vf4*)(rp + 252 + e);
            acc0 += r0[0] * w0 + r0[1] * w1 + r0[2] * w2 + r0[3] * w3;
            acc1 += r1[0] * w0 + r1[1] * w1 + r1[2] * w2 + r1[3] * w3;
            acc2 += r2[0] * w0 + r2[1] * w1 + r2[2] * w2 + r2[3] * w3;
            acc3 += r3[0] * w0 + r3[1] * w1 + r3[2] * w2 + r3[3] * w3;
        }
        vf4 av[4] = {acc0, acc1, acc2, acc3};
        #pragma unroll
        for (int cc = 0; cc < 4; cc++) {
            int col = c0 + cc;
            if (col < 81) {
                #pragma unroll
                for (int rr = 0; rr < 4; rr++) {
                    int idx = (row0 + r4 * 4 + rr) * 81 + col;
                    float v = av[rr][cc];
                    h2[idx] = v;
                    xh[idx] = txall[idx] + v;
                }
            }
        }
    }
}

// ---------------- Qs/Ks (Vs == Qs): 64 rows/block, W-pass split (512 blocks), 4x4 ----------------
__global__ __launch_bounds__(512) void qks_kernel(const float* __restrict__ xh,
                           const float* __restrict__ Wq, const float* __restrict__ Wk,
                           float* __restrict__ Qs, float* __restrict__ Ks) {
    __shared__ float rows_[64 * 84];
    __shared__ float Wl[84 * 84];
    int blk = blockIdx.x;            // 0..511
    int t = blk >> 8;                // 0: Q, 1: K
    int rb = blk & 255;
    int row0 = rb * 64;
    int b = row0 >> 9;
    int s0 = row0 & 511;
    const float* W = (t == 0) ? Wq : Wk;
    int tid = threadIdx.x;
    for (int i = tid; i < 64 * 84; i += 512) {
        int c = i % 84;
        rows_[i] = (c < 81) ? xh[(row0 + i / 84) * 81 + c] : 0.0f;
    }
    for (int i = tid; i < 84 * 84; i += 512) {
        int e = i / 84, hd = i % 84;
        Wl[i] = (e < 81 && hd < 81) ? W[(hd / 9) * 729 + e * 9 + (hd % 9)] : 0.0f;
    }
    __syncthreads();
    float* dst = (t == 0) ? Qs : Ks;
    for (int o = tid; o < 336; o += 512) {
        int r4 = o / 21, cg = o % 21;
        int c0 = cg * 4;
        const float* rp = rows_ + r4 * 4 * 84;
        vf4 acc0 = 0.0f, acc1 = 0.0f, acc2 = 0.0f, acc3 = 0.0f;
        #pragma unroll 7
        for (int e = 0; e < 84; e += 4) {
            vf4 w0 = *(const vf4*)(Wl + (e + 0) * 84 + c0);
            vf4 w1 = *(const vf4*)(Wl + (e + 1) * 84 + c0);
            vf4 w2 = *(const vf4*)(Wl + (e + 2) * 84 + c0);
            vf4 w3 = *(const vf4*)(Wl + (e + 3) * 84 + c0);
            vf4 r0 = *(const vf4*)(rp + e);
            vf4 r1 = *(const vf4*)(rp + 84 + e);
            vf4 r2 = *(const vf4*)(rp + 168 + e);
            vf4 r3 = *(const vf4*)(rp + 252 + e);
            acc0 += r0[0] * w0 + r0[1] * w1 + r0[2] * w2 + r0[3] * w3;
            acc1 += r1[0] * w0 + r1[1] * w1 + r1[2] * w2 + r1[3] * w3;
            acc2 += r2[0] * w0 + r2[1] * w1 + r2[2] * w2 + r2[3] * w3;
            acc3 += r3[0] * w0 + r3[1] * w1 + r3[2] * w2 + r3[3] * w3;
        }
        vf4 av[4] = {acc0, acc1, acc2, acc3};
        #pragma unroll
        for (int cc = 0; cc < 4; cc++) {
            int col = c0 + cc;
            if (col < 81) {
                int h = col / 9, d = col % 9;
                #pragma unroll
                for (int rr = 0; rr < 4; rr++)
                    dst[((b * 9 + h) * 512 + (s0 + r4 * 4 + rr)) * 9 + d] = av[rr][cc];
            }
        }
    }
}

// ---------------- EBT[t*512+s] = exp(cw * (corr @ Cv)^T[t][s] / sqrt(S)) ----------------
__global__ __launch_bounds__(256) void biasmm_kernel(const float* __restrict__ corr,
                              const float* __restrict__ Cv, const float* __restrict__ cwp,
                              float* __restrict__ ebT) {
    __shared__ float As[32][33];
    __shared__ float Bs[32][33];
    int tx = threadIdx.x, ty = threadIdx.y;   // 16 x 16
    int tid = ty * 16 + tx;
    int t0 = blockIdx.y * 32, s0 = blockIdx.x * 32;
    float a00 = 0, a01 = 0, a10 = 0, a11 = 0;
    for (int k0 = 0; k0 < 512; k0 += 32) {
        for (int ii = tid; ii < 1024; ii += 256) {
            int r = ii >> 5, c = ii & 31;
            As[r][c] = Cv[(k0 + r) * 512 + t0 + c];
            Bs[r][c] = corr[(s0 + r) * 512 + k0 + c];
        }
        __syncthreads();
        #pragma unroll
        for (int kk = 0; kk < 32; kk++) {
            float b0 = Bs[tx][kk], b1 = Bs[tx + 16][kk];
            float c0 = As[kk][ty], c1 = As[kk][ty + 16];
            a00 += c0 * b0; a01 += c0 * b1; a10 += c1 * b0; a11 += c1 * b1;
        }
        __syncthreads();
    }
    float cws = cwp[0] * 0.04419417382415922f;   // cw / sqrt(512)
    ebT[(t0 + ty) * 512 + s0 + tx]            = __expf(a00 * cws);
    ebT[(t0 + ty) * 512 + s0 + tx + 16]       = __expf(a01 * cws);
    ebT[(t0 + ty + 16) * 512 + s0 + tx]       = __expf(a10 * cws);
    ebT[(t0 + ty + 16) * 512 + s0 + tx + 16]  = __expf(a11 * cws);
}

// ---------------- attention-1: no-max softmax (exp2), 8-way key split, atomic merge ----------------
// p = exp2(c1*log2e * q.k) * EB[key][q]
// grid 4608: bh = blk>>4, qhalf = (blk>>3)&1, kq8 = blk&7 -- ALL block-uniform (scalar K/V loads)
// each thread: 1 query x 64 keys; partials accumulated into ONE plane set via atomicAdd
// planes: part[e*147456 + (bh*512+q)], e in [0,10)  (zeroed by memset before launch)
__global__ __launch_bounds__(256) void attn1_kernel(const float* __restrict__ Qs,
                                                    const float* __restrict__ Ks,
                                                    const float* __restrict__ ebT,
                                                    const float* __restrict__ cwp,
                                                    float* __restrict__ part) {
    int blk = blockIdx.x;          // 0..4607
    int bh = blk >> 4;             // b*9+h
    int qhalf = (blk >> 3) & 1;
    int kq8 = blk & 7;
    int tid = threadIdx.x;
    const float* Kb = Ks + bh * 4608;
    const float* Qb = Qs + bh * 4608;
    int q = qhalf * 256 + tid;
    float c1 = (1.0f - cwp[0]) * (1.4426950408889634f / 3.0f);   // fold log2e
    vf2 qv[4];
    float q8;
    {
        const float* qp = Qb + q * 9;
        #pragma unroll
        for (int d = 0; d < 4; d++) {
            vf2 t; t.x = c1 * qp[2 * d]; t.y = c1 * qp[2 * d + 1];
            qv[d] = t;
        }
        q8 = c1 * qp[8];
    }
    float l = 0.0f, a8 = 0.0f;
    vf2 acc[4];
    #pragma unroll
    for (int d = 0; d < 4; d++) acc[d] = (vf2)0.0f;
    int k0 = kq8 * 64;             // block-uniform -> K/V scalar loads preserved
    const float* ebp = ebT + q;
    for (int t0 = k0; t0 < k0 + 64; t0 += 8) {
        float eb[8];
        #pragma unroll
        for (int j = 0; j < 8; j++) eb[j] = ebp[(t0 + j) << 9];
        #pragma unroll
        for (int j = 0; j < 8; j++) {
            const float* kr = Kb + (t0 + j) * 9;   // wave-uniform -> scalar loads
            const float* vr = Qb + (t0 + j) * 9;   // Vs == Qs
            vf2 k0v; k0v.x = kr[0]; k0v.y = kr[1];
            vf2 k1v; k1v.x = kr[2]; k1v.y = kr[3];
            vf2 k2v; k2v.x = kr[4]; k2v.y = kr[5];
            vf2 k3v; k3v.x = kr[6]; k3v.y = kr[7];
            vf2 u2 = qv[0] * k0v + qv[1] * k1v + qv[2] * k2v + qv[3] * k3v;
            float u = u2.x + u2.y + q8 * kr[8];
            float p = exp2f(u) * eb[j];
            l += p;
            vf2 p2; p2.x = p; p2.y = p;
            vf2 v0; v0.x = vr[0]; v0.y = vr[1];
            vf2 v1; v1.x = vr[2]; v1.y = vr[3];
            vf2 v2; v2.x = vr[4]; v2.y = vr[5];
            vf2 v3; v3.x = vr[6]; v3.y = vr[7];
            acc[0] += p2 * v0; acc[1] += p2 * v1;
            acc[2] += p2 * v2; acc[3] += p2 * v3;
            a8 += p * vr[8];
        }
    }
    int gidx = bh * 512 + q;
    atomicAdd(&part[gidx], l);
    #pragma unroll
    for (int d = 0; d < 4; d++) {
        atomicAdd(&part[(1 + 2 * d) * 147456 + gidx], acc[d].x);
        atomicAdd(&part[(2 + 2 * d) * 147456 + gidx], acc[d].y);
    }
    atomicAdd(&part[9 * 147456 + gidx], a8);
}

// ---------------- matin = (1-hw)*(h1@Wo1) + hw*h2 + tx ; merge fused, st1 fused ----------------
__global__ __launch_bounds__(512) void h1o_kernel(const float* __restrict__ apart,
                           const float* __restrict__ Wo1, const float* __restrict__ h2,
                           const float* __restrict__ txall, const float* __restrict__ hwp,
                           float* __restrict__ matin, float* __restrict__ st1) {
    __shared__ float rows_[64 * 84];
    __shared__ float Wl[84 * 84];
    __shared__ float ssum[81], ssq[81];
    int row0 = blockIdx.x * 64;
    int tid = threadIdx.x;
    if (tid < 81) { ssum[tid] = 0.0f; ssq[tid] = 0.0f; }
    // stage h1 rows from the (already-merged) atomic plane set
    for (int i = tid; i < 64 * 84; i += 512) {
        int r = i / 84, c = i % 84;
        float v = 0.0f;
        if (c < 81) {
            int row = row0 + r;             // b*512+s
            int b = row >> 9, s = row & 511;
            int h = c / 9, d = c % 9;
            int gidx = (b * 9 + h) * 512 + s;
            float L = apart[gidx];
            float A = apart[(1 + d) * 147456 + gidx];
            v = A / L;
        }
        rows_[i] = v;
    }
    for (int i = tid; i < 84 * 84; i += 512) {
        int e = i / 84, c = i % 84;
        Wl[i] = (e < 81 && c < 81) ? Wo1[e * 81 + c] : 0.0f;
    }
    __syncthreads();
    float hw = hwp[0];
    float onemhw = 1.0f - hw;
    for (int o = tid; o < 336; o += 512) {
        int r4 = o / 21, cg = o % 21;
        int c0 = cg * 4;
        const float* rp = rows_ + r4 * 4 * 84;
        vf4 acc0 = 0.0f, acc1 = 0.0f, acc2 = 0.0f, acc3 = 0.0f;
        #pragma unroll 7
        for (int e = 0; e < 84; e += 4) {
            vf4 w0 = *(const vf4*)(Wl + (e + 0) * 84 + c0);
            vf4 w1 = *(const vf4*)(Wl + (e + 1) * 84 + c0);
            vf4 w2 = *(const vf4*)(Wl + (e + 2) * 84 + c0);
            vf4 w3 = *(const vf4*)(Wl + (e + 3) * 84 + c0);
            vf4 r0 = *(const vf4*)(rp + e);
            vf4 r1 = *(const vf4*)(rp + 84 + e);
            vf4 r2 = *(const vf4*)(rp + 168 + e);
            vf4 r3 = *(const vf4*)(rp + 252 + e);
            acc0 += r0[0] * w0 + r0[1] * w1 + r0[2] * w2 + r0[3] * w3;
            acc1 += r1[0] * w0 + r1[1] * w1 + r1[2] * w2 + r1[3] * w3;
            acc2 += r2[0] * w0 + r2[1] * w1 + r2[2] * w2 + r2[3] * w3;
            acc3 += r3[0] * w0 + r3[1] * w1 + r3[2] * w2 + r3[3] * w3;
        }
        vf4 av[4] = {acc0, acc1, acc2, acc3};
        #pragma unroll
        for (int cc = 0; cc < 4; cc++) {
            int col = c0 + cc;
            if (col < 81) {
                float ls = 0.0f, lq = 0.0f;
                #pragma unroll
                for (int rr = 0; rr < 4; rr++) {
                    int idx = (row0 + r4 * 4 + rr) * 81 + col;
                    float v = onemhw * av[rr][cc] + hw * h2[idx] + txall[idx];
                    matin[idx] = v;
                    ls += v; lq += v * v;
                }
                atomicAdd(&ssum[col], ls);
                atomicAdd(&ssq[col], lq);
            }
        }
    }
    __syncthreads();
    if (tid < 81) {
        atomicAdd(&st1[tid], ssum[tid]);
        atomicAdd(&st1[81 + tid], ssq[tid]);
    }
}

// ---------------- ff1: 64 rows x 64 cols/block, 4x4 tile ; fused st2 ----------------
__global__ __launch_bounds__(512) void ff1_kernel(const float* __restrict__ matin,
                           const float* __restrict__ st1, const float* __restrict__ g1,
                           const float* __restrict__ b1, const float* __restrict__ W,
                           const float* __restrict__ bias, float* __restrict__ f1,
                           float* __restrict__ st2) {
    __shared__ float rows_[64 * 84];
    __shared__ float Wl[84 * 64];       // rows 81..83 zero
    __shared__ float s2s[64], s2q[64];
    int row0 = blockIdx.x * 64;
    int cb = blockIdx.y * 64;
    int tid = threadIdx.x;
    const float invN = 1.0f / 16384.0f;
    if (tid < 64) { s2s[tid] = 0.0f; s2q[tid] = 0.0f; }
    for (int i = tid; i < 64 * 84; i += 512) {
        int c = i % 84;
        float v = 0.0f;
        if (c < 81) {
            float mean = st1[c] * invN;
            float var = st1[81 + c] * invN - mean * mean;
            v = (matin[(row0 + i / 84) * 81 + c] - mean) * rsqrtf(var + EPSV) * g1[c] + b1[c];
        }
        rows_[i] = v;
    }
    for (int i = tid; i < 84 * 64; i += 512) {
        int e = i >> 6, cc = i & 63;
        Wl[i] = (e < 81) ? W[e * 256 + cb + cc] : 0.0f;
    }
    __syncthreads();
    if (tid < 256) {
        int o = tid;                 // 256 tasks: 16 r-groups x 16 c-groups
        int r4 = o >> 4, cg = o & 15;
        int c0 = cg * 4;
        const float* rp = rows_ + r4 * 4 * 84;
        vf4 acc0 = 0.0f, acc1 = 0.0f, acc2 = 0.0f, acc3 = 0.0f;
        #pragma unroll 7
        for (int e = 0; e < 84; e += 4) {
            vf4 w0 = *(const vf4*)(Wl + ((e + 0) << 6) + c0);
            vf4 w1 = *(const vf4*)(Wl + ((e + 1) << 6) + c0);
            vf4 w2 = *(const vf4*)(Wl + ((e + 2) << 6) + c0);
            vf4 w3 = *(const vf4*)(Wl + ((e + 3) << 6) + c0);
            vf4 r0 = *(const vf4*)(rp + e);
            vf4 r1 = *(const vf4*)(rp + 84 + e);
            vf4 r2 = *(const vf4*)(rp + 168 + e);
            vf4 r3 = *(const vf4*)(rp + 252 + e);
            acc0 += r0[0] * w0 + r0[1] * w1 + r0[2] * w2 + r0[3] * w3;
            acc1 += r1[0] * w0 + r1[1] * w1 + r1[2] * w2 + r1[3] * w3;
            acc2 += r2[0] * w0 + r2[1] * w1 + r2[2] * w2 + r2[3] * w3;
            acc3 += r3[0] * w0 + r3[1] * w1 + r3[2] * w2 + r3[3] * w3;
        }
        vf4 bv = *(const vf4*)(bias + cb + c0);
        acc0 = __builtin_elementwise_max(acc0 + bv, (vf4)0.0f);
        acc1 = __builtin_elementwise_max(acc1 + bv, (vf4)0.0f);
        acc2 = __builtin_elementwise_max(acc2 + bv, (vf4)0.0f);
        acc3 = __builtin_elementwise_max(acc3 + bv, (vf4)0.0f);
        int base = (row0 + r4 * 4) * 256 + cb + c0;
        *(vf4*)(f1 + base)       = acc0;
        *(vf4*)(f1 + base + 256) = acc1;
        *(vf4*)(f1 + base + 512) = acc2;
        *(vf4*)(f1 + base + 768) = acc3;
        vf4 cs = acc0 + acc1 + acc2 + acc3;
        vf4 cq = acc0 * acc0 + acc1 * acc1 + acc2 * acc2 + acc3 * acc3;
        #pragma unroll
        for (int cc = 0; cc < 4; cc++) {
            atomicAdd(&s2s[c0 + cc], cs[cc]);
            atomicAdd(&s2q[c0 + cc], cq[cc]);
        }
    }
    __syncthreads();
    if (tid < 64) {
        atomicAdd(&st2[cb + tid], s2s[tid]);
        atomicAdd(&st2[256 + cb + tid], s2q[tid]);
    }
}

// ---------------- ff2: 32 rows/block, 512 thr, 4 K-quarter passes, padded rows (stride 68) ----------------
__global__ __launch_bounds__(512) void ff2_kernel(const float* __restrict__ f1,
                           const float* __restrict__ st2, const float* __restrict__ g2,
                           const float* __restrict__ b2, const float* __restrict__ W,
                           const float* __restrict__ bias, const float* __restrict__ matin,
                           const float* __restrict__ st1, const float* __restrict__ g1,
                           const float* __restrict__ b1, float* __restrict__ t3,
                           float* __restrict__ st3) {
    __shared__ float rows_[32 * 68];    // stride 68: r-group offset 272 %32 = 16 -> 2-way (free)
    __shared__ float Wl[64 * 84];
    __shared__ float s3s[81], s3q[81];
    int row0 = blockIdx.x * 32;
    int tid = threadIdx.x;
    const float invN = 1.0f / 16384.0f;
    if (tid < 81) { s3s[tid] = 0.0f; s3q[tid] = 0.0f; }
    int o = tid;
    int r4 = o / 21, cg = o % 21;
    int c0 = cg * 4;
    bool active = (o < 168);
    vf4 acc0 = 0.0f, acc1 = 0.0f, acc2 = 0.0f, acc3 = 0.0f;
    for (int kq = 0; kq < 4; kq++) {
        __syncthreads();
        for (int i = tid; i < 32 * 68; i += 512) {
            int r = i / 68, e = i % 68;
            float v = 0.0f;
            if (e < 64) {
                int c = kq * 64 + e;
                float mean = st2[c] * invN;
                float var = st2[256 + c] * invN - mean * mean;
                v = (f1[(row0 + r) * 256 + c] - mean) * rsqrtf(var + EPSV) * g2[c] + b2[c];
            }
            rows_[i] = v;
        }
        for (int i = tid; i < 64 * 84; i += 512) {
            int e = i / 84, c = i % 84;
            Wl[i] = (c < 81) ? W[(kq * 64 + e) * 81 + c] : 0.0f;
        }
        __syncthreads();
        if (active) {
            const float* rp = rows_ + r4 * 4 * 68;
            #pragma unroll 8
            for (int e = 0; e < 64; e += 4) {
                vf4 w0 = *(const vf4*)(Wl + (e + 0) * 84 + c0);
                vf4 w1 = *(const vf4*)(Wl + (e + 1) * 84 + c0);
                vf4 w2 = *(const vf4*)(Wl + (e + 2) * 84 + c0);
                vf4 w3 = *(const vf4*)(Wl + (e + 3) * 84 + c0);
                vf4 r0 = *(const vf4*)(rp + e);
                vf4 r1 = *(const vf4*)(rp + 68 + e);
                vf4 r2 = *(const vf4*)(rp + 136 + e);
                vf4 r3 = *(const vf4*)(rp + 204 + e);
                acc0 += r0[0] * w0 + r0[1] * w1 + r0[2] * w2 + r0[3] * w3;
                acc1 += r1[0] * w0 + r1[1] * w1 + r1[2] * w2 + r1[3] * w3;
                acc2 += r2[0] * w0 + r2[1] * w1 + r2[2] * w2 + r2[3] * w3;
                acc3 += r3[0] * w0 + r3[1] * w1 + r3[2] * w2 + r3[3] * w3;
            }
        }
    }
    if (active) {
        vf4 av[4] = {acc0, acc1, acc2, acc3};
        #pragma unroll
        for (int cc = 0; cc < 4; cc++) {
            int col = c0 + cc;
            if (col < 81) {
                float mean = st1[col] * invN;
                float var = st1[81 + col] * invN - mean * mean;
                float rstd = rsqrtf(var + EPSV);
                float bval = bias[col];
                float ls = 0.0f, lq = 0.0f;
                #pragma unroll
                for (int rr = 0; rr < 4; rr++) {
                    int idx = (row0 + r4 * 4 + rr) * 81 + col;
                    float ma = (matin[idx] - mean) * rstd * g1[col] + b1[col];
                    float v = ma + fmaxf(av[rr][cc] + bval, 0.0f);
                    t3[idx] = v;
                    ls += v; lq += v * v;
                }
                atomicAdd(&s3s[col], ls);
                atomicAdd(&s3q[col], lq);
            }
        }
    }
    __syncthreads();
    if (tid < 81) {
        atomicAdd(&st3[tid], s3s[tid]);
        atomicAdd(&st3[81 + tid], s3q[tid]);
    }
}

// ---------------- token_mm: u/v dual GEMM (64 rows/block, W-pass split, 4x4 tile) ----------------
__global__ __launch_bounds__(512) void token_mm(const float* __restrict__ t3,
                            const float* __restrict__ st3, const float* __restrict__ g3,
                            const float* __restrict__ b3, const float* __restrict__ tvw,
                            const float* __restrict__ beta1,
                            float* __restrict__ uv0, float* __restrict__ uv1) {
    __shared__ float rows_[64 * 84];
    __shared__ float Wl[84 * 84];
    int blk = blockIdx.x;            // 0..511
    int t = blk >> 8;
    int row0 = (blk & 255) * 64;
    const float* W = (t == 0) ? tvw : beta1;
    float* dst = (t == 0) ? uv0 : uv1;
    int tid = threadIdx.x;
    const float invN = 1.0f / 16384.0f;
    for (int i = tid; i < 64 * 84; i += 512) {
        int c = i % 84;
        float v = 0.0f;
        if (c < 81) {
            float mean = st3[c] * invN;
            float var = st3[81 + c] * invN - mean * mean;
            v = (t3[(row0 + i / 84) * 81 + c] - mean) * rsqrtf(var + EPSV) * g3[c] + b3[c];
        }
        rows_[i] = v;
    }
    for (int i = tid; i < 84 * 84; i += 512) {
        int e = i / 84, c = i % 84;
        Wl[i] = (e < 81 && c < 81) ? W[e * 81 + c] : 0.0f;
    }
    __syncthreads();
    for (int o = tid; o < 336; o += 512) {
        int r4 = o / 21, cg = o % 21;
        int c0 = cg * 4;
        const float* rp = rows_ + r4 * 4 * 84;
        vf4 acc0 = 0.0f, acc1 = 0.0f, acc2 = 0.0f, acc3 = 0.0f;
        #pragma unroll 7
        for (int e = 0; e < 84; e += 4) {
            vf4 w0 = *(const vf4*)(Wl + (e + 0) * 84 + c0);
            vf4 w1 = *(const vf4*)(Wl + (e + 1) * 84 + c0);
            vf4 w2 = *(const vf4*)(Wl + (e + 2) * 84 + c0);
            vf4 w3 = *(const vf4*)(Wl + (e + 3) * 84 + c0);
            vf4 r0 = *(const vf4*)(rp + e);
            vf4 r1 = *(const vf4*)(rp + 84 + e);
            vf4 r2 = *(const vf4*)(rp + 168 + e);
            vf4 r3 = *(const vf4*)(rp + 252 + e);
            acc0 += r0[0] * w0 + r0[1] * w1 + r0[2] * w2 + r0[3] * w3;
            acc1 += r1[0] * w0 + r1[1] * w1 + r1[2] * w2 + r1[3] * w3;
            acc2 += r2[0] * w0 + r2[1] * w1 + r2[2] * w2 + r2[3] * w3;
            acc3 += r3[0] * w0 + r3[1] * w1 + r3[2] * w2 + r3[3] * w3;
        }
        vf4 av[4] = {acc0, acc1, acc2, acc3};
        #pragma unroll
        for (int cc = 0; cc < 4; cc++) {
            int col = c0 + cc;
            if (col < 81) {
                #pragma unroll
                for (int rr = 0; rr < 4; rr++)
                    dst[(row0 + r4 * 4 + rr) * 81 + col] = av[rr][cc];
            }
        }
    }
}

// ---------------- token_pool: softmax-pool over 81, 32 rows/block, 8 lanes/row ----------------
__global__ __launch_bounds__(256) void token_pool(const float* __restrict__ uv0,
                             const float* __restrict__ uv1, const float* __restrict__ tvb,
                             const float* __restrict__ basel, const float* __restrict__ a1p,
                             const float* __restrict__ a2p, float* __restrict__ fea) {
    int tid = threadIdx.x;
    int r = tid >> 3, j = tid & 7;
    int row = blockIdx.x * 32 + r;
    int base = row * 81;
    float u[11], v[11];
    #pragma unroll
    for (int dd = 0; dd < 11; dd++) {
        int d = j + dd * 8;
        if (d < 81) {
            u[dd] = uv0[base + d] + tvb[d];
            v[dd] = uv1[base + d];
        } else {
            u[dd] = 0.0f; v[dd] = -1e30f;
        }
    }
    float mx = -1e30f;
    #pragma unroll
    for (int dd = 0; dd < 11; dd++) mx = fmaxf(mx, v[dd]);
    #pragma unroll
    for (int msk = 1; msk < 8; msk <<= 1) mx = fmaxf(mx, __shfl_xor(mx, msk, 8));
    float sp = 0.0f, sup = 0.0f;
    #pragma unroll
    for (int dd = 0; dd < 11; dd++) {
        float p = __expf(v[dd] - mx);
        sp += p; sup += u[dd] * p;
    }
    #pragma unroll
    for (int msk = 1; msk < 8; msk <<= 1) {
        sp  += __shfl_xor(sp, msk, 8);
        sup += __shfl_xor(sup, msk, 8);
    }
    if (j == 0) {
        int b = row >> 9, s = row & 511;
        fea[row] = a1p[0] * (sup / sp) + a2p[0] * basel[b * 2048 + s * 4];
    }
}

// ---------------- fc1: relu(fea @ W + b), fused st4 ----------------
__global__ void fc1_kernel(const float* __restrict__ in, const float* __restrict__ W,
                           const float* __restrict__ bias, float* __restrict__ out,
                           float* __restrict__ st) {
    int idx = blockIdx.x * blockDim.x + threadIdx.x;
    if (idx >= 32 * 512) return;
    int b = idx >> 9, j = idx & 511;
    float acc = bias[j];
    const float* ip = in + (b << 9);
    #pragma unroll 8
    for (int k = 0; k < 512; k++) acc += ip[k] * W[k * 512 + j];
    acc = fmaxf(acc, 0.0f);
    out[idx] = acc;
    atomicAdd(&st[j], acc);
    atomicAdd(&st[512 + j], acc * acc);
}

// ---------------- fc2: relu(bn(fch1) @ W + b), fused st5 ----------------
__global__ __launch_bounds__(256) void fc2_kernel(const float* __restrict__ in,
                           const float* __restrict__ st4, const float* __restrict__ g,
                           const float* __restrict__ bb, const float* __restrict__ W,
                           const float* __restrict__ bias, float* __restrict__ out,
                           float* __restrict__ st5) {
    __shared__ float scale[512], shift[512];
    int tid = threadIdx.x;
    for (int k = tid; k < 512; k += 256) {
        float mean = st4[k] * (1.0f / 32.0f);
        float var = st4[512 + k] * (1.0f / 32.0f) - mean * mean;
        float sc_ = rsqrtf(var + EPSV) * g[k];
        scale[k] = sc_;
        shift[k] = bb[k] - mean * sc_;
    }
    __syncthreads();
    int idx = blockIdx.x * 256 + tid;
    if (idx >= 32 * 256) return;
    int b = idx >> 8, j = idx & 255;
    float acc = bias[j];
    const float* ip = in + (b << 9);
    #pragma unroll 8
    for (int k = 0; k < 512; k++) acc += (ip[k] * scale[k] + shift[k]) * W[k * 256 + j];
    acc = fmaxf(acc, 0.0f);
    out[idx] = acc;
    atomicAdd(&st5[j], acc);
    atomicAdd(&st5[256 + j], acc * acc);
}

// ---------------- fc3: tanh(bn(fch2) @ W + b) ----------------
__global__ void fc3_kernel(const float* __restrict__ in, const float* __restrict__ st5,
                           const float* __restrict__ g, const float* __restrict__ bb,
                           const float* __restrict__ W, const float* __restrict__ bias,
                           float* __restrict__ out) {
    __shared__ float scale[256], shift[256];
    int tid = threadIdx.x;   // 128
    for (int k = tid; k < 256; k += 128) {
        float mean = st5[k] * (1.0f / 32.0f);
        float var = st5[256 + k] * (1.0f / 32.0f) - mean * mean;
        float sc_ = rsqrtf(var + EPSV) * g[k];
        scale[k] = sc_;
        shift[k] = bb[k] - mean * sc_;
    }
    __syncthreads();
    int b = tid >> 2, j = tid & 3;
    float acc = bias[j];
    const float* ip = in + (b << 8);
    #pragma unroll 8
    for (int k = 0; k < 256; k++) acc += (ip[k] * scale[k] + shift[k]) * W[k * 4 + j];
    out[tid] = tanhf(acc);
}

// =======================================================================
extern "C" void kernel_launch(void* const* d_in, const int* in_sizes, int n_in,
                              void* d_out, int out_size, void* d_ws, size_t ws_size,
                              hipStream_t stream) {
    const float* x       = (const float*)d_in[0];
    const float* basel   = (const float*)d_in[1];
    const float* cali    = (const float*)d_in[2];
    const float* Wq      = (const float*)d_in[3];
    const float* Wk      = (const float*)d_in[4];
    const float* Wq2     = (const float*)d_in[5];
    const float* Wk2     = (const float*)d_in[6];
    const float* Wv2     = (const float*)d_in[7];
    const float* Cv      = (const float*)d_in[8];
    const float* Wo1     = (const float*)d_in[9];
    const float* Wo2     = (const float*)d_in[10];
    const float* corr_w  = (const float*)d_in[11];
    const float* h_w     = (const float*)d_in[12];
    const float* corr    = (const float*)d_in[13];
    const float* g1      = (const float*)d_in[14];
    const float* b1      = (const float*)d_in[15];
    const float* ff1_w   = (const float*)d_in[16];
    const float* ff1_b   = (const float*)d_in[17];
    const float* g2      = (const float*)d_in[18];
    const float* b2      = (const float*)d_in[19];
    const float* ff2_w   = (const float*)d_in[20];
    const float* ff2_b   = (const float*)d_in[21];
    const float* g3      = (const float*)d_in[22];
    const float* b3      = (const float*)d_in[23];
    const float* tvw     = (const float*)d_in[24];
    const float* tvb     = (const float*)d_in[25];
    const float* beta1   = (const float*)d_in[26];
    const float* a1      = (const float*)d_in[27];
    const float* a2      = (const float*)d_in[28];
    const float* fc1_w   = (const float*)d_in[29];
    const float* fc1_b   = (const float*)d_in[30];
    const float* bnf1_g  = (const float*)d_in[31];
    const float* bnf1_b  = (const float*)d_in[32];
    const float* fc2_w   = (const float*)d_in[33];
    const float* fc2_b   = (const float*)d_in[34];
    const float* bnf2_g  = (const float*)d_in[35];
    const float* bnf2_b  = (const float*)d_in[36];
    const float* fc3_w   = (const float*)d_in[37];
    const float* fc3_b   = (const float*)d_in[38];
    float* out = (float*)d_out;
    float* ws = (float*)d_ws;

    // ---- workspace layout (float offsets) ----
    const size_t SCAL  = 0;         // 2
    const size_t PART  = 16;        // 128
    const size_t ST1   = 512;       // 162
    const size_t ST2   = 768;       // 512
    const size_t ST3   = 1536;      // 162
    const size_t ST4   = 1792;      // 1024
    const size_t ST5   = 2880;      // 512
    const size_t FEA   = 4096;      // 16384
    const size_t FCH1  = 20480;     // 16384
    const size_t FCH2  = 36864;     // 8192
    const size_t PEO   = 45056;     // 41472
    const size_t TX    = 90112;     // 1990656
    const size_t Q2O   = 2080768;   // 1327104
    const size_t KCO   = 3407872;   // 1990656   (reused: Qs)
    const size_t VCO   = 5398528;   // 1990656   (reused: Ks)
    const size_t TMP2  = 7389184;   // 1327104   (reused: matin, then uv0)
    const size_t H2O   = 8716288;   // 1327104   (reused: t3)
    const size_t XHO   = 10043392;  // 1327104   (xh, dead after qks -> uv1)
    const size_t BIASO = 11370496;  // 262144    (EBT)
    const size_t F1O   = 11632640;  // 4194304   (f1; also attn1 planes 1474560)

    float* scal  = ws + SCAL;
    float* part  = ws + PART;
    float* st1   = ws + ST1;
    float* st2   = ws + ST2;
    float* st3   = ws + ST3;
    float* st4   = ws + ST4;
    float* st5   = ws + ST5;
    float* fea   = ws + FEA;
    float* fch1  = ws + FCH1;
    float* fch2  = ws + FCH2;
    float* pe    = ws + PEO;
    float* txall = ws + TX;
    float* Q2    = ws + Q2O;
    float* Kc    = ws + KCO;
    float* Vc    = ws + VCO;
    float* tmp2  = ws + TMP2;
    float* h2    = ws + H2O;
    float* xh    = ws + XHO;
    float* ebT   = ws + BIASO;
    float* f1    = ws + F1O;
    float* Qs    = Kc;     // reuse
    float* Ks    = Vc;     // reuse
    float* matin = tmp2;   // reuse (dead after ff2 -> uv0)
    float* t3    = h2;     // reuse
    float* apart = f1;     // attn1 atomic planes (10 x 147456 floats) in f1 region
    float* uv0   = tmp2;   // token u plane (matin dead after ff2)
    float* uv1   = xh;     // token v plane (xh dead after qks)

    // zero scal/part/stats region — capture-safe
    hipMemsetAsync(ws, 0, 4096 * sizeof(float), stream);
    // zero attn1 atomic planes (5.9 MB)
    hipMemsetAsync(apart, 0, 1474560 * sizeof(float), stream);

    minmax_part<<<64, 256, 0, stream>>>(x, part);
    minmax_fin<<<1, 64, 0, stream>>>(part, scal);

    pe_kernel<<<(512 * 81 + 255) / 256, 256, 0, stream>>>(pe);

    tokenize_kernel<<<(48 * 512 * 81 + 255) / 256, 256, 0, stream>>>(x, cali, scal, pe, txall);

    qkv2_kernel<<<1024, 512, 0, stream>>>(txall, Wq2, Wk2, Wv2, Q2, Kc, Vc);

    attn2_kernel<<<(512 * 9 * 32) / 256, 256, 0, stream>>>(Q2, Kc, Vc, tmp2);

    h2xh_kernel<<<256, 512, 0, stream>>>(tmp2, Wo2, txall, h2, xh);

    qks_kernel<<<512, 512, 0, stream>>>(xh, Wq, Wk, Qs, Ks);

    biasmm_kernel<<<dim3(16, 16), dim3(16, 16), 0, stream>>>(corr, Cv, corr_w, ebT);

    attn1_kernel<<<4608, 256, 0, stream>>>(Qs, Ks, ebT, corr_w, apart);

    h1o_kernel<<<256, 512, 0, stream>>>(apart, Wo1, h2, txall, h_w, matin, st1);

    ff1_kernel<<<dim3(256, 4), 512, 0, stream>>>(matin, st1, g1, b1, ff1_w, ff1_b, f1, st2);

    ff2_kernel<<<512, 512, 0, stream>>>(f1, st2, g2, b2, ff2_w, ff2_b,
                                        matin, st1, g1, b1, t3, st3);

    token_mm<<<512, 512, 0, stream>>>(t3, st3, g3, b3, tvw, beta1, uv0, uv1);
    token_pool<<<512, 256, 0, stream>>>(uv0, uv1, tvb, basel, a1, a2, fea);

    fc1_kernel<<<64, 256, 0, stream>>>(fea, fc1_w, fc1_b, fch1, st4);

    fc2_kernel<<<32, 256, 0, stream>>>(fch1, st4, bnf1_g, bnf1_b, fc2_w, fc2_b, fch2, st5);

    fc3_kernel<<<1, 128, 0, stream>>>(fch2, st5, bnf2_g, bnf2_b, fc3_w, fc3_b, out);
}

// Round 21
// 403.186 us; speedup vs baseline: 1.4127x; 1.0007x over previous
//
#include <hip/hip_runtime.h>
#include <hip/hip_bf16.h>
#include <math.h>

#define EPSV 1e-5f

typedef float vf2 __attribute__((ext_vector_type(2)));
typedef float vf4 __attribute__((ext_vector_type(4)));

// ---------------- sizes ----------------
// B=32 Bc=16 L=2048 TOKEN=40 STRIDE=4 D=81 H=9 dk=9 S=512 FF=256 FC1=512 FC2=256 Y=4

// ---------------- minmax: two-stage ----------------
__global__ void minmax_part(const float* __restrict__ x, float* __restrict__ part) {
    __shared__ float smin[256], smax[256];
    int tid = threadIdx.x;
    float mn = 1e30f, mx = -1e30f;
    for (int i = blockIdx.x * 256 + tid; i < 32 * 2008; i += 64 * 256) {
        int b = i / 2008, c = i % 2008 + 20;
        float v = x[b * 2048 + c];
        mn = fminf(mn, v); mx = fmaxf(mx, v);
    }
    smin[tid] = mn; smax[tid] = mx; __syncthreads();
    for (int off = 128; off > 0; off >>= 1) {
        if (tid < off) { smin[tid] = fminf(smin[tid], smin[tid + off]); smax[tid] = fmaxf(smax[tid], smax[tid + off]); }
        __syncthreads();
    }
    if (tid == 0) { part[blockIdx.x] = smin[0]; part[64 + blockIdx.x] = smax[0]; }
}

__global__ void minmax_fin(const float* __restrict__ part, float* __restrict__ scal) {
    __shared__ float smn[64], smx[64];
    int tid = threadIdx.x;
    smn[tid] = part[tid]; smx[tid] = part[64 + tid]; __syncthreads();
    for (int off = 32; off > 0; off >>= 1) {
        if (tid < off) { smn[tid] = fminf(smn[tid], smn[tid + off]); smx[tid] = fmaxf(smx[tid], smx[tid + off]); }
        __syncthreads();
    }
    if (tid == 0) { scal[0] = smn[0]; scal[1] = smx[0] - smn[0]; }
}

// ---------------- PE table (512 x 81) ----------------
__global__ void pe_kernel(float* __restrict__ pe) {
    int idx = blockIdx.x * blockDim.x + threadIdx.x;
    if (idx >= 512 * 81) return;
    int d = idx % 81, s = idx / 81;
    int j = d >> 1;
    float dv = __expf(-9.210340371976184f * (2.0f * (float)j) / 81.0f);
    float ang = (float)s * dv;
    pe[idx] = (d & 1) ? cosf(ang) : sinf(ang);
}

// ---------------- tokenize + add PE ----------------
__global__ void tokenize_kernel(const float* __restrict__ x, const float* __restrict__ cali,
                                const float* __restrict__ scal, const float* __restrict__ pe,
                                float* __restrict__ txall) {
    int idx = blockIdx.x * blockDim.x + threadIdx.x;
    if (idx >= 48 * 512 * 81) return;
    int d = idx % 81;
    int s = (idx / 81) % 512;
    int r = idx / (81 * 512);
    float xm = scal[0], inv_xs = 1.0f / scal[1];
    int oc = s * 4 + d - 40;
    float val = 0.0f;
    if (oc >= 0 && oc < 2048) {
        float sv = (r < 32) ? x[r * 2048 + oc] : cali[(r - 32) * 2048 + oc];
        val = (sv - xm) * inv_xs;
    }
    txall[idx] = val + pe[s * 81 + d];
}

// ======== 4x4-tile 81->81 GEMM pieces (rows stride 84, W [e][col] stride 84) ========
// 512 threads/block: staging strides 512, compute single pass (336 tasks of 512 threads)

// ---------------- qkv2: 64 rows/block, W-pass split (1024 blocks), 4x4 tile ----------------
__global__ __launch_bounds__(512) void qkv2_kernel(const float* __restrict__ txall,
                            const float* __restrict__ Wq2, const float* __restrict__ Wk2,
                            const float* __restrict__ Wv2,
                            float* __restrict__ Q2, float* __restrict__ Kc, float* __restrict__ Vc) {
    __shared__ float rows_[64 * 84];
    __shared__ float Wl[84 * 84];
    int blk = blockIdx.x;            // 0..1023
    int t, rb;
    if (blk < 256)      { t = 0; rb = blk; }
    else if (blk < 640) { t = 1; rb = blk - 256; }
    else                { t = 2; rb = blk - 640; }
    int row0 = rb * 64;
    int k = row0 >> 9;
    int s0 = row0 & 511;
    const float* W = (t == 0) ? Wq2 : (t == 1) ? Wk2 : Wv2;
    int tid = threadIdx.x;
    for (int i = tid; i < 64 * 84; i += 512) {
        int c = i % 84;
        rows_[i] = (c < 81) ? txall[(row0 + i / 84) * 81 + c] : 0.0f;
    }
    for (int i = tid; i < 84 * 84; i += 512) {
        int e = i / 84, hd = i % 84;
        Wl[i] = (e < 81 && hd < 81) ? W[(hd / 9) * 729 + e * 9 + (hd % 9)] : 0.0f;
    }
    __syncthreads();
    for (int o = tid; o < 336; o += 512) {
        int r4 = o / 21, cg = o % 21;
        int c0 = cg * 4;
        const float* rp = rows_ + r4 * 4 * 84;
        vf4 acc0 = 0.0f, acc1 = 0.0f, acc2 = 0.0f, acc3 = 0.0f;
        #pragma unroll 7
        for (int e = 0; e < 84; e += 4) {
            vf4 w0 = *(const vf4*)(Wl + (e + 0) * 84 + c0);
            vf4 w1 = *(const vf4*)(Wl + (e + 1) * 84 + c0);
            vf4 w2 = *(const vf4*)(Wl + (e + 2) * 84 + c0);
            vf4 w3 = *(const vf4*)(Wl + (e + 3) * 84 + c0);
            vf4 r0 = *(const vf4*)(rp + e);
            vf4 r1 = *(const vf4*)(rp + 84 + e);
            vf4 r2 = *(const vf4*)(rp + 168 + e);
            vf4 r3 = *(const vf4*)(rp + 252 + e);
            acc0 += r0[0] * w0 + r0[1] * w1 + r0[2] * w2 + r0[3] * w3;
            acc1 += r1[0] * w0 + r1[1] * w1 + r1[2] * w2 + r1[3] * w3;
            acc2 += r2[0] * w0 + r2[1] * w1 + r2[2] * w2 + r2[3] * w3;
            acc3 += r3[0] * w0 + r3[1] * w1 + r3[2] * w2 + r3[3] * w3;
        }
        vf4 av[4] = {acc0, acc1, acc2, acc3};
        #pragma unroll
        for (int cc = 0; cc < 4; cc++) {
            int col = c0 + cc;
            if (col < 81) {
                int h = col / 9, d = col % 9;
                #pragma unroll
                for (int rr = 0; rr < 4; rr++) {
                    int s = s0 + r4 * 4 + rr;
                    if (t == 0)      Q2[((s * 9 + h) * 32 + k) * 9 + d] = av[rr][cc];
                    else if (t == 1) Kc[((s * 9 + h) * 48 + k) * 9 + d] = av[rr][cc];
                    else             Vc[((s * 9 + h) * 48 + k) * 9 + d] = av[rr][cc];
                }
            }
        }
    }
}

// ---------------- attention-2 (masked: key==b or key>=32), no-max softmax (exp2) ----------------
__global__ void attn2_kernel(const float* __restrict__ Q2, const float* __restrict__ Kc,
                             const float* __restrict__ Vc, float* __restrict__ tmp2) {
    int tid = blockIdx.x * blockDim.x + threadIdx.x;
    if (tid >= 512 * 9 * 32) return;
    int b = tid & 31;
    int h = (tid >> 5) % 9;
    int s = tid / 288;
    const float* q = Q2 + ((s * 9 + h) * 32 + b) * 9;
    float qr[9];
    const float c2 = 1.4426950408889634f / 3.0f;   // log2e / 3
    #pragma unroll
    for (int d = 0; d < 9; d++) qr[d] = q[d] * c2;
    const float* Kb = Kc + (s * 9 + h) * 48 * 9;
    const float* Vb = Vc + (s * 9 + h) * 48 * 9;
    float l = 0.0f, outv[9];
    #pragma unroll
    for (int d = 0; d < 9; d++) outv[d] = 0.0f;
    #pragma unroll
    for (int j = 0; j < 17; j++) {
        int k = (j == 0) ? b : 31 + j;
        const float* kp = Kb + k * 9;
        float acc = 0.0f;
        #pragma unroll
        for (int d = 0; d < 9; d++) acc += qr[d] * kp[d];
        float p = exp2f(acc);
        l += p;
        const float* vp = Vb + k * 9;
        #pragma unroll
        for (int d = 0; d < 9; d++) outv[d] += p * vp[d];
    }
    float invl = 1.0f / l;
    float* op = tmp2 + (b * 512 + s) * 81 + h * 9;
    #pragma unroll
    for (int d = 0; d < 9; d++) op[d] = outv[d] * invl;
}

// ---------------- h2 = tmp2 @ Wo2 ; xh = tx + h2  (64 rows/block, 4x4 tile) ----------------
__global__ __launch_bounds__(512) void h2xh_kernel(const float* __restrict__ tmp2,
                            const float* __restrict__ Wo2, const float* __restrict__ txall,
                            float* __restrict__ h2, float* __restrict__ xh) {
    __shared__ float rows_[64 * 84];
    __shared__ float Wl[84 * 84];
    int row0 = blockIdx.x * 64;
    int tid = threadIdx.x;
    for (int i = tid; i < 64 * 84; i += 512) {
        int c = i % 84;
        rows_[i] = (c < 81) ? tmp2[(row0 + i / 84) * 81 + c] : 0.0f;
    }
    for (int i = tid; i < 84 * 84; i += 512) {
        int e = i / 84, c = i % 84;
        Wl[i] = (e < 81 && c < 81) ? Wo2[e * 81 + c] : 0.0f;
    }
    __syncthreads();
    for (int o = tid; o < 336; o += 512) {
        int r4 = o / 21, cg = o % 21;
        int c0 = cg * 4;
        const float* rp = rows_ + r4 * 4 * 84;
        vf4 acc0 = 0.0f, acc1 = 0.0f, acc2 = 0.0f, acc3 = 0.0f;
        #pragma unroll 7
        for (int e = 0; e < 84; e += 4) {
            vf4 w0 = *(const vf4*)(Wl + (e + 0) * 84 + c0);
            vf4 w1 = *(const vf4*)(Wl + (e + 1) * 84 + c0);
            vf4 w2 = *(const vf4*)(Wl + (e + 2) * 84 + c0);
            vf4 w3 = *(const vf4*)(Wl + (e + 3) * 84 + c0);
            vf4 r0 = *(const vf4*)(rp + e);
            vf4 r1 = *(const vf4*)(rp + 84 + e);
            vf4 r2 = *(const vf4*)(rp + 168 + e);
            vf4 r3 = *(const vf4*)(rp + 252 + e);
            acc0 += r0[0] * w0 + r0[1] * w1 + r0[2] * w2 + r0[3] * w3;
            acc1 += r1[0] * w0 + r1[1] * w1 + r1[2] * w2 + r1[3] * w3;
            acc2 += r2[0] * w0 + r2[1] * w1 + r2[2] * w2 + r2[3] * w3;
            acc3 += r3[0] * w0 + r3[1] * w1 + r3[2] * w2 + r3[3] * w3;
        }
        vf4 av[4] = {acc0, acc1, acc2, acc3};
        #pragma unroll
        for (int cc = 0; cc < 4; cc++) {
            int col = c0 + cc;
            if (col < 81) {
                #pragma unroll
                for (int rr = 0; rr < 4; rr++) {
                    int idx = (row0 + r4 * 4 + rr) * 81 + col;
                    float v = av[rr][cc];
                    h2[idx] = v;
                    xh[idx] = txall[idx] + v;
                }
            }
        }
    }
}

// ---------------- Qs/Ks (Vs == Qs): 64 rows/block, W-pass split (512 blocks), 4x4 ----------------
__global__ __launch_bounds__(512) void qks_kernel(const float* __restrict__ xh,
                           const float* __restrict__ Wq, const float* __restrict__ Wk,
                           float* __restrict__ Qs, float* __restrict__ Ks) {
    __shared__ float rows_[64 * 84];
    __shared__ float Wl[84 * 84];
    int blk = blockIdx.x;            // 0..511
    int t = blk >> 8;                // 0: Q, 1: K
    int rb = blk & 255;
    int row0 = rb * 64;
    int b = row0 >> 9;
    int s0 = row0 & 511;
    const float* W = (t == 0) ? Wq : Wk;
    int tid = threadIdx.x;
    for (int i = tid; i < 64 * 84; i += 512) {
        int c = i % 84;
        rows_[i] = (c < 81) ? xh[(row0 + i / 84) * 81 + c] : 0.0f;
    }
    for (int i = tid; i < 84 * 84; i += 512) {
        int e = i / 84, hd = i % 84;
        Wl[i] = (e < 81 && hd < 81) ? W[(hd / 9) * 729 + e * 9 + (hd % 9)] : 0.0f;
    }
    __syncthreads();
    float* dst = (t == 0) ? Qs : Ks;
    for (int o = tid; o < 336; o += 512) {
        int r4 = o / 21, cg = o % 21;
        int c0 = cg * 4;
        const float* rp = rows_ + r4 * 4 * 84;
        vf4 acc0 = 0.0f, acc1 = 0.0f, acc2 = 0.0f, acc3 = 0.0f;
        #pragma unroll 7
        for (int e = 0; e < 84; e += 4) {
            vf4 w0 = *(const vf4*)(Wl + (e + 0) * 84 + c0);
            vf4 w1 = *(const vf4*)(Wl + (e + 1) * 84 + c0);
            vf4 w2 = *(const vf4*)(Wl + (e + 2) * 84 + c0);
            vf4 w3 = *(const vf4*)(Wl + (e + 3) * 84 + c0);
            vf4 r0 = *(const vf4*)(rp + e);
            vf4 r1 = *(const vf4*)(rp + 84 + e);
            vf4 r2 = *(const vf4*)(rp + 168 + e);
            vf4 r3 = *(const vf4*)(rp + 252 + e);
            acc0 += r0[0] * w0 + r0[1] * w1 + r0[2] * w2 + r0[3] * w3;
            acc1 += r1[0] * w0 + r1[1] * w1 + r1[2] * w2 + r1[3] * w3;
            acc2 += r2[0] * w0 + r2[1] * w1 + r2[2] * w2 + r2[3] * w3;
            acc3 += r3[0] * w0 + r3[1] * w1 + r3[2] * w2 + r3[3] * w3;
        }
        vf4 av[4] = {acc0, acc1, acc2, acc3};
        #pragma unroll
        for (int cc = 0; cc < 4; cc++) {
            int col = c0 + cc;
            if (col < 81) {
                int h = col / 9, d = col % 9;
                #pragma unroll
                for (int rr = 0; rr < 4; rr++)
                    dst[((b * 9 + h) * 512 + (s0 + r4 * 4 + rr)) * 9 + d] = av[rr][cc];
            }
        }
    }
}

// ---------------- EBT[t*512+s] = exp(cw * (corr @ Cv)^T[t][s] / sqrt(S)) ----------------
__global__ __launch_bounds__(256) void biasmm_kernel(const float* __restrict__ corr,
                              const float* __restrict__ Cv, const float* __restrict__ cwp,
                              float* __restrict__ ebT) {
    __shared__ float As[32][33];
    __shared__ float Bs[32][33];
    int tx = threadIdx.x, ty = threadIdx.y;   // 16 x 16
    int tid = ty * 16 + tx;
    int t0 = blockIdx.y * 32, s0 = blockIdx.x * 32;
    float a00 = 0, a01 = 0, a10 = 0, a11 = 0;
    for (int k0 = 0; k0 < 512; k0 += 32) {
        for (int ii = tid; ii < 1024; ii += 256) {
            int r = ii >> 5, c = ii & 31;
            As[r][c] = Cv[(k0 + r) * 512 + t0 + c];
            Bs[r][c] = corr[(s0 + r) * 512 + k0 + c];
        }
        __syncthreads();
        #pragma unroll
        for (int kk = 0; kk < 32; kk++) {
            float b0 = Bs[tx][kk], b1 = Bs[tx + 16][kk];
            float c0 = As[kk][ty], c1 = As[kk][ty + 16];
            a00 += c0 * b0; a01 += c0 * b1; a10 += c1 * b0; a11 += c1 * b1;
        }
        __syncthreads();
    }
    float cws = cwp[0] * 0.04419417382415922f;   // cw / sqrt(512)
    ebT[(t0 + ty) * 512 + s0 + tx]            = __expf(a00 * cws);
    ebT[(t0 + ty) * 512 + s0 + tx + 16]       = __expf(a01 * cws);
    ebT[(t0 + ty + 16) * 512 + s0 + tx]       = __expf(a10 * cws);
    ebT[(t0 + ty + 16) * 512 + s0 + tx + 16]  = __expf(a11 * cws);
}

// ---------------- attention-1: no-max softmax (exp2), 8-way key split, atomic merge ----------------
// p = exp2(c1*log2e * q.k) * EB[key][q]
// grid 4608: bh = blk>>4, qhalf = (blk>>3)&1, kq8 = blk&7 -- ALL block-uniform (scalar K/V loads)
// each thread: 1 query x 64 keys; partials accumulated into ONE plane set via atomicAdd
// planes: part[e*147456 + (bh*512+q)], e in [0,10)  (zeroed by memset before launch)
__global__ __launch_bounds__(256) void attn1_kernel(const float* __restrict__ Qs,
                                                    const float* __restrict__ Ks,
                                                    const float* __restrict__ ebT,
                                                    const float* __restrict__ cwp,
                                                    float* __restrict__ part) {
    int blk = blockIdx.x;          // 0..4607
    int bh = blk >> 4;             // b*9+h
    int qhalf = (blk >> 3) & 1;
    int kq8 = blk & 7;
    int tid = threadIdx.x;
    const float* Kb = Ks + bh * 4608;
    const float* Qb = Qs + bh * 4608;
    int q = qhalf * 256 + tid;
    float c1 = (1.0f - cwp[0]) * (1.4426950408889634f / 3.0f);   // fold log2e
    vf2 qv[4];
    float q8;
    {
        const float* qp = Qb + q * 9;
        #pragma unroll
        for (int d = 0; d < 4; d++) {
            vf2 t; t.x = c1 * qp[2 * d]; t.y = c1 * qp[2 * d + 1];
            qv[d] = t;
        }
        q8 = c1 * qp[8];
    }
    float l = 0.0f, a8 = 0.0f;
    vf2 acc[4];
    #pragma unroll
    for (int d = 0; d < 4; d++) acc[d] = (vf2)0.0f;
    int k0 = kq8 * 64;             // block-uniform -> K/V scalar loads preserved
    const float* ebp = ebT + q;
    for (int t0 = k0; t0 < k0 + 64; t0 += 8) {
        float eb[8];
        #pragma unroll
        for (int j = 0; j < 8; j++) eb[j] = ebp[(t0 + j) << 9];
        #pragma unroll
        for (int j = 0; j < 8; j++) {
            const float* kr = Kb + (t0 + j) * 9;   // wave-uniform -> scalar loads
            const float* vr = Qb + (t0 + j) * 9;   // Vs == Qs
            vf2 k0v; k0v.x = kr[0]; k0v.y = kr[1];
            vf2 k1v; k1v.x = kr[2]; k1v.y = kr[3];
            vf2 k2v; k2v.x = kr[4]; k2v.y = kr[5];
            vf2 k3v; k3v.x = kr[6]; k3v.y = kr[7];
            vf2 u2 = qv[0] * k0v + qv[1] * k1v + qv[2] * k2v + qv[3] * k3v;
            float u = u2.x + u2.y + q8 * kr[8];
            float p = exp2f(u) * eb[j];
            l += p;
            vf2 p2; p2.x = p; p2.y = p;
            vf2 v0; v0.x = vr[0]; v0.y = vr[1];
            vf2 v1; v1.x = vr[2]; v1.y = vr[3];
            vf2 v2; v2.x = vr[4]; v2.y = vr[5];
            vf2 v3; v3.x = vr[6]; v3.y = vr[7];
            acc[0] += p2 * v0; acc[1] += p2 * v1;
            acc[2] += p2 * v2; acc[3] += p2 * v3;
            a8 += p * vr[8];
        }
    }
    int gidx = bh * 512 + q;
    atomicAdd(&part[gidx], l);
    #pragma unroll
    for (int d = 0; d < 4; d++) {
        atomicAdd(&part[(1 + 2 * d) * 147456 + gidx], acc[d].x);
        atomicAdd(&part[(2 + 2 * d) * 147456 + gidx], acc[d].y);
    }
    atomicAdd(&part[9 * 147456 + gidx], a8);
}

// ---------------- matin = (1-hw)*(h1@Wo1) + hw*h2 + tx ; merge fused, st1 fused ----------------
__global__ __launch_bounds__(512) void h1o_kernel(const float* __restrict__ apart,
                           const float* __restrict__ Wo1, const float* __restrict__ h2,
                           const float* __restrict__ txall, const float* __restrict__ hwp,
                           float* __restrict__ matin, float* __restrict__ st1) {
    __shared__ float rows_[64 * 84];
    __shared__ float Wl[84 * 84];
    __shared__ float ssum[81], ssq[81];
    int row0 = blockIdx.x * 64;
    int tid = threadIdx.x;
    if (tid < 81) { ssum[tid] = 0.0f; ssq[tid] = 0.0f; }
    // stage h1 rows from the (already-merged) atomic plane set
    for (int i = tid; i < 64 * 84; i += 512) {
        int r = i / 84, c = i % 84;
        float v = 0.0f;
        if (c < 81) {
            int row = row0 + r;             // b*512+s
            int b = row >> 9, s = row & 511;
            int h = c / 9, d = c % 9;
            int gidx = (b * 9 + h) * 512 + s;
            float L = apart[gidx];
            float A = apart[(1 + d) * 147456 + gidx];
            v = A / L;
        }
        rows_[i] = v;
    }
    for (int i = tid; i < 84 * 84; i += 512) {
        int e = i / 84, c = i % 84;
        Wl[i] = (e < 81 && c < 81) ? Wo1[e * 81 + c] : 0.0f;
    }
    __syncthreads();
    float hw = hwp[0];
    float onemhw = 1.0f - hw;
    for (int o = tid; o < 336; o += 512) {
        int r4 = o / 21, cg = o % 21;
        int c0 = cg * 4;
        const float* rp = rows_ + r4 * 4 * 84;
        vf4 acc0 = 0.0f, acc1 = 0.0f, acc2 = 0.0f, acc3 = 0.0f;
        #pragma unroll 7
        for (int e = 0; e < 84; e += 4) {
            vf4 w0 = *(const vf4*)(Wl + (e + 0) * 84 + c0);
            vf4 w1 = *(const vf4*)(Wl + (e + 1) * 84 + c0);
            vf4 w2 = *(const vf4*)(Wl + (e + 2) * 84 + c0);
            vf4 w3 = *(const vf4*)(Wl + (e + 3) * 84 + c0);
            vf4 r0 = *(const vf4*)(rp + e);
            vf4 r1 = *(const vf4*)(rp + 84 + e);
            vf4 r2 = *(const vf4*)(rp + 168 + e);
            vf4 r3 = *(const vf4*)(rp + 252 + e);
            acc0 += r0[0] * w0 + r0[1] * w1 + r0[2] * w2 + r0[3] * w3;
            acc1 += r1[0] * w0 + r1[1] * w1 + r1[2] * w2 + r1[3] * w3;
            acc2 += r2[0] * w0 + r2[1] * w1 + r2[2] * w2 + r2[3] * w3;
            acc3 += r3[0] * w0 + r3[1] * w1 + r3[2] * w2 + r3[3] * w3;
        }
        vf4 av[4] = {acc0, acc1, acc2, acc3};
        #pragma unroll
        for (int cc = 0; cc < 4; cc++) {
            int col = c0 + cc;
            if (col < 81) {
                float ls = 0.0f, lq = 0.0f;
                #pragma unroll
                for (int rr = 0; rr < 4; rr++) {
                    int idx = (row0 + r4 * 4 + rr) * 81 + col;
                    float v = onemhw * av[rr][cc] + hw * h2[idx] + txall[idx];
                    matin[idx] = v;
                    ls += v; lq += v * v;
                }
                atomicAdd(&ssum[col], ls);
                atomicAdd(&ssq[col], lq);
            }
        }
    }
    __syncthreads();
    if (tid < 81) {
        atomicAdd(&st1[tid], ssum[tid]);
        atomicAdd(&st1[81 + tid], ssq[tid]);
    }
}

// ---------------- ff1: 64 rows x 64 cols/block, 4x4 tile ; fused st2 ----------------
__global__ __launch_bounds__(512) void ff1_kernel(const float* __restrict__ matin,
                           const float* __restrict__ st1, const float* __restrict__ g1,
                           const float* __restrict__ b1, const float* __restrict__ W,
                           const float* __restrict__ bias, float* __restrict__ f1,
                           float* __restrict__ st2) {
    __shared__ float rows_[64 * 84];
    __shared__ float Wl[84 * 64];       // rows 81..83 zero
    __shared__ float s2s[64], s2q[64];
    int row0 = blockIdx.x * 64;
    int cb = blockIdx.y * 64;
    int tid = threadIdx.x;
    const float invN = 1.0f / 16384.0f;
    if (tid < 64) { s2s[tid] = 0.0f; s2q[tid] = 0.0f; }
    for (int i = tid; i < 64 * 84; i += 512) {
        int c = i % 84;
        float v = 0.0f;
        if (c < 81) {
            float mean = st1[c] * invN;
            float var = st1[81 + c] * invN - mean * mean;
            v = (matin[(row0 + i / 84) * 81 + c] - mean) * rsqrtf(var + EPSV) * g1[c] + b1[c];
        }
        rows_[i] = v;
    }
    for (int i = tid; i < 84 * 64; i += 512) {
        int e = i >> 6, cc = i & 63;
        Wl[i] = (e < 81) ? W[e * 256 + cb + cc] : 0.0f;
    }
    __syncthreads();
    if (tid < 256) {
        int o = tid;                 // 256 tasks: 16 r-groups x 16 c-groups
        int r4 = o >> 4, cg = o & 15;
        int c0 = cg * 4;
        const float* rp = rows_ + r4 * 4 * 84;
        vf4 acc0 = 0.0f, acc1 = 0.0f, acc2 = 0.0f, acc3 = 0.0f;
        #pragma unroll 7
        for (int e = 0; e < 84; e += 4) {
            vf4 w0 = *(const vf4*)(Wl + ((e + 0) << 6) + c0);
            vf4 w1 = *(const vf4*)(Wl + ((e + 1) << 6) + c0);
            vf4 w2 = *(const vf4*)(Wl + ((e + 2) << 6) + c0);
            vf4 w3 = *(const vf4*)(Wl + ((e + 3) << 6) + c0);
            vf4 r0 = *(const vf4*)(rp + e);
            vf4 r1 = *(const vf4*)(rp + 84 + e);
            vf4 r2 = *(const vf4*)(rp + 168 + e);
            vf4 r3 = *(const vf4*)(rp + 252 + e);
            acc0 += r0[0] * w0 + r0[1] * w1 + r0[2] * w2 + r0[3] * w3;
            acc1 += r1[0] * w0 + r1[1] * w1 + r1[2] * w2 + r1[3] * w3;
            acc2 += r2[0] * w0 + r2[1] * w1 + r2[2] * w2 + r2[3] * w3;
            acc3 += r3[0] * w0 + r3[1] * w1 + r3[2] * w2 + r3[3] * w3;
        }
        vf4 bv = *(const vf4*)(bias + cb + c0);
        acc0 = __builtin_elementwise_max(acc0 + bv, (vf4)0.0f);
        acc1 = __builtin_elementwise_max(acc1 + bv, (vf4)0.0f);
        acc2 = __builtin_elementwise_max(acc2 + bv, (vf4)0.0f);
        acc3 = __builtin_elementwise_max(acc3 + bv, (vf4)0.0f);
        int base = (row0 + r4 * 4) * 256 + cb + c0;
        *(vf4*)(f1 + base)       = acc0;
        *(vf4*)(f1 + base + 256) = acc1;
        *(vf4*)(f1 + base + 512) = acc2;
        *(vf4*)(f1 + base + 768) = acc3;
        vf4 cs = acc0 + acc1 + acc2 + acc3;
        vf4 cq = acc0 * acc0 + acc1 * acc1 + acc2 * acc2 + acc3 * acc3;
        #pragma unroll
        for (int cc = 0; cc < 4; cc++) {
            atomicAdd(&s2s[c0 + cc], cs[cc]);
            atomicAdd(&s2q[c0 + cc], cq[cc]);
        }
    }
    __syncthreads();
    if (tid < 64) {
        atomicAdd(&st2[cb + tid], s2s[tid]);
        atomicAdd(&st2[256 + cb + tid], s2q[tid]);
    }
}

// ---------------- ff2: 32 rows/block, 512 thr, 4 K-quarter passes, padded rows (stride 68) ----------------
__global__ __launch_bounds__(512) void ff2_kernel(const float* __restrict__ f1,
                           const float* __restrict__ st2, const float* __restrict__ g2,
                           const float* __restrict__ b2, const float* __restrict__ W,
                           const float* __restrict__ bias, const float* __restrict__ matin,
                           const float* __restrict__ st1, const float* __restrict__ g1,
                           const float* __restrict__ b1, float* __restrict__ t3,
                           float* __restrict__ st3) {
    __shared__ float rows_[32 * 68];    // stride 68: r-group offset 272 %32 = 16 -> 2-way (free)
    __shared__ float Wl[64 * 84];
    __shared__ float s3s[81], s3q[81];
    int row0 = blockIdx.x * 32;
    int tid = threadIdx.x;
    const float invN = 1.0f / 16384.0f;
    if (tid < 81) { s3s[tid] = 0.0f; s3q[tid] = 0.0f; }
    int o = tid;
    int r4 = o / 21, cg = o % 21;
    int c0 = cg * 4;
    bool active = (o < 168);
    vf4 acc0 = 0.0f, acc1 = 0.0f, acc2 = 0.0f, acc3 = 0.0f;
    for (int kq = 0; kq < 4; kq++) {
        __syncthreads();
        for (int i = tid; i < 32 * 68; i += 512) {
            int r = i / 68, e = i % 68;
            float v = 0.0f;
            if (e < 64) {
                int c = kq * 64 + e;
                float mean = st2[c] * invN;
                float var = st2[256 + c] * invN - mean * mean;
                v = (f1[(row0 + r) * 256 + c] - mean) * rsqrtf(var + EPSV) * g2[c] + b2[c];
            }
            rows_[i] = v;
        }
        for (int i = tid; i < 64 * 84; i += 512) {
            int e = i / 84, c = i % 84;
            Wl[i] = (c < 81) ? W[(kq * 64 + e) * 81 + c] : 0.0f;
        }
        __syncthreads();
        if (active) {
            const float* rp = rows_ + r4 * 4 * 68;
            #pragma unroll 8
            for (int e = 0; e < 64; e += 4) {
                vf4 w0 = *(const vf4*)(Wl + (e + 0) * 84 + c0);
                vf4 w1 = *(const vf4*)(Wl + (e + 1) * 84 + c0);
                vf4 w2 = *(const vf4*)(Wl + (e + 2) * 84 + c0);
                vf4 w3 = *(const vf4*)(Wl + (e + 3) * 84 + c0);
                vf4 r0 = *(const vf4*)(rp + e);
                vf4 r1 = *(const vf4*)(rp + 68 + e);
                vf4 r2 = *(const vf4*)(rp + 136 + e);
                vf4 r3 = *(const vf4*)(rp + 204 + e);
                acc0 += r0[0] * w0 + r0[1] * w1 + r0[2] * w2 + r0[3] * w3;
                acc1 += r1[0] * w0 + r1[1] * w1 + r1[2] * w2 + r1[3] * w3;
                acc2 += r2[0] * w0 + r2[1] * w1 + r2[2] * w2 + r2[3] * w3;
                acc3 += r3[0] * w0 + r3[1] * w1 + r3[2] * w2 + r3[3] * w3;
            }
        }
    }
    if (active) {
        vf4 av[4] = {acc0, acc1, acc2, acc3};
        #pragma unroll
        for (int cc = 0; cc < 4; cc++) {
            int col = c0 + cc;
            if (col < 81) {
                float mean = st1[col] * invN;
                float var = st1[81 + col] * invN - mean * mean;
                float rstd = rsqrtf(var + EPSV);
                float bval = bias[col];
                float ls = 0.0f, lq = 0.0f;
                #pragma unroll
                for (int rr = 0; rr < 4; rr++) {
                    int idx = (row0 + r4 * 4 + rr) * 81 + col;
                    float ma = (matin[idx] - mean) * rstd * g1[col] + b1[col];
                    float v = ma + fmaxf(av[rr][cc] + bval, 0.0f);
                    t3[idx] = v;
                    ls += v; lq += v * v;
                }
                atomicAdd(&s3s[col], ls);
                atomicAdd(&s3q[col], lq);
            }
        }
    }
    __syncthreads();
    if (tid < 81) {
        atomicAdd(&st3[tid], s3s[tid]);
        atomicAdd(&st3[81 + tid], s3q[tid]);
    }
}

// ---------------- token_mm: u/v dual GEMM (64 rows/block, W-pass split, 4x4 tile) ----------------
__global__ __launch_bounds__(512) void token_mm(const float* __restrict__ t3,
                            const float* __restrict__ st3, const float* __restrict__ g3,
                            const float* __restrict__ b3, const float* __restrict__ tvw,
                            const float* __restrict__ beta1,
                            float* __restrict__ uv0, float* __restrict__ uv1) {
    __shared__ float rows_[64 * 84];
    __shared__ float Wl[84 * 84];
    int blk = blockIdx.x;            // 0..511
    int t = blk >> 8;
    int row0 = (blk & 255) * 64;
    const float* W = (t == 0) ? tvw : beta1;
    float* dst = (t == 0) ? uv0 : uv1;
    int tid = threadIdx.x;
    const float invN = 1.0f / 16384.0f;
    for (int i = tid; i < 64 * 84; i += 512) {
        int c = i % 84;
        float v = 0.0f;
        if (c < 81) {
            float mean = st3[c] * invN;
            float var = st3[81 + c] * invN - mean * mean;
            v = (t3[(row0 + i / 84) * 81 + c] - mean) * rsqrtf(var + EPSV) * g3[c] + b3[c];
        }
        rows_[i] = v;
    }
    for (int i = tid; i < 84 * 84; i += 512) {
        int e = i / 84, c = i % 84;
        Wl[i] = (e < 81 && c < 81) ? W[e * 81 + c] : 0.0f;
    }
    __syncthreads();
    for (int o = tid; o < 336; o += 512) {
        int r4 = o / 21, cg = o % 21;
        int c0 = cg * 4;
        const float* rp = rows_ + r4 * 4 * 84;
        vf4 acc0 = 0.0f, acc1 = 0.0f, acc2 = 0.0f, acc3 = 0.0f;
        #pragma unroll 7
        for (int e = 0; e < 84; e += 4) {
            vf4 w0 = *(const vf4*)(Wl + (e + 0) * 84 + c0);
            vf4 w1 = *(const vf4*)(Wl + (e + 1) * 84 + c0);
            vf4 w2 = *(const vf4*)(Wl + (e + 2) * 84 + c0);
            vf4 w3 = *(const vf4*)(Wl + (e + 3) * 84 + c0);
            vf4 r0 = *(const vf4*)(rp + e);
            vf4 r1 = *(const vf4*)(rp + 84 + e);
            vf4 r2 = *(const vf4*)(rp + 168 + e);
            vf4 r3 = *(const vf4*)(rp + 252 + e);
            acc0 += r0[0] * w0 + r0[1] * w1 + r0[2] * w2 + r0[3] * w3;
            acc1 += r1[0] * w0 + r1[1] * w1 + r1[2] * w2 + r1[3] * w3;
            acc2 += r2[0] * w0 + r2[1] * w1 + r2[2] * w2 + r2[3] * w3;
            acc3 += r3[0] * w0 + r3[1] * w1 + r3[2] * w2 + r3[3] * w3;
        }
        vf4 av[4] = {acc0, acc1, acc2, acc3};
        #pragma unroll
        for (int cc = 0; cc < 4; cc++) {
            int col = c0 + cc;
            if (col < 81) {
                #pragma unroll
                for (int rr = 0; rr < 4; rr++)
                    dst[(row0 + r4 * 4 + rr) * 81 + col] = av[rr][cc];
            }
        }
    }
}

// ---------------- token_pool: softmax-pool over 81, 32 rows/block, 8 lanes/row ----------------
__global__ __launch_bounds__(256) void token_pool(const float* __restrict__ uv0,
                             const float* __restrict__ uv1, const float* __restrict__ tvb,
                             const float* __restrict__ basel, const float* __restrict__ a1p,
                             const float* __restrict__ a2p, float* __restrict__ fea) {
    int tid = threadIdx.x;
    int r = tid >> 3, j = tid & 7;
    int row = blockIdx.x * 32 + r;
    int base = row * 81;
    float u[11], v[11];
    #pragma unroll
    for (int dd = 0; dd < 11; dd++) {
        int d = j + dd * 8;
        if (d < 81) {
            u[dd] = uv0[base + d] + tvb[d];
            v[dd] = uv1[base + d];
        } else {
            u[dd] = 0.0f; v[dd] = -1e30f;
        }
    }
    float mx = -1e30f;
    #pragma unroll
    for (int dd = 0; dd < 11; dd++) mx = fmaxf(mx, v[dd]);
    #pragma unroll
    for (int msk = 1; msk < 8; msk <<= 1) mx = fmaxf(mx, __shfl_xor(mx, msk, 8));
    float sp = 0.0f, sup = 0.0f;
    #pragma unroll
    for (int dd = 0; dd < 11; dd++) {
        float p = __expf(v[dd] - mx);
        sp += p; sup += u[dd] * p;
    }
    #pragma unroll
    for (int msk = 1; msk < 8; msk <<= 1) {
        sp  += __shfl_xor(sp, msk, 8);
        sup += __shfl_xor(sup, msk, 8);
    }
    if (j == 0) {
        int b = row >> 9, s = row & 511;
        fea[row] = a1p[0] * (sup / sp) + a2p[0] * basel[b * 2048 + s * 4];
    }
}

// ---------------- fc1: relu(fea @ W + b), fused st4 ----------------
__global__ void fc1_kernel(const float* __restrict__ in, const float* __restrict__ W,
                           const float* __restrict__ bias, float* __restrict__ out,
                           float* __restrict__ st) {
    int idx = blockIdx.x * blockDim.x + threadIdx.x;
    if (idx >= 32 * 512) return;
    int b = idx >> 9, j = idx & 511;
    float acc = bias[j];
    const float* ip = in + (b << 9);
    #pragma unroll 8
    for (int k = 0; k < 512; k++) acc += ip[k] * W[k * 512 + j];
    acc = fmaxf(acc, 0.0f);
    out[idx] = acc;
    atomicAdd(&st[j], acc);
    atomicAdd(&st[512 + j], acc * acc);
}

// ---------------- fc2: relu(bn(fch1) @ W + b), fused st5 ----------------
__global__ __launch_bounds__(256) void fc2_kernel(const float* __restrict__ in,
                           const float* __restrict__ st4, const float* __restrict__ g,
                           const float* __restrict__ bb, const float* __restrict__ W,
                           const float* __restrict__ bias, float* __restrict__ out,
                           float* __restrict__ st5) {
    __shared__ float scale[512], shift[512];
    int tid = threadIdx.x;
    for (int k = tid; k < 512; k += 256) {
        float mean = st4[k] * (1.0f / 32.0f);
        float var = st4[512 + k] * (1.0f / 32.0f) - mean * mean;
        float sc_ = rsqrtf(var + EPSV) * g[k];
        scale[k] = sc_;
        shift[k] = bb[k] - mean * sc_;
    }
    __syncthreads();
    int idx = blockIdx.x * 256 + tid;
    if (idx >= 32 * 256) return;
    int b = idx >> 8, j = idx & 255;
    float acc = bias[j];
    const float* ip = in + (b << 9);
    #pragma unroll 8
    for (int k = 0; k < 512; k++) acc += (ip[k] * scale[k] + shift[k]) * W[k * 256 + j];
    acc = fmaxf(acc, 0.0f);
    out[idx] = acc;
    atomicAdd(&st5[j], acc);
    atomicAdd(&st5[256 + j], acc * acc);
}

// ---------------- fc3: tanh(bn(fch2) @ W + b) ----------------
__global__ void fc3_kernel(const float* __restrict__ in, const float* __restrict__ st5,
                           const float* __restrict__ g, const float* __restrict__ bb,
                           const float* __restrict__ W, const float* __restrict__ bias,
                           float* __restrict__ out) {
    __shared__ float scale[256], shift[256];
    int tid = threadIdx.x;   // 128
    for (int k = tid; k < 256; k += 128) {
        float mean = st5[k] * (1.0f / 32.0f);
        float var = st5[256 + k] * (1.0f / 32.0f) - mean * mean;
        float sc_ = rsqrtf(var + EPSV) * g[k];
        scale[k] = sc_;
        shift[k] = bb[k] - mean * sc_;
    }
    __syncthreads();
    int b = tid >> 2, j = tid & 3;
    float acc = bias[j];
    const float* ip = in + (b << 8);
    #pragma unroll 8
    for (int k = 0; k < 256; k++) acc += (ip[k] * scale[k] + shift[k]) * W[k * 4 + j];
    out[tid] = tanhf(acc);
}

// =======================================================================
extern "C" void kernel_launch(void* const* d_in, const int* in_sizes, int n_in,
                              void* d_out, int out_size, void* d_ws, size_t ws_size,
                              hipStream_t stream) {
    const float* x       = (const float*)d_in[0];
    const float* basel   = (const float*)d_in[1];
    const float* cali    = (const float*)d_in[2];
    const float* Wq      = (const float*)d_in[3];
    const float* Wk      = (const float*)d_in[4];
    const float* Wq2     = (const float*)d_in[5];
    const float* Wk2     = (const float*)d_in[6];
    const float* Wv2     = (const float*)d_in[7];
    const float* Cv      = (const float*)d_in[8];
    const float* Wo1     = (const float*)d_in[9];
    const float* Wo2     = (const float*)d_in[10];
    const float* corr_w  = (const float*)d_in[11];
    const float* h_w     = (const float*)d_in[12];
    const float* corr    = (const float*)d_in[13];
    const float* g1      = (const float*)d_in[14];
    const float* b1      = (const float*)d_in[15];
    const float* ff1_w   = (const float*)d_in[16];
    const float* ff1_b   = (const float*)d_in[17];
    const float* g2      = (const float*)d_in[18];
    const float* b2      = (const float*)d_in[19];
    const float* ff2_w   = (const float*)d_in[20];
    const float* ff2_b   = (const float*)d_in[21];
    const float* g3      = (const float*)d_in[22];
    const float* b3      = (const float*)d_in[23];
    const float* tvw     = (const float*)d_in[24];
    const float* tvb     = (const float*)d_in[25];
    const float* beta1   = (const float*)d_in[26];
    const float* a1      = (const float*)d_in[27];
    const float* a2      = (const float*)d_in[28];
    const float* fc1_w   = (const float*)d_in[29];
    const float* fc1_b   = (const float*)d_in[30];
    const float* bnf1_g  = (const float*)d_in[31];
    const float* bnf1_b  = (const float*)d_in[32];
    const float* fc2_w   = (const float*)d_in[33];
    const float* fc2_b   = (const float*)d_in[34];
    const float* bnf2_g  = (const float*)d_in[35];
    const float* bnf2_b  = (const float*)d_in[36];
    const float* fc3_w   = (const float*)d_in[37];
    const float* fc3_b   = (const float*)d_in[38];
    float* out = (float*)d_out;
    float* ws = (float*)d_ws;

    // ---- workspace layout (float offsets) ----
    const size_t SCAL  = 0;         // 2
    const size_t PART  = 16;        // 128
    const size_t ST1   = 512;       // 162
    const size_t ST2   = 768;       // 512
    const size_t ST3   = 1536;      // 162
    const size_t ST4   = 1792;      // 1024
    const size_t ST5   = 2880;      // 512
    const size_t FEA   = 4096;      // 16384
    const size_t FCH1  = 20480;     // 16384
    const size_t FCH2  = 36864;     // 8192
    const size_t PEO   = 45056;     // 41472
    const size_t TX    = 90112;     // 1990656
    const size_t Q2O   = 2080768;   // 1327104
    const size_t KCO   = 3407872;   // 1990656   (reused: Qs)
    const size_t VCO   = 5398528;   // 1990656   (reused: Ks)
    const size_t TMP2  = 7389184;   // 1327104   (reused: matin, then uv0)
    const size_t H2O   = 8716288;   // 1327104   (reused: t3)
    const size_t XHO   = 10043392;  // 1327104   (xh, dead after qks -> uv1)
    const size_t BIASO = 11370496;  // 262144    (EBT)
    const size_t F1O   = 11632640;  // 4194304   (f1; also attn1 planes 1474560)

    float* scal  = ws + SCAL;
    float* part  = ws + PART;
    float* st1   = ws + ST1;
    float* st2   = ws + ST2;
    float* st3   = ws + ST3;
    float* st4   = ws + ST4;
    float* st5   = ws + ST5;
    float* fea   = ws + FEA;
    float* fch1  = ws + FCH1;
    float* fch2  = ws + FCH2;
    float* pe    = ws + PEO;
    float* txall = ws + TX;
    float* Q2    = ws + Q2O;
    float* Kc    = ws + KCO;
    float* Vc    = ws + VCO;
    float* tmp2  = ws + TMP2;
    float* h2    = ws + H2O;
    float* xh    = ws + XHO;
    float* ebT   = ws + BIASO;
    float* f1    = ws + F1O;
    float* Qs    = Kc;     // reuse
    float* Ks    = Vc;     // reuse
    float* matin = tmp2;   // reuse (dead after ff2 -> uv0)
    float* t3    = h2;     // reuse
    float* apart = f1;     // attn1 atomic planes (10 x 147456 floats) in f1 region
    float* uv0   = tmp2;   // token u plane (matin dead after ff2)
    float* uv1   = xh;     // token v plane (xh dead after qks)

    // zero scal/part/stats region — capture-safe
    hipMemsetAsync(ws, 0, 4096 * sizeof(float), stream);
    // zero attn1 atomic planes (5.9 MB)
    hipMemsetAsync(apart, 0, 1474560 * sizeof(float), stream);

    minmax_part<<<64, 256, 0, stream>>>(x, part);
    minmax_fin<<<1, 64, 0, stream>>>(part, scal);

    pe_kernel<<<(512 * 81 + 255) / 256, 256, 0, stream>>>(pe);

    tokenize_kernel<<<(48 * 512 * 81 + 255) / 256, 256, 0, stream>>>(x, cali, scal, pe, txall);

    qkv2_kernel<<<1024, 512, 0, stream>>>(txall, Wq2, Wk2, Wv2, Q2, Kc, Vc);

    attn2_kernel<<<(512 * 9 * 32) / 256, 256, 0, stream>>>(Q2, Kc, Vc, tmp2);

    h2xh_kernel<<<256, 512, 0, stream>>>(tmp2, Wo2, txall, h2, xh);

    qks_kernel<<<512, 512, 0, stream>>>(xh, Wq, Wk, Qs, Ks);

    biasmm_kernel<<<dim3(16, 16), dim3(16, 16), 0, stream>>>(corr, Cv, corr_w, ebT);

    attn1_kernel<<<4608, 256, 0, stream>>>(Qs, Ks, ebT, corr_w, apart);

    h1o_kernel<<<256, 512, 0, stream>>>(apart, Wo1, h2, txall, h_w, matin, st1);

    ff1_kernel<<<dim3(256, 4), 512, 0, stream>>>(matin, st1, g1, b1, ff1_w, ff1_b, f1, st2);

    ff2_kernel<<<512, 512, 0, stream>>>(f1, st2, g2, b2, ff2_w, ff2_b,
                                        matin, st1, g1, b1, t3, st3);

    token_mm<<<512, 512, 0, stream>>>(t3, st3, g3, b3, tvw, beta1, uv0, uv1);
    token_pool<<<512, 256, 0, stream>>>(uv0, uv1, tvb, basel, a1, a2, fea);

    fc1_kernel<<<64, 256, 0, stream>>>(fea, fc1_w, fc1_b, fch1, st4);

    fc2_kernel<<<32, 256, 0, stream>>>(fch1, st4, bnf1_g, bnf1_b, fc2_w, fc2_b, fch2, st5);

    fc3_kernel<<<1, 128, 0, stream>>>(fch2, st5, bnf2_g, bnf2_b, fc3_w, fc3_b, out);
}